// Round 7
// baseline (244.730 us; speedup 1.0000x reference)
//
#include <hip/hip_runtime.h>
#include <math.h>

#define N_NODES 50000
#define N_EDGES 1600000
#define NFEAT 256
#define NHID 64
#define NCLASS 16

#define PBITS 7
#define PNODES 128                       // nodes per bin (R5-proven geometry)
#define NBINS ((N_NODES + PNODES - 1) / PNODES)   // 391
#define BIN_CAP 5120                     // mean 4092, sigma 64 -> +16 sigma
#define K3_CHUNK 4096
#define K3_THREADS 512
#define K3_PER_T 8                       // 4096 / 512
#define K3_BLOCKS ((N_EDGES + K3_CHUNK - 1) / K3_CHUNK)  // 391

__device__ inline unsigned short f2bf(float f) {     // RNE f32 -> bf16
    unsigned u = __float_as_uint(f);
    return (unsigned short)((u + 0x7FFFu + ((u >> 16) & 1u)) >> 16);
}

// ============ fused bin-scatter + dense GEMM1 (sequential phases) ==========
// Phase 1: per-block counting sort of 4096 edges into 391 bins -> csr_bin.
// Phase 2: each 512-thread block = 2x 256-thread gemm1 tiles (391*2 = 782
// tiles exactly covers 50000 nodes). No dependency between phases; blocks
// desynchronize so phase-2 VMEM overlaps other blocks' phase-1 LDS work.
// LDS is a union: scatter 58.8 KB superset of gemm1 16.9 KB -> 2 blocks/CU.
#define BK 16
__global__ __launch_bounds__(512) void scatter_gemm1_fused(
        const int* __restrict__ src, const int* __restrict__ dst,
        const float* __restrict__ w, int* __restrict__ bin_cursor,
        int2* __restrict__ csr_bin,
        const float* __restrict__ x, const float* __restrict__ W1,
        unsigned short* __restrict__ s1b) {
    __shared__ union {
        struct {                                     // scatter phase: 58.8 KB
            int2 sdata[K3_CHUNK];                    // 32 KB
            unsigned short sbinid[K3_CHUNK];         // 8 KB
            int swhist[4][NBINS];                    // 6.1 KB (wave-pair priv)
            int swcur[4][NBINS];                     // 6.1 KB
            int stot[NBINS];
            int lscan[NBINS];
            int sbase[NBINS];
            int stmp[512];
        } s;
        struct {                                     // gemm1 phase: 16.9 KB
            float xT[2][BK][68];
            float wt[2][BK][64];
        } g;
    } u;
    int t = threadIdx.x;

    // ------------------------- phase 1: scatter ---------------------------
    {
        int wv = t >> 7;                             // 4 hist copies, 2 waves ea
        int base_e = blockIdx.x * K3_CHUNK;
        for (int b = t; b < NBINS; b += K3_THREADS) {
            u.s.swhist[0][b] = 0; u.s.swhist[1][b] = 0;
            u.s.swhist[2][b] = 0; u.s.swhist[3][b] = 0;
        }
        __syncthreads();

        int2 myedge[K3_PER_T];
        short mybin[K3_PER_T];
#pragma unroll
        for (int k = 0; k < K3_PER_T; ++k) {
            int e = base_e + t + k * K3_THREADS;
            if (e < N_EDGES) {
                int d = min(max(dst[e], 0), N_NODES - 1);
                int s = min(max(src[e], 0), N_NODES - 1);
                int b = d >> PBITS;
                mybin[k] = (short)b;
                myedge[k] = make_int2((s << PBITS) | (d & (PNODES - 1)),
                                      __float_as_int(w[e]));
                atomicAdd(&u.s.swhist[wv][b], 1);
            } else mybin[k] = -1;
        }
        __syncthreads();
        {
            int v = 0;
            if (t < NBINS) {
                v = u.s.swhist[0][t] + u.s.swhist[1][t]
                  + u.s.swhist[2][t] + u.s.swhist[3][t];
                u.s.stot[t] = v;
            }
            u.s.stmp[t] = v;
        }
        __syncthreads();
        for (int off = 1; off < 512; off <<= 1) {
            int v0 = (t >= off) ? u.s.stmp[t - off] : 0;
            __syncthreads();
            u.s.stmp[t] += v0;
            __syncthreads();
        }
        if (t < NBINS) {
            u.s.lscan[t] = u.s.stmp[t] - u.s.stot[t];
            int c = u.s.stot[t];
            // count-only cursor: global slot base is b*BIN_CAP + prior count
            if (c > 0) u.s.sbase[t] = t * BIN_CAP + atomicAdd(&bin_cursor[t], c);
            int run = u.s.lscan[t];
            u.s.swcur[0][t] = run; run += u.s.swhist[0][t];
            u.s.swcur[1][t] = run; run += u.s.swhist[1][t];
            u.s.swcur[2][t] = run; run += u.s.swhist[2][t];
            u.s.swcur[3][t] = run;
        }
        __syncthreads();
#pragma unroll
        for (int k = 0; k < K3_PER_T; ++k) {
            int b = mybin[k];
            if (b >= 0) {
                int p = atomicAdd(&u.s.swcur[wv][b], 1);
                u.s.sdata[p] = myedge[k];
                u.s.sbinid[p] = (unsigned short)b;
            }
        }
        __syncthreads();
        int cnt = min(N_EDGES - base_e, K3_CHUNK);
#pragma unroll
        for (int k = 0; k < K3_PER_T; ++k) {
            int p = t + k * K3_THREADS;
            if (p < cnt) {
                int b = u.s.sbinid[p];
                int idx = u.s.sbase[b] + (p - u.s.lscan[b]);
                idx = min(idx, (b + 1) * BIN_CAP - 1);   // overflow-safe
                csr_bin[idx] = u.s.sdata[p];
            }
        }
    }
    __syncthreads();                                 // LDS union handoff

    // ------------------------- phase 2: gemm1 (2 tiles) -------------------
    {
        int sub = t >> 8;                            // 0/1: which 256-tile
        int t2  = t & 255;
        int tile = blockIdx.x * 2 + sub;             // < 782
        int n_base = tile * 64;
        int cq = t2 & 15;
        int nq = t2 >> 4;
        int ld_node = t2 >> 2;
        int ld_k4   = (t2 & 3) * 4;
        int gnode = min(n_base + ld_node, N_NODES - 1);
        const float* xrow = x + (size_t)gnode * NFEAT;
        int wr = t2 >> 4;
        int wc = (t2 & 15) * 4;
        float acc[4][4] = {};
        for (int k0 = 0; k0 < NFEAT; k0 += BK) {
            float4 xv = *(const float4*)(xrow + k0 + ld_k4);
            u.g.xT[sub][ld_k4 + 0][ld_node] = xv.x;
            u.g.xT[sub][ld_k4 + 1][ld_node] = xv.y;
            u.g.xT[sub][ld_k4 + 2][ld_node] = xv.z;
            u.g.xT[sub][ld_k4 + 3][ld_node] = xv.w;
            *(float4*)&u.g.wt[sub][wr][wc] =
                *(const float4*)(W1 + (size_t)(k0 + wr) * NHID + wc);
            __syncthreads();
#pragma unroll
            for (int k = 0; k < BK; ++k) {
                float4 a = *(const float4*)&u.g.xT[sub][k][4 * nq];
                float4 bb = *(const float4*)&u.g.wt[sub][k][4 * cq];
                acc[0][0] = fmaf(a.x, bb.x, acc[0][0]);
                acc[0][1] = fmaf(a.x, bb.y, acc[0][1]);
                acc[0][2] = fmaf(a.x, bb.z, acc[0][2]);
                acc[0][3] = fmaf(a.x, bb.w, acc[0][3]);
                acc[1][0] = fmaf(a.y, bb.x, acc[1][0]);
                acc[1][1] = fmaf(a.y, bb.y, acc[1][1]);
                acc[1][2] = fmaf(a.y, bb.z, acc[1][2]);
                acc[1][3] = fmaf(a.y, bb.w, acc[1][3]);
                acc[2][0] = fmaf(a.z, bb.x, acc[2][0]);
                acc[2][1] = fmaf(a.z, bb.y, acc[2][1]);
                acc[2][2] = fmaf(a.z, bb.z, acc[2][2]);
                acc[2][3] = fmaf(a.z, bb.w, acc[2][3]);
                acc[3][0] = fmaf(a.w, bb.x, acc[3][0]);
                acc[3][1] = fmaf(a.w, bb.y, acc[3][1]);
                acc[3][2] = fmaf(a.w, bb.z, acc[3][2]);
                acc[3][3] = fmaf(a.w, bb.w, acc[3][3]);
            }
            __syncthreads();
        }
#pragma unroll
        for (int i = 0; i < 4; ++i) {
            int n = n_base + 4 * nq + i;
            if (n < N_NODES) {
                ushort4 o;
                o.x = f2bf(acc[i][0]); o.y = f2bf(acc[i][1]);
                o.z = f2bf(acc[i][2]); o.w = f2bf(acc[i][3]);
                *(ushort4*)&s1b[(size_t)n * NHID + 4 * cq] = o;
            }
        }
    }
}

// ============ fused per-bin sort + SpMM1 + bias/ReLU + GEMM2 ===============
// R5-proven version (PNODES=128), reverted verbatim after R6's regression.
__global__ __launch_bounds__(1024, 4) void sort_spmm1_fused(
        const int* __restrict__ bin_cursor, const int2* __restrict__ csr_bin,
        int2* __restrict__ csr_edge, int2* __restrict__ row_range,
        const uint2* __restrict__ s1p2, const float* __restrict__ b1,
        const float* __restrict__ W2, float* __restrict__ s2) {
    __shared__ int2 sdata[BIN_CAP];                  // 40 KB sorted edges
    __shared__ union {
        struct { int whist[16][PNODES]; int wcur[16][PNODES]; } c;  // 16 KB
        float hsh[64][64];                                          // 16 KB
    } u;
    __shared__ int ltot[PNODES];
    __shared__ int ltmp[PNODES];
    __shared__ float W2s[NHID * NCLASS];             // 4 KB
    __shared__ float b1s[NHID];
    int t = threadIdx.x;
    int wv = t >> 6;                                 // 16 waves
    int b = blockIdx.x;
    int base = b * BIN_CAP;
    int cnt = min(bin_cursor[b], BIN_CAP);

    for (int i = t; i < 16 * PNODES; i += 1024) ((int*)u.c.whist)[i] = 0;
    if (t < NHID * NCLASS) W2s[t] = W2[t];
    if (t < NHID) b1s[t] = b1[t];
    __syncthreads();

    // --- hist pass ---
    {
        int j = t;
        for (; j + 1024 < cnt; j += 2048) {
            int2 e0 = csr_bin[base + j];
            int2 e1 = csr_bin[base + j + 1024];
            atomicAdd(&u.c.whist[wv][e0.x & (PNODES - 1)], 1);
            atomicAdd(&u.c.whist[wv][e1.x & (PNODES - 1)], 1);
        }
        if (j < cnt)
            atomicAdd(&u.c.whist[wv][csr_bin[base + j].x & (PNODES - 1)], 1);
    }
    __syncthreads();
    if (t < PNODES) {
        int v = 0;
#pragma unroll
        for (int k = 0; k < 16; ++k) v += u.c.whist[k][t];
        ltot[t] = v; ltmp[t] = v;
    }
    __syncthreads();
    for (int off = 1; off < PNODES; off <<= 1) {
        int a = 0;
        if (t < PNODES && t >= off) a = ltmp[t - off];
        __syncthreads();
        if (t < PNODES) ltmp[t] += a;
        __syncthreads();
    }
    if (t < PNODES) {
        int begl = ltmp[t] - ltot[t];                // local (0-based in bin)
        int node = b * PNODES + t;
        if (node < N_NODES)
            row_range[node] = make_int2(base + begl, base + ltmp[t]);
        int run = begl;
#pragma unroll
        for (int k = 0; k < 16; ++k) { u.c.wcur[k][t] = run; run += u.c.whist[k][t]; }
    }
    __syncthreads();
    // --- scatter pass: sorted (src, w) into LDS ---
    {
        int j = t;
        for (; j + 1024 < cnt; j += 2048) {
            int2 e0 = csr_bin[base + j];
            int2 e1 = csr_bin[base + j + 1024];
            int p0 = atomicAdd(&u.c.wcur[wv][e0.x & (PNODES - 1)], 1);
            int p1 = atomicAdd(&u.c.wcur[wv][e1.x & (PNODES - 1)], 1);
            sdata[p0] = make_int2(e0.x >> PBITS, e0.y);
            sdata[p1] = make_int2(e1.x >> PBITS, e1.y);
        }
        if (j < cnt) {
            int2 e0 = csr_bin[base + j];
            int p0 = atomicAdd(&u.c.wcur[wv][e0.x & (PNODES - 1)], 1);
            sdata[p0] = make_int2(e0.x >> PBITS, e0.y);
        }
    }
    __syncthreads();
    // --- coalesced writeback for spmm2 ---
    for (int i = t; i < cnt; i += 1024) csr_edge[base + i] = sdata[i];

    // --- spmm1 + bias/ReLU + gemm2, 64 node-groups x 16 lanes, 2 rounds ---
    int g = t >> 4, lane = t & 15;
#pragma unroll
    for (int round = 0; round < 2; ++round) {
        int nl = g + 64 * round;
        int node = b * PNODES + nl;
        if (node >= N_NODES) continue;
        int endl = ltmp[nl];
        int j = endl - ltot[nl];
        float4 accA = {0.f, 0.f, 0.f, 0.f}, accB = {0.f, 0.f, 0.f, 0.f};
        for (; j + 7 < endl; j += 8) {
            int2 e0 = sdata[j],     e1 = sdata[j + 1];
            int2 e2 = sdata[j + 2], e3 = sdata[j + 3];
            int2 e4 = sdata[j + 4], e5 = sdata[j + 5];
            int2 e6 = sdata[j + 6], e7 = sdata[j + 7];
            uint2 v0 = s1p2[(size_t)e0.x * 16 + lane];
            uint2 v1 = s1p2[(size_t)e1.x * 16 + lane];
            uint2 v2 = s1p2[(size_t)e2.x * 16 + lane];
            uint2 v3 = s1p2[(size_t)e3.x * 16 + lane];
            uint2 v4 = s1p2[(size_t)e4.x * 16 + lane];
            uint2 v5 = s1p2[(size_t)e5.x * 16 + lane];
            uint2 v6 = s1p2[(size_t)e6.x * 16 + lane];
            uint2 v7 = s1p2[(size_t)e7.x * 16 + lane];
            float w0 = __int_as_float(e0.y), w1 = __int_as_float(e1.y);
            float w2 = __int_as_float(e2.y), w3 = __int_as_float(e3.y);
            float w4 = __int_as_float(e4.y), w5 = __int_as_float(e5.y);
            float w6 = __int_as_float(e6.y), w7 = __int_as_float(e7.y);
            accA.x = fmaf(w0, __uint_as_float(v0.x << 16), accA.x);
            accA.y = fmaf(w0, __uint_as_float(v0.x & 0xFFFF0000u), accA.y);
            accA.z = fmaf(w0, __uint_as_float(v0.y << 16), accA.z);
            accA.w = fmaf(w0, __uint_as_float(v0.y & 0xFFFF0000u), accA.w);
            accB.x = fmaf(w1, __uint_as_float(v1.x << 16), accB.x);
            accB.y = fmaf(w1, __uint_as_float(v1.x & 0xFFFF0000u), accB.y);
            accB.z = fmaf(w1, __uint_as_float(v1.y << 16), accB.z);
            accB.w = fmaf(w1, __uint_as_float(v1.y & 0xFFFF0000u), accB.w);
            accA.x = fmaf(w2, __uint_as_float(v2.x << 16), accA.x);
            accA.y = fmaf(w2, __uint_as_float(v2.x & 0xFFFF0000u), accA.y);
            accA.z = fmaf(w2, __uint_as_float(v2.y << 16), accA.z);
            accA.w = fmaf(w2, __uint_as_float(v2.y & 0xFFFF0000u), accA.w);
            accB.x = fmaf(w3, __uint_as_float(v3.x << 16), accB.x);
            accB.y = fmaf(w3, __uint_as_float(v3.x & 0xFFFF0000u), accB.y);
            accB.z = fmaf(w3, __uint_as_float(v3.y << 16), accB.z);
            accB.w = fmaf(w3, __uint_as_float(v3.y & 0xFFFF0000u), accB.w);
            accA.x = fmaf(w4, __uint_as_float(v4.x << 16), accA.x);
            accA.y = fmaf(w4, __uint_as_float(v4.x & 0xFFFF0000u), accA.y);
            accA.z = fmaf(w4, __uint_as_float(v4.y << 16), accA.z);
            accA.w = fmaf(w4, __uint_as_float(v4.y & 0xFFFF0000u), accA.w);
            accB.x = fmaf(w5, __uint_as_float(v5.x << 16), accB.x);
            accB.y = fmaf(w5, __uint_as_float(v5.x & 0xFFFF0000u), accB.y);
            accB.z = fmaf(w5, __uint_as_float(v5.y << 16), accB.z);
            accB.w = fmaf(w5, __uint_as_float(v5.y & 0xFFFF0000u), accB.w);
            accA.x = fmaf(w6, __uint_as_float(v6.x << 16), accA.x);
            accA.y = fmaf(w6, __uint_as_float(v6.x & 0xFFFF0000u), accA.y);
            accA.z = fmaf(w6, __uint_as_float(v6.y << 16), accA.z);
            accA.w = fmaf(w6, __uint_as_float(v6.y & 0xFFFF0000u), accA.w);
            accB.x = fmaf(w7, __uint_as_float(v7.x << 16), accB.x);
            accB.y = fmaf(w7, __uint_as_float(v7.x & 0xFFFF0000u), accB.y);
            accB.z = fmaf(w7, __uint_as_float(v7.y << 16), accB.z);
            accB.w = fmaf(w7, __uint_as_float(v7.y & 0xFFFF0000u), accB.w);
        }
        for (; j < endl; ++j) {
            int2 e0 = sdata[j];
            uint2 v0 = s1p2[(size_t)e0.x * 16 + lane];
            float w0 = __int_as_float(e0.y);
            accA.x = fmaf(w0, __uint_as_float(v0.x << 16), accA.x);
            accA.y = fmaf(w0, __uint_as_float(v0.x & 0xFFFF0000u), accA.y);
            accA.z = fmaf(w0, __uint_as_float(v0.y << 16), accA.z);
            accA.w = fmaf(w0, __uint_as_float(v0.y & 0xFFFF0000u), accA.w);
        }
        float4 bb = *(const float4*)&b1s[4 * lane];
        float4 hv;
        hv.x = accA.x + accB.x + bb.x;
        hv.y = accA.y + accB.y + bb.y;
        hv.z = accA.z + accB.z + bb.z;
        hv.w = accA.w + accB.w + bb.w;
        hv.x = hv.x > 0.f ? hv.x : 0.f;
        hv.y = hv.y > 0.f ? hv.y : 0.f;
        hv.z = hv.z > 0.f ? hv.z : 0.f;
        hv.w = hv.w > 0.f ? hv.w : 0.f;
        // same-wave LDS park (lockstep within wave, no barrier needed)
        *(float4*)&u.hsh[g][4 * lane] = hv;
        float acc = 0.f;
#pragma unroll 16
        for (int k = 0; k < NHID; ++k)
            acc = fmaf(u.hsh[g][k], W2s[k * NCLASS + lane], acc);
        s2[(size_t)node * NCLASS + lane] = acc;
    }
}

// ======================= SpMM2 + bias + log_softmax ========================
// R13-exact: fp32 s2, 16 lanes/node, 8-edge unrolled.
__global__ void spmm2_csr_kernel(const int2* __restrict__ row_range,
                                 const int2* __restrict__ csr_edge,
                                 const float* __restrict__ s2,
                                 const float* __restrict__ b2,
                                 float* __restrict__ out) {
    int node = blockIdx.x * 16 + (threadIdx.x >> 4);
    if (node >= N_NODES) return;
    int c = threadIdx.x & 15;
    int2 rr = row_range[node];
    int beg = rr.x, end = rr.y;
    float acc0 = 0.f, acc1 = 0.f, acc2 = 0.f, acc3 = 0.f;
    int j = beg;
    for (; j + 7 < end; j += 8) {
        int2 e0 = csr_edge[j],     e1 = csr_edge[j + 1];
        int2 e2 = csr_edge[j + 2], e3 = csr_edge[j + 3];
        int2 e4 = csr_edge[j + 4], e5 = csr_edge[j + 5];
        int2 e6 = csr_edge[j + 6], e7 = csr_edge[j + 7];
        float g0 = s2[(size_t)e0.x * NCLASS + c];
        float g1 = s2[(size_t)e1.x * NCLASS + c];
        float g2 = s2[(size_t)e2.x * NCLASS + c];
        float g3 = s2[(size_t)e3.x * NCLASS + c];
        float g4 = s2[(size_t)e4.x * NCLASS + c];
        float g5 = s2[(size_t)e5.x * NCLASS + c];
        float g6 = s2[(size_t)e6.x * NCLASS + c];
        float g7 = s2[(size_t)e7.x * NCLASS + c];
        acc0 = fmaf(__int_as_float(e0.y), g0, acc0);
        acc1 = fmaf(__int_as_float(e1.y), g1, acc1);
        acc2 = fmaf(__int_as_float(e2.y), g2, acc2);
        acc3 = fmaf(__int_as_float(e3.y), g3, acc3);
        acc0 = fmaf(__int_as_float(e4.y), g4, acc0);
        acc1 = fmaf(__int_as_float(e5.y), g5, acc1);
        acc2 = fmaf(__int_as_float(e6.y), g6, acc2);
        acc3 = fmaf(__int_as_float(e7.y), g7, acc3);
    }
    for (; j + 3 < end; j += 4) {
        int2 e0 = csr_edge[j],     e1 = csr_edge[j + 1];
        int2 e2 = csr_edge[j + 2], e3 = csr_edge[j + 3];
        acc0 = fmaf(__int_as_float(e0.y), s2[(size_t)e0.x * NCLASS + c], acc0);
        acc1 = fmaf(__int_as_float(e1.y), s2[(size_t)e1.x * NCLASS + c], acc1);
        acc2 = fmaf(__int_as_float(e2.y), s2[(size_t)e2.x * NCLASS + c], acc2);
        acc3 = fmaf(__int_as_float(e3.y), s2[(size_t)e3.x * NCLASS + c], acc3);
    }
    for (; j < end; ++j) {
        int2 e0 = csr_edge[j];
        acc0 = fmaf(__int_as_float(e0.y), s2[(size_t)e0.x * NCLASS + c], acc0);
    }
    float v = (acc0 + acc1) + (acc2 + acc3) + b2[c];
    float mx = v;
    for (int off = 8; off; off >>= 1) mx = fmaxf(mx, __shfl_xor(mx, off, 16));
    float ss = expf(v - mx);
    for (int off = 8; off; off >>= 1) ss += __shfl_xor(ss, off, 16);
    out[(size_t)node * NCLASS + c] = v - mx - logf(ss);
}

// ======================= fallback path (R3 atomic version) =================

__global__ void zero_kernel(float* __restrict__ h, float* __restrict__ out) {
    int i = blockIdx.x * 256 + threadIdx.x;
    if (i < N_NODES * NHID) h[i] = 0.f;
    if (i < N_NODES * NCLASS) out[i] = 0.f;
}

__global__ void gemm1_kernel(const float* __restrict__ x,
                             const float* __restrict__ W1,
                             float* __restrict__ s1) {
    int node = blockIdx.x * 4 + (threadIdx.x >> 6);
    int col  = threadIdx.x & 63;
    if (node >= N_NODES) return;
    const float* xr = x + (size_t)node * NFEAT;
    float sum = 0.f;
#pragma unroll 8
    for (int k = 0; k < NFEAT; ++k)
        sum = fmaf(xr[k], W1[k * NHID + col], sum);
    s1[(size_t)node * NHID + col] = sum;
}

__global__ void spmm1_kernel(const int* __restrict__ src, const int* __restrict__ dst,
                             const float* __restrict__ w, const float* __restrict__ s1,
                             float* __restrict__ h) {
    int e = blockIdx.x * 4 + (threadIdx.x >> 6);
    if (e >= N_EDGES) return;
    int lane = threadIdx.x & 63;
    int s = min(max(src[e], 0), N_NODES - 1);
    int d = min(max(dst[e], 0), N_NODES - 1);
    float v = w[e] * s1[(size_t)s * NHID + lane];
    atomicAdd(&h[(size_t)d * NHID + lane], v);
}

__global__ void bias_relu_kernel(float* __restrict__ h, const float* __restrict__ b1) {
    int i = blockIdx.x * 256 + threadIdx.x;
    if (i >= N_NODES * NHID) return;
    float v = h[i] + b1[i & (NHID - 1)];
    h[i] = v > 0.f ? v : 0.f;
}

__global__ void gemm2_kernel(const float* __restrict__ h,
                             const float* __restrict__ W2,
                             float* __restrict__ s2) {
    int node = blockIdx.x * 16 + (threadIdx.x >> 4);
    int col  = threadIdx.x & 15;
    if (node >= N_NODES) return;
    const float* hr = h + (size_t)node * NHID;
    float sum = 0.f;
#pragma unroll 8
    for (int k = 0; k < NHID; ++k)
        sum = fmaf(hr[k], W2[k * NCLASS + col], sum);
    s2[(size_t)node * NCLASS + col] = sum;
}

__global__ void spmm2_kernel(const int* __restrict__ src, const int* __restrict__ dst,
                             const float* __restrict__ w, const float* __restrict__ s2,
                             float* __restrict__ out) {
    int e = blockIdx.x * 16 + (threadIdx.x >> 4);
    if (e >= N_EDGES) return;
    int lane = threadIdx.x & 15;
    int s = min(max(src[e], 0), N_NODES - 1);
    int d = min(max(dst[e], 0), N_NODES - 1);
    float v = w[e] * s2[(size_t)s * NCLASS + lane];
    atomicAdd(&out[(size_t)d * NCLASS + lane], v);
}

__global__ void logsoftmax_kernel(float* __restrict__ out, const float* __restrict__ b2) {
    int n = blockIdx.x * 256 + threadIdx.x;
    if (n >= N_NODES) return;
    float v[NCLASS];
    float mx = -INFINITY;
#pragma unroll
    for (int c = 0; c < NCLASS; ++c) {
        v[c] = out[(size_t)n * NCLASS + c] + b2[c];
        mx = fmaxf(mx, v[c]);
    }
    float ssum = 0.f;
#pragma unroll
    for (int c = 0; c < NCLASS; ++c) ssum += expf(v[c] - mx);
    float ls = mx + logf(ssum);
#pragma unroll
    for (int c = 0; c < NCLASS; ++c) out[(size_t)n * NCLASS + c] = v[c] - ls;
}

// ======================= launch ============================================

extern "C" void kernel_launch(void* const* d_in, const int* in_sizes, int n_in,
                              void* d_out, int out_size, void* d_ws, size_t ws_size,
                              hipStream_t stream) {
    if (n_in != 8) return;
    const int expected[8] = { N_NODES * NFEAT, NFEAT * NHID, NHID,
                              NHID * NCLASS, NCLASS, N_EDGES, N_EDGES, N_EDGES };
    for (int i = 0; i < 8; ++i)
        if (in_sizes[i] != expected[i]) return;
    if (out_size != N_NODES * NCLASS) return;

    const float* x  = (const float*)d_in[0];
    const float* W1 = (const float*)d_in[1];
    const float* b1 = (const float*)d_in[2];
    const float* W2 = (const float*)d_in[3];
    const float* b2 = (const float*)d_in[4];
    const int* edge_src = (const int*)d_in[5];
    const int* edge_dst = (const int*)d_in[6];
    const float* edge_w = (const float*)d_in[7];
    float* out = (float*)d_out;

    const size_t S1_ELTS = (size_t)N_NODES * NHID;          // 3.2M (ushorts)
    const size_t CAP_WORDS = (size_t)NBINS * BIN_CAP * 2;   // int2 region, words
    // layout (32-bit words) — fully DISJOINT (s1b live alongside csr_bin
    // inside sort_spmm1_fused):
    //   [0, CAP)          csr_bin    (16 MB)
    //   [CAP, 2CAP)       csr_edge   (16 MB)
    //   [2CAP, +2N)       row_range  (0.4 MB)
    //   [.., +512)        bin_cursor (391 ints + pad, keeps s1b 8B-aligned)
    //   [.., +S1/2)       s1b        (6.4 MB bf16)
    //   [.., +N*NCLASS)   s2         (3.2 MB fp32)
    const size_t NEW_WORDS = 2 * CAP_WORDS + 2 * (size_t)N_NODES + 512
                           + S1_ELTS / 2 + (size_t)N_NODES * NCLASS;
    if (ws_size >= NEW_WORDS * 4) {
        int2*  csr_bin    = (int2*)d_ws;
        int2*  csr_edge   = (int2*)((int*)d_ws + CAP_WORDS);
        int2*  row_range  = (int2*)((int*)d_ws + 2 * CAP_WORDS);
        int*   bin_cursor = (int*)d_ws + 2 * CAP_WORDS + 2 * (size_t)N_NODES;
        unsigned short* s1b =
            (unsigned short*)((int*)d_ws + 2 * CAP_WORDS + 2 * (size_t)N_NODES + 512);
        float* s2 = (float*)d_ws + 2 * CAP_WORDS + 2 * (size_t)N_NODES + 512
                  + S1_ELTS / 2;

        hipMemsetAsync(bin_cursor, 0, NBINS * sizeof(int), stream);
        scatter_gemm1_fused<<<K3_BLOCKS, K3_THREADS, 0, stream>>>(
            edge_src, edge_dst, edge_w, bin_cursor, csr_bin, x, W1, s1b);
        sort_spmm1_fused<<<NBINS, 1024, 0, stream>>>(
            bin_cursor, csr_bin, csr_edge, row_range,
            (const uint2*)s1b, b1, W2, s2);
        spmm2_csr_kernel<<<(N_NODES + 15) / 16, 256, 0, stream>>>(
            row_range, csr_edge, s2, b2, out);
        return;
    }

    // --- fallback: proven atomic path (25.6 MB ws) ---
    if (ws_size < 2 * S1_ELTS * sizeof(float)) return;
    float* s1 = (float*)d_ws;
    float* h  = s1 + S1_ELTS;
    float* s2 = s1;
    zero_kernel<<<(N_NODES * NHID + 255) / 256, 256, 0, stream>>>(h, out);
    gemm1_kernel<<<(N_NODES + 3) / 4, 256, 0, stream>>>(x, W1, s1);
    spmm1_kernel<<<(N_EDGES + 3) / 4, 256, 0, stream>>>(edge_src, edge_dst, edge_w, s1, h);
    bias_relu_kernel<<<(N_NODES * NHID + 255) / 256, 256, 0, stream>>>(h, b1);
    gemm2_kernel<<<(N_NODES + 15) / 16, 256, 0, stream>>>(h, W2, s2);
    spmm2_kernel<<<(N_EDGES + 15) / 16, 256, 0, stream>>>(edge_src, edge_dst, edge_w, s2, out);
    logsoftmax_kernel<<<(N_NODES + 255) / 256, 256, 0, stream>>>(out, b2);
}

// Round 10
// 209.021 us; speedup vs baseline: 1.1708x; 1.1708x over previous
//
#include <hip/hip_runtime.h>
#include <math.h>

#define N_NODES 50000
#define N_EDGES 1600000
#define NFEAT 256
#define NHID 64
#define NCLASS 16

#define PBITS 7
#define PNODES 128                       // nodes per bin (R5-proven geometry)
#define NBINS ((N_NODES + PNODES - 1) / PNODES)   // 391
#define BIN_CAP 5120                     // mean 4092, sigma 64 -> +16 sigma
#define K3_CHUNK 4096
#define K3_THREADS 512
#define K3_PER_T 8                       // 4096 / 512
#define K3_BLOCKS ((N_EDGES + K3_CHUNK - 1) / K3_CHUNK)  // 391

__device__ inline unsigned short f2bf(float f) {     // RNE f32 -> bf16
    unsigned u = __float_as_uint(f);
    return (unsigned short)((u + 0x7FFFu + ((u >> 16) & 1u)) >> 16);
}

// ======================= bin scatter (counting sort, pass 1) ===============
// R10: 512 threads (8 waves -> ~12 waves/CU vs R5's ~6) for the latency-bound
// sort. Structure validated in R7 phase-1 (correctness-proven there; R7's
// regression was the gemm1 fusion, not this). bin_cursor is COUNT-ONLY
// (memset 0 by host); slot base is b*BIN_CAP.
__global__ __launch_bounds__(512) void bin_scatter_kernel(
        const int* __restrict__ src, const int* __restrict__ dst,
        const float* __restrict__ w, int* __restrict__ bin_cursor,
        int2* __restrict__ csr_bin) {
    __shared__ int2 sdata[K3_CHUNK];                 // 32 KB
    __shared__ unsigned short sbinid[K3_CHUNK];      // 8 KB
    __shared__ int swhist[4][NBINS];                 // 6.1 KB (wave-pair priv)
    __shared__ int swcur[4][NBINS];                  // 6.1 KB
    __shared__ int stot[NBINS];
    __shared__ int lscan[NBINS];
    __shared__ int sbase[NBINS];
    __shared__ int stmp[512];
    int t = threadIdx.x;
    int wv = t >> 7;                                 // 4 hist copies, 2 waves ea
    int base_e = blockIdx.x * K3_CHUNK;

    for (int b = t; b < NBINS; b += K3_THREADS) {
        swhist[0][b] = 0; swhist[1][b] = 0; swhist[2][b] = 0; swhist[3][b] = 0;
    }
    __syncthreads();

    int2 myedge[K3_PER_T];
    short mybin[K3_PER_T];
#pragma unroll
    for (int k = 0; k < K3_PER_T; ++k) {
        int e = base_e + t + k * K3_THREADS;
        if (e < N_EDGES) {
            int d = min(max(dst[e], 0), N_NODES - 1);
            int s = min(max(src[e], 0), N_NODES - 1);
            int b = d >> PBITS;
            mybin[k] = (short)b;
            myedge[k] = make_int2((s << PBITS) | (d & (PNODES - 1)),
                                  __float_as_int(w[e]));
            atomicAdd(&swhist[wv][b], 1);
        } else mybin[k] = -1;
    }
    __syncthreads();
    {
        int v = 0;
        if (t < NBINS) {
            v = swhist[0][t] + swhist[1][t] + swhist[2][t] + swhist[3][t];
            stot[t] = v;
        }
        stmp[t] = v;
    }
    __syncthreads();
    for (int off = 1; off < 512; off <<= 1) {
        int v0 = (t >= off) ? stmp[t - off] : 0;
        __syncthreads();
        stmp[t] += v0;
        __syncthreads();
    }
    if (t < NBINS) {
        lscan[t] = stmp[t] - stot[t];
        int c = stot[t];
        // count-only cursor: global slot base is b*BIN_CAP + prior count
        if (c > 0) sbase[t] = t * BIN_CAP + atomicAdd(&bin_cursor[t], c);
        int run = lscan[t];
        swcur[0][t] = run; run += swhist[0][t];
        swcur[1][t] = run; run += swhist[1][t];
        swcur[2][t] = run; run += swhist[2][t];
        swcur[3][t] = run;
    }
    __syncthreads();
#pragma unroll
    for (int k = 0; k < K3_PER_T; ++k) {
        int b = mybin[k];
        if (b >= 0) {
            int p = atomicAdd(&swcur[wv][b], 1);
            sdata[p] = myedge[k];
            sbinid[p] = (unsigned short)b;
        }
    }
    __syncthreads();
    int cnt = min(N_EDGES - base_e, K3_CHUNK);
#pragma unroll
    for (int k = 0; k < K3_PER_T; ++k) {
        int p = t + k * K3_THREADS;
        if (p < cnt) {
            int b = sbinid[p];
            int idx = sbase[b] + (p - lscan[b]);
            idx = min(idx, (b + 1) * BIN_CAP - 1);   // overflow-safe (no fault)
            csr_bin[idx] = sdata[p];
        }
    }
}

// ======================= dense GEMM 1 (R13-proven) =========================

#define BK 16
__global__ __launch_bounds__(256) void gemm1_tiled(const float* __restrict__ x,
                                                   const float* __restrict__ W1,
                                                   unsigned short* __restrict__ s1b) {
    __shared__ float xT[BK][68];
    __shared__ float wt[BK][64];
    int t = threadIdx.x;
    int n_base = blockIdx.x * 64;
    int cq = t & 15;
    int nq = t >> 4;
    int ld_node = t >> 2;
    int ld_k4   = (t & 3) * 4;
    int gnode = min(n_base + ld_node, N_NODES - 1);
    const float* xrow = x + (size_t)gnode * NFEAT;
    int wr = t >> 4;
    int wc = (t & 15) * 4;
    float acc[4][4] = {};
    for (int k0 = 0; k0 < NFEAT; k0 += BK) {
        float4 xv = *(const float4*)(xrow + k0 + ld_k4);
        xT[ld_k4 + 0][ld_node] = xv.x;
        xT[ld_k4 + 1][ld_node] = xv.y;
        xT[ld_k4 + 2][ld_node] = xv.z;
        xT[ld_k4 + 3][ld_node] = xv.w;
        *(float4*)&wt[wr][wc] = *(const float4*)(W1 + (size_t)(k0 + wr) * NHID + wc);
        __syncthreads();
#pragma unroll
        for (int k = 0; k < BK; ++k) {
            float4 a = *(const float4*)&xT[k][4 * nq];
            float4 bb = *(const float4*)&wt[k][4 * cq];
            acc[0][0] = fmaf(a.x, bb.x, acc[0][0]);
            acc[0][1] = fmaf(a.x, bb.y, acc[0][1]);
            acc[0][2] = fmaf(a.x, bb.z, acc[0][2]);
            acc[0][3] = fmaf(a.x, bb.w, acc[0][3]);
            acc[1][0] = fmaf(a.y, bb.x, acc[1][0]);
            acc[1][1] = fmaf(a.y, bb.y, acc[1][1]);
            acc[1][2] = fmaf(a.y, bb.z, acc[1][2]);
            acc[1][3] = fmaf(a.y, bb.w, acc[1][3]);
            acc[2][0] = fmaf(a.z, bb.x, acc[2][0]);
            acc[2][1] = fmaf(a.z, bb.y, acc[2][1]);
            acc[2][2] = fmaf(a.z, bb.z, acc[2][2]);
            acc[2][3] = fmaf(a.z, bb.w, acc[2][3]);
            acc[3][0] = fmaf(a.w, bb.x, acc[3][0]);
            acc[3][1] = fmaf(a.w, bb.y, acc[3][1]);
            acc[3][2] = fmaf(a.w, bb.z, acc[3][2]);
            acc[3][3] = fmaf(a.w, bb.w, acc[3][3]);
        }
        __syncthreads();
    }
#pragma unroll
    for (int i = 0; i < 4; ++i) {
        int n = n_base + 4 * nq + i;
        if (n < N_NODES) {
            ushort4 o;
            o.x = f2bf(acc[i][0]); o.y = f2bf(acc[i][1]);
            o.z = f2bf(acc[i][2]); o.w = f2bf(acc[i][3]);
            *(ushort4*)&s1b[(size_t)n * NHID + 4 * cq] = o;
        }
    }
}

// ============ fused per-bin sort + SpMM1 + bias/ReLU + GEMM2 ===============
// R5-proven version, verbatim (45.4 us measured, best known).
__global__ __launch_bounds__(1024, 4) void sort_spmm1_fused(
        const int* __restrict__ bin_cursor, const int2* __restrict__ csr_bin,
        int2* __restrict__ csr_edge, int2* __restrict__ row_range,
        const uint2* __restrict__ s1p2, const float* __restrict__ b1,
        const float* __restrict__ W2, float* __restrict__ s2) {
    __shared__ int2 sdata[BIN_CAP];                  // 40 KB sorted edges
    __shared__ union {
        struct { int whist[16][PNODES]; int wcur[16][PNODES]; } c;  // 16 KB
        float hsh[64][64];                                          // 16 KB
    } u;
    __shared__ int ltot[PNODES];
    __shared__ int ltmp[PNODES];
    __shared__ float W2s[NHID * NCLASS];             // 4 KB
    __shared__ float b1s[NHID];
    int t = threadIdx.x;
    int wv = t >> 6;                                 // 16 waves
    int b = blockIdx.x;
    int base = b * BIN_CAP;
    int cnt = min(bin_cursor[b], BIN_CAP);

    for (int i = t; i < 16 * PNODES; i += 1024) ((int*)u.c.whist)[i] = 0;
    if (t < NHID * NCLASS) W2s[t] = W2[t];
    if (t < NHID) b1s[t] = b1[t];
    __syncthreads();

    // --- hist pass ---
    {
        int j = t;
        for (; j + 1024 < cnt; j += 2048) {
            int2 e0 = csr_bin[base + j];
            int2 e1 = csr_bin[base + j + 1024];
            atomicAdd(&u.c.whist[wv][e0.x & (PNODES - 1)], 1);
            atomicAdd(&u.c.whist[wv][e1.x & (PNODES - 1)], 1);
        }
        if (j < cnt)
            atomicAdd(&u.c.whist[wv][csr_bin[base + j].x & (PNODES - 1)], 1);
    }
    __syncthreads();
    if (t < PNODES) {
        int v = 0;
#pragma unroll
        for (int k = 0; k < 16; ++k) v += u.c.whist[k][t];
        ltot[t] = v; ltmp[t] = v;
    }
    __syncthreads();
    for (int off = 1; off < PNODES; off <<= 1) {
        int a = 0;
        if (t < PNODES && t >= off) a = ltmp[t - off];
        __syncthreads();
        if (t < PNODES) ltmp[t] += a;
        __syncthreads();
    }
    if (t < PNODES) {
        int begl = ltmp[t] - ltot[t];                // local (0-based in bin)
        int node = b * PNODES + t;
        if (node < N_NODES)
            row_range[node] = make_int2(base + begl, base + ltmp[t]);
        int run = begl;
#pragma unroll
        for (int k = 0; k < 16; ++k) { u.c.wcur[k][t] = run; run += u.c.whist[k][t]; }
    }
    __syncthreads();
    // --- scatter pass: sorted (src, w) into LDS ---
    {
        int j = t;
        for (; j + 1024 < cnt; j += 2048) {
            int2 e0 = csr_bin[base + j];
            int2 e1 = csr_bin[base + j + 1024];
            int p0 = atomicAdd(&u.c.wcur[wv][e0.x & (PNODES - 1)], 1);
            int p1 = atomicAdd(&u.c.wcur[wv][e1.x & (PNODES - 1)], 1);
            sdata[p0] = make_int2(e0.x >> PBITS, e0.y);
            sdata[p1] = make_int2(e1.x >> PBITS, e1.y);
        }
        if (j < cnt) {
            int2 e0 = csr_bin[base + j];
            int p0 = atomicAdd(&u.c.wcur[wv][e0.x & (PNODES - 1)], 1);
            sdata[p0] = make_int2(e0.x >> PBITS, e0.y);
        }
    }
    __syncthreads();
    // --- coalesced writeback for spmm2 ---
    for (int i = t; i < cnt; i += 1024) csr_edge[base + i] = sdata[i];

    // --- spmm1 + bias/ReLU + gemm2, 64 node-groups x 16 lanes, 2 rounds ---
    int g = t >> 4, lane = t & 15;
#pragma unroll
    for (int round = 0; round < 2; ++round) {
        int nl = g + 64 * round;
        int node = b * PNODES + nl;
        if (node >= N_NODES) continue;
        int endl = ltmp[nl];
        int j = endl - ltot[nl];
        float4 accA = {0.f, 0.f, 0.f, 0.f}, accB = {0.f, 0.f, 0.f, 0.f};
        for (; j + 7 < endl; j += 8) {
            int2 e0 = sdata[j],     e1 = sdata[j + 1];
            int2 e2 = sdata[j + 2], e3 = sdata[j + 3];
            int2 e4 = sdata[j + 4], e5 = sdata[j + 5];
            int2 e6 = sdata[j + 6], e7 = sdata[j + 7];
            uint2 v0 = s1p2[(size_t)e0.x * 16 + lane];
            uint2 v1 = s1p2[(size_t)e1.x * 16 + lane];
            uint2 v2 = s1p2[(size_t)e2.x * 16 + lane];
            uint2 v3 = s1p2[(size_t)e3.x * 16 + lane];
            uint2 v4 = s1p2[(size_t)e4.x * 16 + lane];
            uint2 v5 = s1p2[(size_t)e5.x * 16 + lane];
            uint2 v6 = s1p2[(size_t)e6.x * 16 + lane];
            uint2 v7 = s1p2[(size_t)e7.x * 16 + lane];
            float w0 = __int_as_float(e0.y), w1 = __int_as_float(e1.y);
            float w2 = __int_as_float(e2.y), w3 = __int_as_float(e3.y);
            float w4 = __int_as_float(e4.y), w5 = __int_as_float(e5.y);
            float w6 = __int_as_float(e6.y), w7 = __int_as_float(e7.y);
            accA.x = fmaf(w0, __uint_as_float(v0.x << 16), accA.x);
            accA.y = fmaf(w0, __uint_as_float(v0.x & 0xFFFF0000u), accA.y);
            accA.z = fmaf(w0, __uint_as_float(v0.y << 16), accA.z);
            accA.w = fmaf(w0, __uint_as_float(v0.y & 0xFFFF0000u), accA.w);
            accB.x = fmaf(w1, __uint_as_float(v1.x << 16), accB.x);
            accB.y = fmaf(w1, __uint_as_float(v1.x & 0xFFFF0000u), accB.y);
            accB.z = fmaf(w1, __uint_as_float(v1.y << 16), accB.z);
            accB.w = fmaf(w1, __uint_as_float(v1.y & 0xFFFF0000u), accB.w);
            accA.x = fmaf(w2, __uint_as_float(v2.x << 16), accA.x);
            accA.y = fmaf(w2, __uint_as_float(v2.x & 0xFFFF0000u), accA.y);
            accA.z = fmaf(w2, __uint_as_float(v2.y << 16), accA.z);
            accA.w = fmaf(w2, __uint_as_float(v2.y & 0xFFFF0000u), accA.w);
            accB.x = fmaf(w3, __uint_as_float(v3.x << 16), accB.x);
            accB.y = fmaf(w3, __uint_as_float(v3.x & 0xFFFF0000u), accB.y);
            accB.z = fmaf(w3, __uint_as_float(v3.y << 16), accB.z);
            accB.w = fmaf(w3, __uint_as_float(v3.y & 0xFFFF0000u), accB.w);
            accA.x = fmaf(w4, __uint_as_float(v4.x << 16), accA.x);
            accA.y = fmaf(w4, __uint_as_float(v4.x & 0xFFFF0000u), accA.y);
            accA.z = fmaf(w4, __uint_as_float(v4.y << 16), accA.z);
            accA.w = fmaf(w4, __uint_as_float(v4.y & 0xFFFF0000u), accA.w);
            accB.x = fmaf(w5, __uint_as_float(v5.x << 16), accB.x);
            accB.y = fmaf(w5, __uint_as_float(v5.x & 0xFFFF0000u), accB.y);
            accB.z = fmaf(w5, __uint_as_float(v5.y << 16), accB.z);
            accB.w = fmaf(w5, __uint_as_float(v5.y & 0xFFFF0000u), accB.w);
            accA.x = fmaf(w6, __uint_as_float(v6.x << 16), accA.x);
            accA.y = fmaf(w6, __uint_as_float(v6.x & 0xFFFF0000u), accA.y);
            accA.z = fmaf(w6, __uint_as_float(v6.y << 16), accA.z);
            accA.w = fmaf(w6, __uint_as_float(v6.y & 0xFFFF0000u), accA.w);
            accB.x = fmaf(w7, __uint_as_float(v7.x << 16), accB.x);
            accB.y = fmaf(w7, __uint_as_float(v7.x & 0xFFFF0000u), accB.y);
            accB.z = fmaf(w7, __uint_as_float(v7.y << 16), accB.z);
            accB.w = fmaf(w7, __uint_as_float(v7.y & 0xFFFF0000u), accB.w);
        }
        for (; j < endl; ++j) {
            int2 e0 = sdata[j];
            uint2 v0 = s1p2[(size_t)e0.x * 16 + lane];
            float w0 = __int_as_float(e0.y);
            accA.x = fmaf(w0, __uint_as_float(v0.x << 16), accA.x);
            accA.y = fmaf(w0, __uint_as_float(v0.x & 0xFFFF0000u), accA.y);
            accA.z = fmaf(w0, __uint_as_float(v0.y << 16), accA.z);
            accA.w = fmaf(w0, __uint_as_float(v0.y & 0xFFFF0000u), accA.w);
        }
        float4 bb = *(const float4*)&b1s[4 * lane];
        float4 hv;
        hv.x = accA.x + accB.x + bb.x;
        hv.y = accA.y + accB.y + bb.y;
        hv.z = accA.z + accB.z + bb.z;
        hv.w = accA.w + accB.w + bb.w;
        hv.x = hv.x > 0.f ? hv.x : 0.f;
        hv.y = hv.y > 0.f ? hv.y : 0.f;
        hv.z = hv.z > 0.f ? hv.z : 0.f;
        hv.w = hv.w > 0.f ? hv.w : 0.f;
        // same-wave LDS park (lockstep within wave, no barrier needed)
        *(float4*)&u.hsh[g][4 * lane] = hv;
        float acc = 0.f;
#pragma unroll 16
        for (int k = 0; k < NHID; ++k)
            acc = fmaf(u.hsh[g][k], W2s[k * NCLASS + lane], acc);
        s2[(size_t)node * NCLASS + lane] = acc;
    }
}

// ======================= SpMM2 + bias + log_softmax ========================
// R13-exact: fp32 s2, 16 lanes/node, 8-edge unrolled.
__global__ void spmm2_csr_kernel(const int2* __restrict__ row_range,
                                 const int2* __restrict__ csr_edge,
                                 const float* __restrict__ s2,
                                 const float* __restrict__ b2,
                                 float* __restrict__ out) {
    int node = blockIdx.x * 16 + (threadIdx.x >> 4);
    if (node >= N_NODES) return;
    int c = threadIdx.x & 15;
    int2 rr = row_range[node];
    int beg = rr.x, end = rr.y;
    float acc0 = 0.f, acc1 = 0.f, acc2 = 0.f, acc3 = 0.f;
    int j = beg;
    for (; j + 7 < end; j += 8) {
        int2 e0 = csr_edge[j],     e1 = csr_edge[j + 1];
        int2 e2 = csr_edge[j + 2], e3 = csr_edge[j + 3];
        int2 e4 = csr_edge[j + 4], e5 = csr_edge[j + 5];
        int2 e6 = csr_edge[j + 6], e7 = csr_edge[j + 7];
        float g0 = s2[(size_t)e0.x * NCLASS + c];
        float g1 = s2[(size_t)e1.x * NCLASS + c];
        float g2 = s2[(size_t)e2.x * NCLASS + c];
        float g3 = s2[(size_t)e3.x * NCLASS + c];
        float g4 = s2[(size_t)e4.x * NCLASS + c];
        float g5 = s2[(size_t)e5.x * NCLASS + c];
        float g6 = s2[(size_t)e6.x * NCLASS + c];
        float g7 = s2[(size_t)e7.x * NCLASS + c];
        acc0 = fmaf(__int_as_float(e0.y), g0, acc0);
        acc1 = fmaf(__int_as_float(e1.y), g1, acc1);
        acc2 = fmaf(__int_as_float(e2.y), g2, acc2);
        acc3 = fmaf(__int_as_float(e3.y), g3, acc3);
        acc0 = fmaf(__int_as_float(e4.y), g4, acc0);
        acc1 = fmaf(__int_as_float(e5.y), g5, acc1);
        acc2 = fmaf(__int_as_float(e6.y), g6, acc2);
        acc3 = fmaf(__int_as_float(e7.y), g7, acc3);
    }
    for (; j + 3 < end; j += 4) {
        int2 e0 = csr_edge[j],     e1 = csr_edge[j + 1];
        int2 e2 = csr_edge[j + 2], e3 = csr_edge[j + 3];
        acc0 = fmaf(__int_as_float(e0.y), s2[(size_t)e0.x * NCLASS + c], acc0);
        acc1 = fmaf(__int_as_float(e1.y), s2[(size_t)e1.x * NCLASS + c], acc1);
        acc2 = fmaf(__int_as_float(e2.y), s2[(size_t)e2.x * NCLASS + c], acc2);
        acc3 = fmaf(__int_as_float(e3.y), s2[(size_t)e3.x * NCLASS + c], acc3);
    }
    for (; j < end; ++j) {
        int2 e0 = csr_edge[j];
        acc0 = fmaf(__int_as_float(e0.y), s2[(size_t)e0.x * NCLASS + c], acc0);
    }
    float v = (acc0 + acc1) + (acc2 + acc3) + b2[c];
    float mx = v;
    for (int off = 8; off; off >>= 1) mx = fmaxf(mx, __shfl_xor(mx, off, 16));
    float ss = expf(v - mx);
    for (int off = 8; off; off >>= 1) ss += __shfl_xor(ss, off, 16);
    out[(size_t)node * NCLASS + c] = v - mx - logf(ss);
}

// ======================= fallback path (R3 atomic version) =================

__global__ void zero_kernel(float* __restrict__ h, float* __restrict__ out) {
    int i = blockIdx.x * 256 + threadIdx.x;
    if (i < N_NODES * NHID) h[i] = 0.f;
    if (i < N_NODES * NCLASS) out[i] = 0.f;
}

__global__ void gemm1_kernel(const float* __restrict__ x,
                             const float* __restrict__ W1,
                             float* __restrict__ s1) {
    int node = blockIdx.x * 4 + (threadIdx.x >> 6);
    int col  = threadIdx.x & 63;
    if (node >= N_NODES) return;
    const float* xr = x + (size_t)node * NFEAT;
    float sum = 0.f;
#pragma unroll 8
    for (int k = 0; k < NFEAT; ++k)
        sum = fmaf(xr[k], W1[k * NHID + col], sum);
    s1[(size_t)node * NHID + col] = sum;
}

__global__ void spmm1_kernel(const int* __restrict__ src, const int* __restrict__ dst,
                             const float* __restrict__ w, const float* __restrict__ s1,
                             float* __restrict__ h) {
    int e = blockIdx.x * 4 + (threadIdx.x >> 6);
    if (e >= N_EDGES) return;
    int lane = threadIdx.x & 63;
    int s = min(max(src[e], 0), N_NODES - 1);
    int d = min(max(dst[e], 0), N_NODES - 1);
    float v = w[e] * s1[(size_t)s * NHID + lane];
    atomicAdd(&h[(size_t)d * NHID + lane], v);
}

__global__ void bias_relu_kernel(float* __restrict__ h, const float* __restrict__ b1) {
    int i = blockIdx.x * 256 + threadIdx.x;
    if (i >= N_NODES * NHID) return;
    float v = h[i] + b1[i & (NHID - 1)];
    h[i] = v > 0.f ? v : 0.f;
}

__global__ void gemm2_kernel(const float* __restrict__ h,
                             const float* __restrict__ W2,
                             float* __restrict__ s2) {
    int node = blockIdx.x * 16 + (threadIdx.x >> 4);
    int col  = threadIdx.x & 15;
    if (node >= N_NODES) return;
    const float* hr = h + (size_t)node * NHID;
    float sum = 0.f;
#pragma unroll 8
    for (int k = 0; k < NHID; ++k)
        sum = fmaf(hr[k], W2[k * NCLASS + col], sum);
    s2[(size_t)node * NCLASS + col] = sum;
}

__global__ void spmm2_kernel(const int* __restrict__ src, const int* __restrict__ dst,
                             const float* __restrict__ w, const float* __restrict__ s2,
                             float* __restrict__ out) {
    int e = blockIdx.x * 16 + (threadIdx.x >> 4);
    if (e >= N_EDGES) return;
    int lane = threadIdx.x & 15;
    int s = min(max(src[e], 0), N_NODES - 1);
    int d = min(max(dst[e], 0), N_NODES - 1);
    float v = w[e] * s2[(size_t)s * NCLASS + lane];
    atomicAdd(&out[(size_t)d * NCLASS + lane], v);
}

__global__ void logsoftmax_kernel(float* __restrict__ out, const float* __restrict__ b2) {
    int n = blockIdx.x * 256 + threadIdx.x;
    if (n >= N_NODES) return;
    float v[NCLASS];
    float mx = -INFINITY;
#pragma unroll
    for (int c = 0; c < NCLASS; ++c) {
        v[c] = out[(size_t)n * NCLASS + c] + b2[c];
        mx = fmaxf(mx, v[c]);
    }
    float ssum = 0.f;
#pragma unroll
    for (int c = 0; c < NCLASS; ++c) ssum += expf(v[c] - mx);
    float ls = mx + logf(ssum);
#pragma unroll
    for (int c = 0; c < NCLASS; ++c) out[(size_t)n * NCLASS + c] = v[c] - ls;
}

// ======================= launch ============================================

extern "C" void kernel_launch(void* const* d_in, const int* in_sizes, int n_in,
                              void* d_out, int out_size, void* d_ws, size_t ws_size,
                              hipStream_t stream) {
    if (n_in != 8) return;
    const int expected[8] = { N_NODES * NFEAT, NFEAT * NHID, NHID,
                              NHID * NCLASS, NCLASS, N_EDGES, N_EDGES, N_EDGES };
    for (int i = 0; i < 8; ++i)
        if (in_sizes[i] != expected[i]) return;
    if (out_size != N_NODES * NCLASS) return;

    const float* x  = (const float*)d_in[0];
    const float* W1 = (const float*)d_in[1];
    const float* b1 = (const float*)d_in[2];
    const float* W2 = (const float*)d_in[3];
    const float* b2 = (const float*)d_in[4];
    const int* edge_src = (const int*)d_in[5];
    const int* edge_dst = (const int*)d_in[6];
    const float* edge_w = (const float*)d_in[7];
    float* out = (float*)d_out;

    const size_t S1_ELTS = (size_t)N_NODES * NHID;          // 3.2M (ushorts)
    const size_t CAP_WORDS = (size_t)NBINS * BIN_CAP * 2;   // int2 region, words
    // layout (32-bit words) — fully DISJOINT (s1b live alongside csr_bin
    // inside sort_spmm1_fused):
    //   [0, CAP)          csr_bin    (16 MB)
    //   [CAP, 2CAP)       csr_edge   (16 MB)
    //   [2CAP, +2N)       row_range  (0.4 MB)
    //   [.., +512)        bin_cursor (391 ints + pad, keeps s1b 8B-aligned)
    //   [.., +S1/2)       s1b        (6.4 MB bf16)
    //   [.., +N*NCLASS)   s2         (3.2 MB fp32)
    const size_t NEW_WORDS = 2 * CAP_WORDS + 2 * (size_t)N_NODES + 512
                           + S1_ELTS / 2 + (size_t)N_NODES * NCLASS;
    if (ws_size >= NEW_WORDS * 4) {
        int2*  csr_bin    = (int2*)d_ws;
        int2*  csr_edge   = (int2*)((int*)d_ws + CAP_WORDS);
        int2*  row_range  = (int2*)((int*)d_ws + 2 * CAP_WORDS);
        int*   bin_cursor = (int*)d_ws + 2 * CAP_WORDS + 2 * (size_t)N_NODES;
        unsigned short* s1b =
            (unsigned short*)((int*)d_ws + 2 * CAP_WORDS + 2 * (size_t)N_NODES + 512);
        float* s2 = (float*)d_ws + 2 * CAP_WORDS + 2 * (size_t)N_NODES + 512
                  + S1_ELTS / 2;

        hipMemsetAsync(bin_cursor, 0, NBINS * sizeof(int), stream);
        bin_scatter_kernel<<<K3_BLOCKS, K3_THREADS, 0, stream>>>(
            edge_src, edge_dst, edge_w, bin_cursor, csr_bin);
        gemm1_tiled<<<(N_NODES + 63) / 64, 256, 0, stream>>>(x, W1, s1b);
        sort_spmm1_fused<<<NBINS, 1024, 0, stream>>>(
            bin_cursor, csr_bin, csr_edge, row_range,
            (const uint2*)s1b, b1, W2, s2);
        spmm2_csr_kernel<<<(N_NODES + 15) / 16, 256, 0, stream>>>(
            row_range, csr_edge, s2, b2, out);
        return;
    }

    // --- fallback: proven atomic path (25.6 MB ws) ---
    if (ws_size < 2 * S1_ELTS * sizeof(float)) return;
    float* s1 = (float*)d_ws;
    float* h  = s1 + S1_ELTS;
    float* s2 = s1;
    zero_kernel<<<(N_NODES * NHID + 255) / 256, 256, 0, stream>>>(h, out);
    gemm1_kernel<<<(N_NODES + 3) / 4, 256, 0, stream>>>(x, W1, s1);
    spmm1_kernel<<<(N_EDGES + 3) / 4, 256, 0, stream>>>(edge_src, edge_dst, edge_w, s1, h);
    bias_relu_kernel<<<(N_NODES * NHID + 255) / 256, 256, 0, stream>>>(h, b1);
    gemm2_kernel<<<(N_NODES + 15) / 16, 256, 0, stream>>>(h, W2, s2);
    spmm2_kernel<<<(N_EDGES + 15) / 16, 256, 0, stream>>>(edge_src, edge_dst, edge_w, s2, out);
    logsoftmax_kernel<<<(N_NODES + 255) / 256, 256, 0, stream>>>(out, b2);
}

// Round 11
// 205.880 us; speedup vs baseline: 1.1887x; 1.0153x over previous
//
#include <hip/hip_runtime.h>
#include <math.h>

#define N_NODES 50000
#define N_EDGES 1600000
#define NFEAT 256
#define NHID 64
#define NCLASS 16

#define PBITS 7
#define PNODES 128                       // nodes per bin (R5-proven geometry)
#define NBINS ((N_NODES + PNODES - 1) / PNODES)   // 391
#define BIN_CAP 5120                     // mean 4092, sigma 64 -> +16 sigma
#define K3_CHUNK 4096
#define K3_THREADS 512
#define K3_PER_T 8                       // 4096 / 512
#define K3_BLOCKS ((N_EDGES + K3_CHUNK - 1) / K3_CHUNK)  // 391

__device__ inline unsigned short f2bf(float f) {     // RNE f32 -> bf16
    unsigned u = __float_as_uint(f);
    return (unsigned short)((u + 0x7FFFu + ((u >> 16) & 1u)) >> 16);
}

// ======================= bin scatter (counting sort, pass 1) ===============
// R10-proven 512-thread version. bin_cursor is COUNT-ONLY (zeroed by
// gemm1_tiled block 0, which runs in the PRECEDING dispatch); slot base is
// b*BIN_CAP.
__global__ __launch_bounds__(512) void bin_scatter_kernel(
        const int* __restrict__ src, const int* __restrict__ dst,
        const float* __restrict__ w, int* __restrict__ bin_cursor,
        int2* __restrict__ csr_bin) {
    __shared__ int2 sdata[K3_CHUNK];                 // 32 KB
    __shared__ unsigned short sbinid[K3_CHUNK];      // 8 KB
    __shared__ int swhist[4][NBINS];                 // 6.1 KB (wave-pair priv)
    __shared__ int swcur[4][NBINS];                  // 6.1 KB
    __shared__ int stot[NBINS];
    __shared__ int lscan[NBINS];
    __shared__ int sbase[NBINS];
    __shared__ int stmp[512];
    int t = threadIdx.x;
    int wv = t >> 7;                                 // 4 hist copies, 2 waves ea
    int base_e = blockIdx.x * K3_CHUNK;

    for (int b = t; b < NBINS; b += K3_THREADS) {
        swhist[0][b] = 0; swhist[1][b] = 0; swhist[2][b] = 0; swhist[3][b] = 0;
    }
    __syncthreads();

    int2 myedge[K3_PER_T];
    short mybin[K3_PER_T];
#pragma unroll
    for (int k = 0; k < K3_PER_T; ++k) {
        int e = base_e + t + k * K3_THREADS;
        if (e < N_EDGES) {
            int d = min(max(dst[e], 0), N_NODES - 1);
            int s = min(max(src[e], 0), N_NODES - 1);
            int b = d >> PBITS;
            mybin[k] = (short)b;
            myedge[k] = make_int2((s << PBITS) | (d & (PNODES - 1)),
                                  __float_as_int(w[e]));
            atomicAdd(&swhist[wv][b], 1);
        } else mybin[k] = -1;
    }
    __syncthreads();
    {
        int v = 0;
        if (t < NBINS) {
            v = swhist[0][t] + swhist[1][t] + swhist[2][t] + swhist[3][t];
            stot[t] = v;
        }
        stmp[t] = v;
    }
    __syncthreads();
    for (int off = 1; off < 512; off <<= 1) {
        int v0 = (t >= off) ? stmp[t - off] : 0;
        __syncthreads();
        stmp[t] += v0;
        __syncthreads();
    }
    if (t < NBINS) {
        lscan[t] = stmp[t] - stot[t];
        int c = stot[t];
        // count-only cursor: global slot base is b*BIN_CAP + prior count
        if (c > 0) sbase[t] = t * BIN_CAP + atomicAdd(&bin_cursor[t], c);
        int run = lscan[t];
        swcur[0][t] = run; run += swhist[0][t];
        swcur[1][t] = run; run += swhist[1][t];
        swcur[2][t] = run; run += swhist[2][t];
        swcur[3][t] = run;
    }
    __syncthreads();
#pragma unroll
    for (int k = 0; k < K3_PER_T; ++k) {
        int b = mybin[k];
        if (b >= 0) {
            int p = atomicAdd(&swcur[wv][b], 1);
            sdata[p] = myedge[k];
            sbinid[p] = (unsigned short)b;
        }
    }
    __syncthreads();
    int cnt = min(N_EDGES - base_e, K3_CHUNK);
#pragma unroll
    for (int k = 0; k < K3_PER_T; ++k) {
        int p = t + k * K3_THREADS;
        if (p < cnt) {
            int b = sbinid[p];
            int idx = sbase[b] + (p - lscan[b]);
            idx = min(idx, (b + 1) * BIN_CAP - 1);   // overflow-safe (no fault)
            csr_bin[idx] = sdata[p];
        }
    }
}

// ======================= dense GEMM 1 (R13-proven) =========================
// R11: launched FIRST; block 0 zeroes bin_cursor (replaces the memset
// dispatch -> one fewer launch gap). gemm1 is independent of the CSR build,
// and the stream serializes this kernel before bin_scatter.

#define BK 16
__global__ __launch_bounds__(256) void gemm1_tiled(const float* __restrict__ x,
                                                   const float* __restrict__ W1,
                                                   unsigned short* __restrict__ s1b,
                                                   int* __restrict__ bin_cursor) {
    __shared__ float xT[BK][68];
    __shared__ float wt[BK][64];
    int t = threadIdx.x;
    if (blockIdx.x == 0)
        for (int i = t; i < NBINS; i += 256) bin_cursor[i] = 0;
    int n_base = blockIdx.x * 64;
    int cq = t & 15;
    int nq = t >> 4;
    int ld_node = t >> 2;
    int ld_k4   = (t & 3) * 4;
    int gnode = min(n_base + ld_node, N_NODES - 1);
    const float* xrow = x + (size_t)gnode * NFEAT;
    int wr = t >> 4;
    int wc = (t & 15) * 4;
    float acc[4][4] = {};
    for (int k0 = 0; k0 < NFEAT; k0 += BK) {
        float4 xv = *(const float4*)(xrow + k0 + ld_k4);
        xT[ld_k4 + 0][ld_node] = xv.x;
        xT[ld_k4 + 1][ld_node] = xv.y;
        xT[ld_k4 + 2][ld_node] = xv.z;
        xT[ld_k4 + 3][ld_node] = xv.w;
        *(float4*)&wt[wr][wc] = *(const float4*)(W1 + (size_t)(k0 + wr) * NHID + wc);
        __syncthreads();
#pragma unroll
        for (int k = 0; k < BK; ++k) {
            float4 a = *(const float4*)&xT[k][4 * nq];
            float4 bb = *(const float4*)&wt[k][4 * cq];
            acc[0][0] = fmaf(a.x, bb.x, acc[0][0]);
            acc[0][1] = fmaf(a.x, bb.y, acc[0][1]);
            acc[0][2] = fmaf(a.x, bb.z, acc[0][2]);
            acc[0][3] = fmaf(a.x, bb.w, acc[0][3]);
            acc[1][0] = fmaf(a.y, bb.x, acc[1][0]);
            acc[1][1] = fmaf(a.y, bb.y, acc[1][1]);
            acc[1][2] = fmaf(a.y, bb.z, acc[1][2]);
            acc[1][3] = fmaf(a.y, bb.w, acc[1][3]);
            acc[2][0] = fmaf(a.z, bb.x, acc[2][0]);
            acc[2][1] = fmaf(a.z, bb.y, acc[2][1]);
            acc[2][2] = fmaf(a.z, bb.z, acc[2][2]);
            acc[2][3] = fmaf(a.z, bb.w, acc[2][3]);
            acc[3][0] = fmaf(a.w, bb.x, acc[3][0]);
            acc[3][1] = fmaf(a.w, bb.y, acc[3][1]);
            acc[3][2] = fmaf(a.w, bb.z, acc[3][2]);
            acc[3][3] = fmaf(a.w, bb.w, acc[3][3]);
        }
        __syncthreads();
    }
#pragma unroll
    for (int i = 0; i < 4; ++i) {
        int n = n_base + 4 * nq + i;
        if (n < N_NODES) {
            ushort4 o;
            o.x = f2bf(acc[i][0]); o.y = f2bf(acc[i][1]);
            o.z = f2bf(acc[i][2]); o.w = f2bf(acc[i][3]);
            *(ushort4*)&s1b[(size_t)n * NHID + 4 * cq] = o;
        }
    }
}

// ============ fused per-bin sort + SpMM1 + bias/ReLU + GEMM2 ===============
// R5-proven version, verbatim (45 us measured, best known).
__global__ __launch_bounds__(1024, 4) void sort_spmm1_fused(
        const int* __restrict__ bin_cursor, const int2* __restrict__ csr_bin,
        int2* __restrict__ csr_edge, int2* __restrict__ row_range,
        const uint2* __restrict__ s1p2, const float* __restrict__ b1,
        const float* __restrict__ W2, float* __restrict__ s2) {
    __shared__ int2 sdata[BIN_CAP];                  // 40 KB sorted edges
    __shared__ union {
        struct { int whist[16][PNODES]; int wcur[16][PNODES]; } c;  // 16 KB
        float hsh[64][64];                                          // 16 KB
    } u;
    __shared__ int ltot[PNODES];
    __shared__ int ltmp[PNODES];
    __shared__ float W2s[NHID * NCLASS];             // 4 KB
    __shared__ float b1s[NHID];
    int t = threadIdx.x;
    int wv = t >> 6;                                 // 16 waves
    int b = blockIdx.x;
    int base = b * BIN_CAP;
    int cnt = min(bin_cursor[b], BIN_CAP);

    for (int i = t; i < 16 * PNODES; i += 1024) ((int*)u.c.whist)[i] = 0;
    if (t < NHID * NCLASS) W2s[t] = W2[t];
    if (t < NHID) b1s[t] = b1[t];
    __syncthreads();

    // --- hist pass ---
    {
        int j = t;
        for (; j + 1024 < cnt; j += 2048) {
            int2 e0 = csr_bin[base + j];
            int2 e1 = csr_bin[base + j + 1024];
            atomicAdd(&u.c.whist[wv][e0.x & (PNODES - 1)], 1);
            atomicAdd(&u.c.whist[wv][e1.x & (PNODES - 1)], 1);
        }
        if (j < cnt)
            atomicAdd(&u.c.whist[wv][csr_bin[base + j].x & (PNODES - 1)], 1);
    }
    __syncthreads();
    if (t < PNODES) {
        int v = 0;
#pragma unroll
        for (int k = 0; k < 16; ++k) v += u.c.whist[k][t];
        ltot[t] = v; ltmp[t] = v;
    }
    __syncthreads();
    for (int off = 1; off < PNODES; off <<= 1) {
        int a = 0;
        if (t < PNODES && t >= off) a = ltmp[t - off];
        __syncthreads();
        if (t < PNODES) ltmp[t] += a;
        __syncthreads();
    }
    if (t < PNODES) {
        int begl = ltmp[t] - ltot[t];                // local (0-based in bin)
        int node = b * PNODES + t;
        if (node < N_NODES)
            row_range[node] = make_int2(base + begl, base + ltmp[t]);
        int run = begl;
#pragma unroll
        for (int k = 0; k < 16; ++k) { u.c.wcur[k][t] = run; run += u.c.whist[k][t]; }
    }
    __syncthreads();
    // --- scatter pass: sorted (src, w) into LDS ---
    {
        int j = t;
        for (; j + 1024 < cnt; j += 2048) {
            int2 e0 = csr_bin[base + j];
            int2 e1 = csr_bin[base + j + 1024];
            int p0 = atomicAdd(&u.c.wcur[wv][e0.x & (PNODES - 1)], 1);
            int p1 = atomicAdd(&u.c.wcur[wv][e1.x & (PNODES - 1)], 1);
            sdata[p0] = make_int2(e0.x >> PBITS, e0.y);
            sdata[p1] = make_int2(e1.x >> PBITS, e1.y);
        }
        if (j < cnt) {
            int2 e0 = csr_bin[base + j];
            int p0 = atomicAdd(&u.c.wcur[wv][e0.x & (PNODES - 1)], 1);
            sdata[p0] = make_int2(e0.x >> PBITS, e0.y);
        }
    }
    __syncthreads();
    // --- coalesced writeback for spmm2 ---
    for (int i = t; i < cnt; i += 1024) csr_edge[base + i] = sdata[i];

    // --- spmm1 + bias/ReLU + gemm2, 64 node-groups x 16 lanes, 2 rounds ---
    int g = t >> 4, lane = t & 15;
#pragma unroll
    for (int round = 0; round < 2; ++round) {
        int nl = g + 64 * round;
        int node = b * PNODES + nl;
        if (node >= N_NODES) continue;
        int endl = ltmp[nl];
        int j = endl - ltot[nl];
        float4 accA = {0.f, 0.f, 0.f, 0.f}, accB = {0.f, 0.f, 0.f, 0.f};
        for (; j + 7 < endl; j += 8) {
            int2 e0 = sdata[j],     e1 = sdata[j + 1];
            int2 e2 = sdata[j + 2], e3 = sdata[j + 3];
            int2 e4 = sdata[j + 4], e5 = sdata[j + 5];
            int2 e6 = sdata[j + 6], e7 = sdata[j + 7];
            uint2 v0 = s1p2[(size_t)e0.x * 16 + lane];
            uint2 v1 = s1p2[(size_t)e1.x * 16 + lane];
            uint2 v2 = s1p2[(size_t)e2.x * 16 + lane];
            uint2 v3 = s1p2[(size_t)e3.x * 16 + lane];
            uint2 v4 = s1p2[(size_t)e4.x * 16 + lane];
            uint2 v5 = s1p2[(size_t)e5.x * 16 + lane];
            uint2 v6 = s1p2[(size_t)e6.x * 16 + lane];
            uint2 v7 = s1p2[(size_t)e7.x * 16 + lane];
            float w0 = __int_as_float(e0.y), w1 = __int_as_float(e1.y);
            float w2 = __int_as_float(e2.y), w3 = __int_as_float(e3.y);
            float w4 = __int_as_float(e4.y), w5 = __int_as_float(e5.y);
            float w6 = __int_as_float(e6.y), w7 = __int_as_float(e7.y);
            accA.x = fmaf(w0, __uint_as_float(v0.x << 16), accA.x);
            accA.y = fmaf(w0, __uint_as_float(v0.x & 0xFFFF0000u), accA.y);
            accA.z = fmaf(w0, __uint_as_float(v0.y << 16), accA.z);
            accA.w = fmaf(w0, __uint_as_float(v0.y & 0xFFFF0000u), accA.w);
            accB.x = fmaf(w1, __uint_as_float(v1.x << 16), accB.x);
            accB.y = fmaf(w1, __uint_as_float(v1.x & 0xFFFF0000u), accB.y);
            accB.z = fmaf(w1, __uint_as_float(v1.y << 16), accB.z);
            accB.w = fmaf(w1, __uint_as_float(v1.y & 0xFFFF0000u), accB.w);
            accA.x = fmaf(w2, __uint_as_float(v2.x << 16), accA.x);
            accA.y = fmaf(w2, __uint_as_float(v2.x & 0xFFFF0000u), accA.y);
            accA.z = fmaf(w2, __uint_as_float(v2.y << 16), accA.z);
            accA.w = fmaf(w2, __uint_as_float(v2.y & 0xFFFF0000u), accA.w);
            accB.x = fmaf(w3, __uint_as_float(v3.x << 16), accB.x);
            accB.y = fmaf(w3, __uint_as_float(v3.x & 0xFFFF0000u), accB.y);
            accB.z = fmaf(w3, __uint_as_float(v3.y << 16), accB.z);
            accB.w = fmaf(w3, __uint_as_float(v3.y & 0xFFFF0000u), accB.w);
            accA.x = fmaf(w4, __uint_as_float(v4.x << 16), accA.x);
            accA.y = fmaf(w4, __uint_as_float(v4.x & 0xFFFF0000u), accA.y);
            accA.z = fmaf(w4, __uint_as_float(v4.y << 16), accA.z);
            accA.w = fmaf(w4, __uint_as_float(v4.y & 0xFFFF0000u), accA.w);
            accB.x = fmaf(w5, __uint_as_float(v5.x << 16), accB.x);
            accB.y = fmaf(w5, __uint_as_float(v5.x & 0xFFFF0000u), accB.y);
            accB.z = fmaf(w5, __uint_as_float(v5.y << 16), accB.z);
            accB.w = fmaf(w5, __uint_as_float(v5.y & 0xFFFF0000u), accB.w);
            accA.x = fmaf(w6, __uint_as_float(v6.x << 16), accA.x);
            accA.y = fmaf(w6, __uint_as_float(v6.x & 0xFFFF0000u), accA.y);
            accA.z = fmaf(w6, __uint_as_float(v6.y << 16), accA.z);
            accA.w = fmaf(w6, __uint_as_float(v6.y & 0xFFFF0000u), accA.w);
            accB.x = fmaf(w7, __uint_as_float(v7.x << 16), accB.x);
            accB.y = fmaf(w7, __uint_as_float(v7.x & 0xFFFF0000u), accB.y);
            accB.z = fmaf(w7, __uint_as_float(v7.y << 16), accB.z);
            accB.w = fmaf(w7, __uint_as_float(v7.y & 0xFFFF0000u), accB.w);
        }
        for (; j < endl; ++j) {
            int2 e0 = sdata[j];
            uint2 v0 = s1p2[(size_t)e0.x * 16 + lane];
            float w0 = __int_as_float(e0.y);
            accA.x = fmaf(w0, __uint_as_float(v0.x << 16), accA.x);
            accA.y = fmaf(w0, __uint_as_float(v0.x & 0xFFFF0000u), accA.y);
            accA.z = fmaf(w0, __uint_as_float(v0.y << 16), accA.z);
            accA.w = fmaf(w0, __uint_as_float(v0.y & 0xFFFF0000u), accA.w);
        }
        float4 bb = *(const float4*)&b1s[4 * lane];
        float4 hv;
        hv.x = accA.x + accB.x + bb.x;
        hv.y = accA.y + accB.y + bb.y;
        hv.z = accA.z + accB.z + bb.z;
        hv.w = accA.w + accB.w + bb.w;
        hv.x = hv.x > 0.f ? hv.x : 0.f;
        hv.y = hv.y > 0.f ? hv.y : 0.f;
        hv.z = hv.z > 0.f ? hv.z : 0.f;
        hv.w = hv.w > 0.f ? hv.w : 0.f;
        // same-wave LDS park (lockstep within wave, no barrier needed)
        *(float4*)&u.hsh[g][4 * lane] = hv;
        float acc = 0.f;
#pragma unroll 16
        for (int k = 0; k < NHID; ++k)
            acc = fmaf(u.hsh[g][k], W2s[k * NCLASS + lane], acc);
        s2[(size_t)node * NCLASS + lane] = acc;
    }
}

// ======================= SpMM2 + bias + log_softmax ========================
// R13-exact: fp32 s2, 16 lanes/node, 8-edge unrolled.
__global__ void spmm2_csr_kernel(const int2* __restrict__ row_range,
                                 const int2* __restrict__ csr_edge,
                                 const float* __restrict__ s2,
                                 const float* __restrict__ b2,
                                 float* __restrict__ out) {
    int node = blockIdx.x * 16 + (threadIdx.x >> 4);
    if (node >= N_NODES) return;
    int c = threadIdx.x & 15;
    int2 rr = row_range[node];
    int beg = rr.x, end = rr.y;
    float acc0 = 0.f, acc1 = 0.f, acc2 = 0.f, acc3 = 0.f;
    int j = beg;
    for (; j + 7 < end; j += 8) {
        int2 e0 = csr_edge[j],     e1 = csr_edge[j + 1];
        int2 e2 = csr_edge[j + 2], e3 = csr_edge[j + 3];
        int2 e4 = csr_edge[j + 4], e5 = csr_edge[j + 5];
        int2 e6 = csr_edge[j + 6], e7 = csr_edge[j + 7];
        float g0 = s2[(size_t)e0.x * NCLASS + c];
        float g1 = s2[(size_t)e1.x * NCLASS + c];
        float g2 = s2[(size_t)e2.x * NCLASS + c];
        float g3 = s2[(size_t)e3.x * NCLASS + c];
        float g4 = s2[(size_t)e4.x * NCLASS + c];
        float g5 = s2[(size_t)e5.x * NCLASS + c];
        float g6 = s2[(size_t)e6.x * NCLASS + c];
        float g7 = s2[(size_t)e7.x * NCLASS + c];
        acc0 = fmaf(__int_as_float(e0.y), g0, acc0);
        acc1 = fmaf(__int_as_float(e1.y), g1, acc1);
        acc2 = fmaf(__int_as_float(e2.y), g2, acc2);
        acc3 = fmaf(__int_as_float(e3.y), g3, acc3);
        acc0 = fmaf(__int_as_float(e4.y), g4, acc0);
        acc1 = fmaf(__int_as_float(e5.y), g5, acc1);
        acc2 = fmaf(__int_as_float(e6.y), g6, acc2);
        acc3 = fmaf(__int_as_float(e7.y), g7, acc3);
    }
    for (; j + 3 < end; j += 4) {
        int2 e0 = csr_edge[j],     e1 = csr_edge[j + 1];
        int2 e2 = csr_edge[j + 2], e3 = csr_edge[j + 3];
        acc0 = fmaf(__int_as_float(e0.y), s2[(size_t)e0.x * NCLASS + c], acc0);
        acc1 = fmaf(__int_as_float(e1.y), s2[(size_t)e1.x * NCLASS + c], acc1);
        acc2 = fmaf(__int_as_float(e2.y), s2[(size_t)e2.x * NCLASS + c], acc2);
        acc3 = fmaf(__int_as_float(e3.y), s2[(size_t)e3.x * NCLASS + c], acc3);
    }
    for (; j < end; ++j) {
        int2 e0 = csr_edge[j];
        acc0 = fmaf(__int_as_float(e0.y), s2[(size_t)e0.x * NCLASS + c], acc0);
    }
    float v = (acc0 + acc1) + (acc2 + acc3) + b2[c];
    float mx = v;
    for (int off = 8; off; off >>= 1) mx = fmaxf(mx, __shfl_xor(mx, off, 16));
    float ss = expf(v - mx);
    for (int off = 8; off; off >>= 1) ss += __shfl_xor(ss, off, 16);
    out[(size_t)node * NCLASS + c] = v - mx - logf(ss);
}

// ======================= fallback path (R3 atomic version) =================

__global__ void zero_kernel(float* __restrict__ h, float* __restrict__ out) {
    int i = blockIdx.x * 256 + threadIdx.x;
    if (i < N_NODES * NHID) h[i] = 0.f;
    if (i < N_NODES * NCLASS) out[i] = 0.f;
}

__global__ void gemm1_kernel(const float* __restrict__ x,
                             const float* __restrict__ W1,
                             float* __restrict__ s1) {
    int node = blockIdx.x * 4 + (threadIdx.x >> 6);
    int col  = threadIdx.x & 63;
    if (node >= N_NODES) return;
    const float* xr = x + (size_t)node * NFEAT;
    float sum = 0.f;
#pragma unroll 8
    for (int k = 0; k < NFEAT; ++k)
        sum = fmaf(xr[k], W1[k * NHID + col], sum);
    s1[(size_t)node * NHID + col] = sum;
}

__global__ void spmm1_kernel(const int* __restrict__ src, const int* __restrict__ dst,
                             const float* __restrict__ w, const float* __restrict__ s1,
                             float* __restrict__ h) {
    int e = blockIdx.x * 4 + (threadIdx.x >> 6);
    if (e >= N_EDGES) return;
    int lane = threadIdx.x & 63;
    int s = min(max(src[e], 0), N_NODES - 1);
    int d = min(max(dst[e], 0), N_NODES - 1);
    float v = w[e] * s1[(size_t)s * NHID + lane];
    atomicAdd(&h[(size_t)d * NHID + lane], v);
}

__global__ void bias_relu_kernel(float* __restrict__ h, const float* __restrict__ b1) {
    int i = blockIdx.x * 256 + threadIdx.x;
    if (i >= N_NODES * NHID) return;
    float v = h[i] + b1[i & (NHID - 1)];
    h[i] = v > 0.f ? v : 0.f;
}

__global__ void gemm2_kernel(const float* __restrict__ h,
                             const float* __restrict__ W2,
                             float* __restrict__ s2) {
    int node = blockIdx.x * 16 + (threadIdx.x >> 4);
    int col  = threadIdx.x & 15;
    if (node >= N_NODES) return;
    const float* hr = h + (size_t)node * NHID;
    float sum = 0.f;
#pragma unroll 8
    for (int k = 0; k < NHID; ++k)
        sum = fmaf(hr[k], W2[k * NCLASS + col], sum);
    s2[(size_t)node * NCLASS + col] = sum;
}

__global__ void spmm2_kernel(const int* __restrict__ src, const int* __restrict__ dst,
                             const float* __restrict__ w, const float* __restrict__ s2,
                             float* __restrict__ out) {
    int e = blockIdx.x * 16 + (threadIdx.x >> 4);
    if (e >= N_EDGES) return;
    int lane = threadIdx.x & 15;
    int s = min(max(src[e], 0), N_NODES - 1);
    int d = min(max(dst[e], 0), N_NODES - 1);
    float v = w[e] * s2[(size_t)s * NCLASS + lane];
    atomicAdd(&out[(size_t)d * NCLASS + lane], v);
}

__global__ void logsoftmax_kernel(float* __restrict__ out, const float* __restrict__ b2) {
    int n = blockIdx.x * 256 + threadIdx.x;
    if (n >= N_NODES) return;
    float v[NCLASS];
    float mx = -INFINITY;
#pragma unroll
    for (int c = 0; c < NCLASS; ++c) {
        v[c] = out[(size_t)n * NCLASS + c] + b2[c];
        mx = fmaxf(mx, v[c]);
    }
    float ssum = 0.f;
#pragma unroll
    for (int c = 0; c < NCLASS; ++c) ssum += expf(v[c] - mx);
    float ls = mx + logf(ssum);
#pragma unroll
    for (int c = 0; c < NCLASS; ++c) out[(size_t)n * NCLASS + c] = v[c] - ls;
}

// ======================= launch ============================================

extern "C" void kernel_launch(void* const* d_in, const int* in_sizes, int n_in,
                              void* d_out, int out_size, void* d_ws, size_t ws_size,
                              hipStream_t stream) {
    if (n_in != 8) return;
    const int expected[8] = { N_NODES * NFEAT, NFEAT * NHID, NHID,
                              NHID * NCLASS, NCLASS, N_EDGES, N_EDGES, N_EDGES };
    for (int i = 0; i < 8; ++i)
        if (in_sizes[i] != expected[i]) return;
    if (out_size != N_NODES * NCLASS) return;

    const float* x  = (const float*)d_in[0];
    const float* W1 = (const float*)d_in[1];
    const float* b1 = (const float*)d_in[2];
    const float* W2 = (const float*)d_in[3];
    const float* b2 = (const float*)d_in[4];
    const int* edge_src = (const int*)d_in[5];
    const int* edge_dst = (const int*)d_in[6];
    const float* edge_w = (const float*)d_in[7];
    float* out = (float*)d_out;

    const size_t S1_ELTS = (size_t)N_NODES * NHID;          // 3.2M (ushorts)
    const size_t CAP_WORDS = (size_t)NBINS * BIN_CAP * 2;   // int2 region, words
    // layout (32-bit words) — fully DISJOINT (s1b live alongside csr_bin
    // inside sort_spmm1_fused):
    //   [0, CAP)          csr_bin    (16 MB)
    //   [CAP, 2CAP)       csr_edge   (16 MB)
    //   [2CAP, +2N)       row_range  (0.4 MB)
    //   [.., +512)        bin_cursor (391 ints + pad, keeps s1b 8B-aligned)
    //   [.., +S1/2)       s1b        (6.4 MB bf16)
    //   [.., +N*NCLASS)   s2         (3.2 MB fp32)
    const size_t NEW_WORDS = 2 * CAP_WORDS + 2 * (size_t)N_NODES + 512
                           + S1_ELTS / 2 + (size_t)N_NODES * NCLASS;
    if (ws_size >= NEW_WORDS * 4) {
        int2*  csr_bin    = (int2*)d_ws;
        int2*  csr_edge   = (int2*)((int*)d_ws + CAP_WORDS);
        int2*  row_range  = (int2*)((int*)d_ws + 2 * CAP_WORDS);
        int*   bin_cursor = (int*)d_ws + 2 * CAP_WORDS + 2 * (size_t)N_NODES;
        unsigned short* s1b =
            (unsigned short*)((int*)d_ws + 2 * CAP_WORDS + 2 * (size_t)N_NODES + 512);
        float* s2 = (float*)d_ws + 2 * CAP_WORDS + 2 * (size_t)N_NODES + 512
                  + S1_ELTS / 2;

        // gemm1 first: its block 0 zeroes bin_cursor (replaces memset dispatch)
        gemm1_tiled<<<(N_NODES + 63) / 64, 256, 0, stream>>>(x, W1, s1b, bin_cursor);
        bin_scatter_kernel<<<K3_BLOCKS, K3_THREADS, 0, stream>>>(
            edge_src, edge_dst, edge_w, bin_cursor, csr_bin);
        sort_spmm1_fused<<<NBINS, 1024, 0, stream>>>(
            bin_cursor, csr_bin, csr_edge, row_range,
            (const uint2*)s1b, b1, W2, s2);
        spmm2_csr_kernel<<<(N_NODES + 15) / 16, 256, 0, stream>>>(
            row_range, csr_edge, s2, b2, out);
        return;
    }

    // --- fallback: proven atomic path (25.6 MB ws) ---
    if (ws_size < 2 * S1_ELTS * sizeof(float)) return;
    float* s1 = (float*)d_ws;
    float* h  = s1 + S1_ELTS;
    float* s2 = s1;
    zero_kernel<<<(N_NODES * NHID + 255) / 256, 256, 0, stream>>>(h, out);
    gemm1_kernel<<<(N_NODES + 3) / 4, 256, 0, stream>>>(x, W1, s1);
    spmm1_kernel<<<(N_EDGES + 3) / 4, 256, 0, stream>>>(edge_src, edge_dst, edge_w, s1, h);
    bias_relu_kernel<<<(N_NODES * NHID + 255) / 256, 256, 0, stream>>>(h, b1);
    gemm2_kernel<<<(N_NODES + 15) / 16, 256, 0, stream>>>(h, W2, s2);
    spmm2_kernel<<<(N_EDGES + 15) / 16, 256, 0, stream>>>(edge_src, edge_dst, edge_w, s2, out);
    logsoftmax_kernel<<<(N_NODES + 255) / 256, 256, 0, stream>>>(out, b2);
}

// Round 12
// 205.424 us; speedup vs baseline: 1.1913x; 1.0022x over previous
//
#include <hip/hip_runtime.h>
#include <math.h>

#define N_NODES 50000
#define N_EDGES 1600000
#define NFEAT 256
#define NHID 64
#define NCLASS 16

#define PBITS 7
#define PNODES 128                       // nodes per bin (R5-proven geometry)
#define NBINS ((N_NODES + PNODES - 1) / PNODES)   // 391
#define BIN_CAP 5120                     // mean 4092, sigma 64 -> +16 sigma
#define K3_CHUNK 4096
#define K3_THREADS 512
#define K3_PER_T 8                       // 4096 / 512
#define K3_BLOCKS ((N_EDGES + K3_CHUNK - 1) / K3_CHUNK)  // 391
#define S_PER_T 5                        // ceil(BIN_CAP / 1024)

__device__ inline unsigned short f2bf(float f) {     // RNE f32 -> bf16
    unsigned u = __float_as_uint(f);
    return (unsigned short)((u + 0x7FFFu + ((u >> 16) & 1u)) >> 16);
}

// ======================= bin scatter (counting sort, pass 1) ===============
// R10-proven 512-thread version. bin_cursor is COUNT-ONLY (zeroed by
// gemm1_tiled block 0, which runs in the PRECEDING dispatch); slot base is
// b*BIN_CAP.
__global__ __launch_bounds__(512) void bin_scatter_kernel(
        const int* __restrict__ src, const int* __restrict__ dst,
        const float* __restrict__ w, int* __restrict__ bin_cursor,
        int2* __restrict__ csr_bin) {
    __shared__ int2 sdata[K3_CHUNK];                 // 32 KB
    __shared__ unsigned short sbinid[K3_CHUNK];      // 8 KB
    __shared__ int swhist[4][NBINS];                 // 6.1 KB (wave-pair priv)
    __shared__ int swcur[4][NBINS];                  // 6.1 KB
    __shared__ int stot[NBINS];
    __shared__ int lscan[NBINS];
    __shared__ int sbase[NBINS];
    __shared__ int stmp[512];
    int t = threadIdx.x;
    int wv = t >> 7;                                 // 4 hist copies, 2 waves ea
    int base_e = blockIdx.x * K3_CHUNK;

    for (int b = t; b < NBINS; b += K3_THREADS) {
        swhist[0][b] = 0; swhist[1][b] = 0; swhist[2][b] = 0; swhist[3][b] = 0;
    }
    __syncthreads();

    int2 myedge[K3_PER_T];
    short mybin[K3_PER_T];
#pragma unroll
    for (int k = 0; k < K3_PER_T; ++k) {
        int e = base_e + t + k * K3_THREADS;
        if (e < N_EDGES) {
            int d = min(max(dst[e], 0), N_NODES - 1);
            int s = min(max(src[e], 0), N_NODES - 1);
            int b = d >> PBITS;
            mybin[k] = (short)b;
            myedge[k] = make_int2((s << PBITS) | (d & (PNODES - 1)),
                                  __float_as_int(w[e]));
            atomicAdd(&swhist[wv][b], 1);
        } else mybin[k] = -1;
    }
    __syncthreads();
    {
        int v = 0;
        if (t < NBINS) {
            v = swhist[0][t] + swhist[1][t] + swhist[2][t] + swhist[3][t];
            stot[t] = v;
        }
        stmp[t] = v;
    }
    __syncthreads();
    for (int off = 1; off < 512; off <<= 1) {
        int v0 = (t >= off) ? stmp[t - off] : 0;
        __syncthreads();
        stmp[t] += v0;
        __syncthreads();
    }
    if (t < NBINS) {
        lscan[t] = stmp[t] - stot[t];
        int c = stot[t];
        // count-only cursor: global slot base is b*BIN_CAP + prior count
        if (c > 0) sbase[t] = t * BIN_CAP + atomicAdd(&bin_cursor[t], c);
        int run = lscan[t];
        swcur[0][t] = run; run += swhist[0][t];
        swcur[1][t] = run; run += swhist[1][t];
        swcur[2][t] = run; run += swhist[2][t];
        swcur[3][t] = run;
    }
    __syncthreads();
#pragma unroll
    for (int k = 0; k < K3_PER_T; ++k) {
        int b = mybin[k];
        if (b >= 0) {
            int p = atomicAdd(&swcur[wv][b], 1);
            sdata[p] = myedge[k];
            sbinid[p] = (unsigned short)b;
        }
    }
    __syncthreads();
    int cnt = min(N_EDGES - base_e, K3_CHUNK);
#pragma unroll
    for (int k = 0; k < K3_PER_T; ++k) {
        int p = t + k * K3_THREADS;
        if (p < cnt) {
            int b = sbinid[p];
            int idx = sbase[b] + (p - lscan[b]);
            idx = min(idx, (b + 1) * BIN_CAP - 1);   // overflow-safe (no fault)
            csr_bin[idx] = sdata[p];
        }
    }
}

// ======================= dense GEMM 1 (R13-proven) =========================
// R11: launched FIRST; block 0 zeroes bin_cursor (replaces the memset
// dispatch). gemm1 is independent of the CSR build; the stream serializes
// this kernel before bin_scatter.

#define BK 16
__global__ __launch_bounds__(256) void gemm1_tiled(const float* __restrict__ x,
                                                   const float* __restrict__ W1,
                                                   unsigned short* __restrict__ s1b,
                                                   int* __restrict__ bin_cursor) {
    __shared__ float xT[BK][68];
    __shared__ float wt[BK][64];
    int t = threadIdx.x;
    if (blockIdx.x == 0)
        for (int i = t; i < NBINS; i += 256) bin_cursor[i] = 0;
    int n_base = blockIdx.x * 64;
    int cq = t & 15;
    int nq = t >> 4;
    int ld_node = t >> 2;
    int ld_k4   = (t & 3) * 4;
    int gnode = min(n_base + ld_node, N_NODES - 1);
    const float* xrow = x + (size_t)gnode * NFEAT;
    int wr = t >> 4;
    int wc = (t & 15) * 4;
    float acc[4][4] = {};
    for (int k0 = 0; k0 < NFEAT; k0 += BK) {
        float4 xv = *(const float4*)(xrow + k0 + ld_k4);
        xT[ld_k4 + 0][ld_node] = xv.x;
        xT[ld_k4 + 1][ld_node] = xv.y;
        xT[ld_k4 + 2][ld_node] = xv.z;
        xT[ld_k4 + 3][ld_node] = xv.w;
        *(float4*)&wt[wr][wc] = *(const float4*)(W1 + (size_t)(k0 + wr) * NHID + wc);
        __syncthreads();
#pragma unroll
        for (int k = 0; k < BK; ++k) {
            float4 a = *(const float4*)&xT[k][4 * nq];
            float4 bb = *(const float4*)&wt[k][4 * cq];
            acc[0][0] = fmaf(a.x, bb.x, acc[0][0]);
            acc[0][1] = fmaf(a.x, bb.y, acc[0][1]);
            acc[0][2] = fmaf(a.x, bb.z, acc[0][2]);
            acc[0][3] = fmaf(a.x, bb.w, acc[0][3]);
            acc[1][0] = fmaf(a.y, bb.x, acc[1][0]);
            acc[1][1] = fmaf(a.y, bb.y, acc[1][1]);
            acc[1][2] = fmaf(a.y, bb.z, acc[1][2]);
            acc[1][3] = fmaf(a.y, bb.w, acc[1][3]);
            acc[2][0] = fmaf(a.z, bb.x, acc[2][0]);
            acc[2][1] = fmaf(a.z, bb.y, acc[2][1]);
            acc[2][2] = fmaf(a.z, bb.z, acc[2][2]);
            acc[2][3] = fmaf(a.z, bb.w, acc[2][3]);
            acc[3][0] = fmaf(a.w, bb.x, acc[3][0]);
            acc[3][1] = fmaf(a.w, bb.y, acc[3][1]);
            acc[3][2] = fmaf(a.w, bb.z, acc[3][2]);
            acc[3][3] = fmaf(a.w, bb.w, acc[3][3]);
        }
        __syncthreads();
    }
#pragma unroll
    for (int i = 0; i < 4; ++i) {
        int n = n_base + 4 * nq + i;
        if (n < N_NODES) {
            ushort4 o;
            o.x = f2bf(acc[i][0]); o.y = f2bf(acc[i][1]);
            o.z = f2bf(acc[i][2]); o.w = f2bf(acc[i][3]);
            *(ushort4*)&s1b[(size_t)n * NHID + 4 * cq] = o;
        }
    }
}

// ============ fused per-bin sort + SpMM1 + bias/ReLU + GEMM2 ===============
// R12: hist pass caches each thread's <=5 edges in REGISTERS (fully unrolled,
// compile-time indices -> no scratch); scatter pass replays from registers.
// Deletes the second 12.8 MB csr_bin global read. Placement order identical
// to R5 (k-ascending == old j/j+1024 pair order) -> bit-identical output.
__global__ __launch_bounds__(1024, 4) void sort_spmm1_fused(
        const int* __restrict__ bin_cursor, const int2* __restrict__ csr_bin,
        int2* __restrict__ csr_edge, int2* __restrict__ row_range,
        const uint2* __restrict__ s1p2, const float* __restrict__ b1,
        const float* __restrict__ W2, float* __restrict__ s2) {
    __shared__ int2 sdata[BIN_CAP];                  // 40 KB sorted edges
    __shared__ union {
        struct { int whist[16][PNODES]; int wcur[16][PNODES]; } c;  // 16 KB
        float hsh[64][64];                                          // 16 KB
    } u;
    __shared__ int ltot[PNODES];
    __shared__ int ltmp[PNODES];
    __shared__ float W2s[NHID * NCLASS];             // 4 KB
    __shared__ float b1s[NHID];
    int t = threadIdx.x;
    int wv = t >> 6;                                 // 16 waves
    int b = blockIdx.x;
    int base = b * BIN_CAP;
    int cnt = min(bin_cursor[b], BIN_CAP);

    for (int i = t; i < 16 * PNODES; i += 1024) ((int*)u.c.whist)[i] = 0;
    if (t < NHID * NCLASS) W2s[t] = W2[t];
    if (t < NHID) b1s[t] = b1[t];
    __syncthreads();

    // --- hist pass: load each thread's edges ONCE, keep in registers ---
    int2 myed[S_PER_T];
#pragma unroll
    for (int k = 0; k < S_PER_T; ++k) {
        int j = t + k * 1024;
        if (j < cnt) {
            int2 e0 = csr_bin[base + j];
            myed[k] = e0;
            atomicAdd(&u.c.whist[wv][e0.x & (PNODES - 1)], 1);
        }
    }
    __syncthreads();
    if (t < PNODES) {
        int v = 0;
#pragma unroll
        for (int k = 0; k < 16; ++k) v += u.c.whist[k][t];
        ltot[t] = v; ltmp[t] = v;
    }
    __syncthreads();
    for (int off = 1; off < PNODES; off <<= 1) {
        int a = 0;
        if (t < PNODES && t >= off) a = ltmp[t - off];
        __syncthreads();
        if (t < PNODES) ltmp[t] += a;
        __syncthreads();
    }
    if (t < PNODES) {
        int begl = ltmp[t] - ltot[t];                // local (0-based in bin)
        int node = b * PNODES + t;
        if (node < N_NODES)
            row_range[node] = make_int2(base + begl, base + ltmp[t]);
        int run = begl;
#pragma unroll
        for (int k = 0; k < 16; ++k) { u.c.wcur[k][t] = run; run += u.c.whist[k][t]; }
    }
    __syncthreads();
    // --- scatter pass: sorted (src, w) into LDS, from registers ---
#pragma unroll
    for (int k = 0; k < S_PER_T; ++k) {
        int j = t + k * 1024;
        if (j < cnt) {
            int2 e0 = myed[k];
            int p0 = atomicAdd(&u.c.wcur[wv][e0.x & (PNODES - 1)], 1);
            sdata[p0] = make_int2(e0.x >> PBITS, e0.y);
        }
    }
    __syncthreads();
    // --- coalesced writeback for spmm2 ---
    for (int i = t; i < cnt; i += 1024) csr_edge[base + i] = sdata[i];

    // --- spmm1 + bias/ReLU + gemm2, 64 node-groups x 16 lanes, 2 rounds ---
    int g = t >> 4, lane = t & 15;
#pragma unroll
    for (int round = 0; round < 2; ++round) {
        int nl = g + 64 * round;
        int node = b * PNODES + nl;
        if (node >= N_NODES) continue;
        int endl = ltmp[nl];
        int j = endl - ltot[nl];
        float4 accA = {0.f, 0.f, 0.f, 0.f}, accB = {0.f, 0.f, 0.f, 0.f};
        for (; j + 7 < endl; j += 8) {
            int2 e0 = sdata[j],     e1 = sdata[j + 1];
            int2 e2 = sdata[j + 2], e3 = sdata[j + 3];
            int2 e4 = sdata[j + 4], e5 = sdata[j + 5];
            int2 e6 = sdata[j + 6], e7 = sdata[j + 7];
            uint2 v0 = s1p2[(size_t)e0.x * 16 + lane];
            uint2 v1 = s1p2[(size_t)e1.x * 16 + lane];
            uint2 v2 = s1p2[(size_t)e2.x * 16 + lane];
            uint2 v3 = s1p2[(size_t)e3.x * 16 + lane];
            uint2 v4 = s1p2[(size_t)e4.x * 16 + lane];
            uint2 v5 = s1p2[(size_t)e5.x * 16 + lane];
            uint2 v6 = s1p2[(size_t)e6.x * 16 + lane];
            uint2 v7 = s1p2[(size_t)e7.x * 16 + lane];
            float w0 = __int_as_float(e0.y), w1 = __int_as_float(e1.y);
            float w2 = __int_as_float(e2.y), w3 = __int_as_float(e3.y);
            float w4 = __int_as_float(e4.y), w5 = __int_as_float(e5.y);
            float w6 = __int_as_float(e6.y), w7 = __int_as_float(e7.y);
            accA.x = fmaf(w0, __uint_as_float(v0.x << 16), accA.x);
            accA.y = fmaf(w0, __uint_as_float(v0.x & 0xFFFF0000u), accA.y);
            accA.z = fmaf(w0, __uint_as_float(v0.y << 16), accA.z);
            accA.w = fmaf(w0, __uint_as_float(v0.y & 0xFFFF0000u), accA.w);
            accB.x = fmaf(w1, __uint_as_float(v1.x << 16), accB.x);
            accB.y = fmaf(w1, __uint_as_float(v1.x & 0xFFFF0000u), accB.y);
            accB.z = fmaf(w1, __uint_as_float(v1.y << 16), accB.z);
            accB.w = fmaf(w1, __uint_as_float(v1.y & 0xFFFF0000u), accB.w);
            accA.x = fmaf(w2, __uint_as_float(v2.x << 16), accA.x);
            accA.y = fmaf(w2, __uint_as_float(v2.x & 0xFFFF0000u), accA.y);
            accA.z = fmaf(w2, __uint_as_float(v2.y << 16), accA.z);
            accA.w = fmaf(w2, __uint_as_float(v2.y & 0xFFFF0000u), accA.w);
            accB.x = fmaf(w3, __uint_as_float(v3.x << 16), accB.x);
            accB.y = fmaf(w3, __uint_as_float(v3.x & 0xFFFF0000u), accB.y);
            accB.z = fmaf(w3, __uint_as_float(v3.y << 16), accB.z);
            accB.w = fmaf(w3, __uint_as_float(v3.y & 0xFFFF0000u), accB.w);
            accA.x = fmaf(w4, __uint_as_float(v4.x << 16), accA.x);
            accA.y = fmaf(w4, __uint_as_float(v4.x & 0xFFFF0000u), accA.y);
            accA.z = fmaf(w4, __uint_as_float(v4.y << 16), accA.z);
            accA.w = fmaf(w4, __uint_as_float(v4.y & 0xFFFF0000u), accA.w);
            accB.x = fmaf(w5, __uint_as_float(v5.x << 16), accB.x);
            accB.y = fmaf(w5, __uint_as_float(v5.x & 0xFFFF0000u), accB.y);
            accB.z = fmaf(w5, __uint_as_float(v5.y << 16), accB.z);
            accB.w = fmaf(w5, __uint_as_float(v5.y & 0xFFFF0000u), accB.w);
            accA.x = fmaf(w6, __uint_as_float(v6.x << 16), accA.x);
            accA.y = fmaf(w6, __uint_as_float(v6.x & 0xFFFF0000u), accA.y);
            accA.z = fmaf(w6, __uint_as_float(v6.y << 16), accA.z);
            accA.w = fmaf(w6, __uint_as_float(v6.y & 0xFFFF0000u), accA.w);
            accB.x = fmaf(w7, __uint_as_float(v7.x << 16), accB.x);
            accB.y = fmaf(w7, __uint_as_float(v7.x & 0xFFFF0000u), accB.y);
            accB.z = fmaf(w7, __uint_as_float(v7.y << 16), accB.z);
            accB.w = fmaf(w7, __uint_as_float(v7.y & 0xFFFF0000u), accB.w);
        }
        for (; j < endl; ++j) {
            int2 e0 = sdata[j];
            uint2 v0 = s1p2[(size_t)e0.x * 16 + lane];
            float w0 = __int_as_float(e0.y);
            accA.x = fmaf(w0, __uint_as_float(v0.x << 16), accA.x);
            accA.y = fmaf(w0, __uint_as_float(v0.x & 0xFFFF0000u), accA.y);
            accA.z = fmaf(w0, __uint_as_float(v0.y << 16), accA.z);
            accA.w = fmaf(w0, __uint_as_float(v0.y & 0xFFFF0000u), accA.w);
        }
        float4 bb = *(const float4*)&b1s[4 * lane];
        float4 hv;
        hv.x = accA.x + accB.x + bb.x;
        hv.y = accA.y + accB.y + bb.y;
        hv.z = accA.z + accB.z + bb.z;
        hv.w = accA.w + accB.w + bb.w;
        hv.x = hv.x > 0.f ? hv.x : 0.f;
        hv.y = hv.y > 0.f ? hv.y : 0.f;
        hv.z = hv.z > 0.f ? hv.z : 0.f;
        hv.w = hv.w > 0.f ? hv.w : 0.f;
        // same-wave LDS park (lockstep within wave, no barrier needed)
        *(float4*)&u.hsh[g][4 * lane] = hv;
        float acc = 0.f;
#pragma unroll 16
        for (int k = 0; k < NHID; ++k)
            acc = fmaf(u.hsh[g][k], W2s[k * NCLASS + lane], acc);
        s2[(size_t)node * NCLASS + lane] = acc;
    }
}

// ======================= SpMM2 + bias + log_softmax ========================
// R13-exact: fp32 s2, 16 lanes/node, 8-edge unrolled.
__global__ void spmm2_csr_kernel(const int2* __restrict__ row_range,
                                 const int2* __restrict__ csr_edge,
                                 const float* __restrict__ s2,
                                 const float* __restrict__ b2,
                                 float* __restrict__ out) {
    int node = blockIdx.x * 16 + (threadIdx.x >> 4);
    if (node >= N_NODES) return;
    int c = threadIdx.x & 15;
    int2 rr = row_range[node];
    int beg = rr.x, end = rr.y;
    float acc0 = 0.f, acc1 = 0.f, acc2 = 0.f, acc3 = 0.f;
    int j = beg;
    for (; j + 7 < end; j += 8) {
        int2 e0 = csr_edge[j],     e1 = csr_edge[j + 1];
        int2 e2 = csr_edge[j + 2], e3 = csr_edge[j + 3];
        int2 e4 = csr_edge[j + 4], e5 = csr_edge[j + 5];
        int2 e6 = csr_edge[j + 6], e7 = csr_edge[j + 7];
        float g0 = s2[(size_t)e0.x * NCLASS + c];
        float g1 = s2[(size_t)e1.x * NCLASS + c];
        float g2 = s2[(size_t)e2.x * NCLASS + c];
        float g3 = s2[(size_t)e3.x * NCLASS + c];
        float g4 = s2[(size_t)e4.x * NCLASS + c];
        float g5 = s2[(size_t)e5.x * NCLASS + c];
        float g6 = s2[(size_t)e6.x * NCLASS + c];
        float g7 = s2[(size_t)e7.x * NCLASS + c];
        acc0 = fmaf(__int_as_float(e0.y), g0, acc0);
        acc1 = fmaf(__int_as_float(e1.y), g1, acc1);
        acc2 = fmaf(__int_as_float(e2.y), g2, acc2);
        acc3 = fmaf(__int_as_float(e3.y), g3, acc3);
        acc0 = fmaf(__int_as_float(e4.y), g4, acc0);
        acc1 = fmaf(__int_as_float(e5.y), g5, acc1);
        acc2 = fmaf(__int_as_float(e6.y), g6, acc2);
        acc3 = fmaf(__int_as_float(e7.y), g7, acc3);
    }
    for (; j + 3 < end; j += 4) {
        int2 e0 = csr_edge[j],     e1 = csr_edge[j + 1];
        int2 e2 = csr_edge[j + 2], e3 = csr_edge[j + 3];
        acc0 = fmaf(__int_as_float(e0.y), s2[(size_t)e0.x * NCLASS + c], acc0);
        acc1 = fmaf(__int_as_float(e1.y), s2[(size_t)e1.x * NCLASS + c], acc1);
        acc2 = fmaf(__int_as_float(e2.y), s2[(size_t)e2.x * NCLASS + c], acc2);
        acc3 = fmaf(__int_as_float(e3.y), s2[(size_t)e3.x * NCLASS + c], acc3);
    }
    for (; j < end; ++j) {
        int2 e0 = csr_edge[j];
        acc0 = fmaf(__int_as_float(e0.y), s2[(size_t)e0.x * NCLASS + c], acc0);
    }
    float v = (acc0 + acc1) + (acc2 + acc3) + b2[c];
    float mx = v;
    for (int off = 8; off; off >>= 1) mx = fmaxf(mx, __shfl_xor(mx, off, 16));
    float ss = expf(v - mx);
    for (int off = 8; off; off >>= 1) ss += __shfl_xor(ss, off, 16);
    out[(size_t)node * NCLASS + c] = v - mx - logf(ss);
}

// ======================= fallback path (R3 atomic version) =================

__global__ void zero_kernel(float* __restrict__ h, float* __restrict__ out) {
    int i = blockIdx.x * 256 + threadIdx.x;
    if (i < N_NODES * NHID) h[i] = 0.f;
    if (i < N_NODES * NCLASS) out[i] = 0.f;
}

__global__ void gemm1_kernel(const float* __restrict__ x,
                             const float* __restrict__ W1,
                             float* __restrict__ s1) {
    int node = blockIdx.x * 4 + (threadIdx.x >> 6);
    int col  = threadIdx.x & 63;
    if (node >= N_NODES) return;
    const float* xr = x + (size_t)node * NFEAT;
    float sum = 0.f;
#pragma unroll 8
    for (int k = 0; k < NFEAT; ++k)
        sum = fmaf(xr[k], W1[k * NHID + col], sum);
    s1[(size_t)node * NHID + col] = sum;
}

__global__ void spmm1_kernel(const int* __restrict__ src, const int* __restrict__ dst,
                             const float* __restrict__ w, const float* __restrict__ s1,
                             float* __restrict__ h) {
    int e = blockIdx.x * 4 + (threadIdx.x >> 6);
    if (e >= N_EDGES) return;
    int lane = threadIdx.x & 63;
    int s = min(max(src[e], 0), N_NODES - 1);
    int d = min(max(dst[e], 0), N_NODES - 1);
    float v = w[e] * s1[(size_t)s * NHID + lane];
    atomicAdd(&h[(size_t)d * NHID + lane], v);
}

__global__ void bias_relu_kernel(float* __restrict__ h, const float* __restrict__ b1) {
    int i = blockIdx.x * 256 + threadIdx.x;
    if (i >= N_NODES * NHID) return;
    float v = h[i] + b1[i & (NHID - 1)];
    h[i] = v > 0.f ? v : 0.f;
}

__global__ void gemm2_kernel(const float* __restrict__ h,
                             const float* __restrict__ W2,
                             float* __restrict__ s2) {
    int node = blockIdx.x * 16 + (threadIdx.x >> 4);
    int col  = threadIdx.x & 15;
    if (node >= N_NODES) return;
    const float* hr = h + (size_t)node * NHID;
    float sum = 0.f;
#pragma unroll 8
    for (int k = 0; k < NHID; ++k)
        sum = fmaf(hr[k], W2[k * NCLASS + col], sum);
    s2[(size_t)node * NCLASS + col] = sum;
}

__global__ void spmm2_kernel(const int* __restrict__ src, const int* __restrict__ dst,
                             const float* __restrict__ w, const float* __restrict__ s2,
                             float* __restrict__ out) {
    int e = blockIdx.x * 16 + (threadIdx.x >> 4);
    if (e >= N_EDGES) return;
    int lane = threadIdx.x & 15;
    int s = min(max(src[e], 0), N_NODES - 1);
    int d = min(max(dst[e], 0), N_NODES - 1);
    float v = w[e] * s2[(size_t)s * NCLASS + lane];
    atomicAdd(&out[(size_t)d * NCLASS + lane], v);
}

__global__ void logsoftmax_kernel(float* __restrict__ out, const float* __restrict__ b2) {
    int n = blockIdx.x * 256 + threadIdx.x;
    if (n >= N_NODES) return;
    float v[NCLASS];
    float mx = -INFINITY;
#pragma unroll
    for (int c = 0; c < NCLASS; ++c) {
        v[c] = out[(size_t)n * NCLASS + c] + b2[c];
        mx = fmaxf(mx, v[c]);
    }
    float ssum = 0.f;
#pragma unroll
    for (int c = 0; c < NCLASS; ++c) ssum += expf(v[c] - mx);
    float ls = mx + logf(ssum);
#pragma unroll
    for (int c = 0; c < NCLASS; ++c) out[(size_t)n * NCLASS + c] = v[c] - ls;
}

// ======================= launch ============================================

extern "C" void kernel_launch(void* const* d_in, const int* in_sizes, int n_in,
                              void* d_out, int out_size, void* d_ws, size_t ws_size,
                              hipStream_t stream) {
    if (n_in != 8) return;
    const int expected[8] = { N_NODES * NFEAT, NFEAT * NHID, NHID,
                              NHID * NCLASS, NCLASS, N_EDGES, N_EDGES, N_EDGES };
    for (int i = 0; i < 8; ++i)
        if (in_sizes[i] != expected[i]) return;
    if (out_size != N_NODES * NCLASS) return;

    const float* x  = (const float*)d_in[0];
    const float* W1 = (const float*)d_in[1];
    const float* b1 = (const float*)d_in[2];
    const float* W2 = (const float*)d_in[3];
    const float* b2 = (const float*)d_in[4];
    const int* edge_src = (const int*)d_in[5];
    const int* edge_dst = (const int*)d_in[6];
    const float* edge_w = (const float*)d_in[7];
    float* out = (float*)d_out;

    const size_t S1_ELTS = (size_t)N_NODES * NHID;          // 3.2M (ushorts)
    const size_t CAP_WORDS = (size_t)NBINS * BIN_CAP * 2;   // int2 region, words
    // layout (32-bit words) — fully DISJOINT (s1b live alongside csr_bin
    // inside sort_spmm1_fused):
    //   [0, CAP)          csr_bin    (16 MB)
    //   [CAP, 2CAP)       csr_edge   (16 MB)
    //   [2CAP, +2N)       row_range  (0.4 MB)
    //   [.., +512)        bin_cursor (391 ints + pad, keeps s1b 8B-aligned)
    //   [.., +S1/2)       s1b        (6.4 MB bf16)
    //   [.., +N*NCLASS)   s2         (3.2 MB fp32)
    const size_t NEW_WORDS = 2 * CAP_WORDS + 2 * (size_t)N_NODES + 512
                           + S1_ELTS / 2 + (size_t)N_NODES * NCLASS;
    if (ws_size >= NEW_WORDS * 4) {
        int2*  csr_bin    = (int2*)d_ws;
        int2*  csr_edge   = (int2*)((int*)d_ws + CAP_WORDS);
        int2*  row_range  = (int2*)((int*)d_ws + 2 * CAP_WORDS);
        int*   bin_cursor = (int*)d_ws + 2 * CAP_WORDS + 2 * (size_t)N_NODES;
        unsigned short* s1b =
            (unsigned short*)((int*)d_ws + 2 * CAP_WORDS + 2 * (size_t)N_NODES + 512);
        float* s2 = (float*)d_ws + 2 * CAP_WORDS + 2 * (size_t)N_NODES + 512
                  + S1_ELTS / 2;

        // gemm1 first: its block 0 zeroes bin_cursor (replaces memset dispatch)
        gemm1_tiled<<<(N_NODES + 63) / 64, 256, 0, stream>>>(x, W1, s1b, bin_cursor);
        bin_scatter_kernel<<<K3_BLOCKS, K3_THREADS, 0, stream>>>(
            edge_src, edge_dst, edge_w, bin_cursor, csr_bin);
        sort_spmm1_fused<<<NBINS, 1024, 0, stream>>>(
            bin_cursor, csr_bin, csr_edge, row_range,
            (const uint2*)s1b, b1, W2, s2);
        spmm2_csr_kernel<<<(N_NODES + 15) / 16, 256, 0, stream>>>(
            row_range, csr_edge, s2, b2, out);
        return;
    }

    // --- fallback: proven atomic path (25.6 MB ws) ---
    if (ws_size < 2 * S1_ELTS * sizeof(float)) return;
    float* s1 = (float*)d_ws;
    float* h  = s1 + S1_ELTS;
    float* s2 = s1;
    zero_kernel<<<(N_NODES * NHID + 255) / 256, 256, 0, stream>>>(h, out);
    gemm1_kernel<<<(N_NODES + 3) / 4, 256, 0, stream>>>(x, W1, s1);
    spmm1_kernel<<<(N_EDGES + 3) / 4, 256, 0, stream>>>(edge_src, edge_dst, edge_w, s1, h);
    bias_relu_kernel<<<(N_NODES * NHID + 255) / 256, 256, 0, stream>>>(h, b1);
    gemm2_kernel<<<(N_NODES + 15) / 16, 256, 0, stream>>>(h, W2, s2);
    spmm2_kernel<<<(N_EDGES + 15) / 16, 256, 0, stream>>>(edge_src, edge_dst, edge_w, s2, out);
    logsoftmax_kernel<<<(N_NODES + 255) / 256, 256, 0, stream>>>(out, b2);
}

// Round 13
// 201.942 us; speedup vs baseline: 1.2119x; 1.0172x over previous
//
#include <hip/hip_runtime.h>
#include <math.h>

#define N_NODES 50000
#define N_EDGES 1600000
#define NFEAT 256
#define NHID 64
#define NCLASS 16

#define PBITS 7
#define PNODES 128                       // nodes per bin (R5-proven geometry)
#define NBINS ((N_NODES + PNODES - 1) / PNODES)   // 391
#define BIN_CAP 5120                     // mean 4092, sigma 64 -> +16 sigma
#define K3_CHUNK 4096
#define K3_THREADS 512
#define K3_PER_T 8                       // 4096 / 512
#define K3_BLOCKS ((N_EDGES + K3_CHUNK - 1) / K3_CHUNK)  // 391
#define S_PER_T 5                        // ceil(BIN_CAP / 1024)

__device__ inline unsigned short f2bf(float f) {     // RNE f32 -> bf16
    unsigned u = __float_as_uint(f);
    return (unsigned short)((u + 0x7FFFu + ((u >> 16) & 1u)) >> 16);
}

// ======================= bin scatter (counting sort, pass 1) ===============
// R10-proven 512-thread version. bin_cursor is COUNT-ONLY (zeroed by
// gemm1_tiled block 0, which runs in the PRECEDING dispatch); slot base is
// b*BIN_CAP.
__global__ __launch_bounds__(512) void bin_scatter_kernel(
        const int* __restrict__ src, const int* __restrict__ dst,
        const float* __restrict__ w, int* __restrict__ bin_cursor,
        int2* __restrict__ csr_bin) {
    __shared__ int2 sdata[K3_CHUNK];                 // 32 KB
    __shared__ unsigned short sbinid[K3_CHUNK];      // 8 KB
    __shared__ int swhist[4][NBINS];                 // 6.1 KB (wave-pair priv)
    __shared__ int swcur[4][NBINS];                  // 6.1 KB
    __shared__ int stot[NBINS];
    __shared__ int lscan[NBINS];
    __shared__ int sbase[NBINS];
    __shared__ int stmp[512];
    int t = threadIdx.x;
    int wv = t >> 7;                                 // 4 hist copies, 2 waves ea
    int base_e = blockIdx.x * K3_CHUNK;

    for (int b = t; b < NBINS; b += K3_THREADS) {
        swhist[0][b] = 0; swhist[1][b] = 0; swhist[2][b] = 0; swhist[3][b] = 0;
    }
    __syncthreads();

    int2 myedge[K3_PER_T];
    short mybin[K3_PER_T];
#pragma unroll
    for (int k = 0; k < K3_PER_T; ++k) {
        int e = base_e + t + k * K3_THREADS;
        if (e < N_EDGES) {
            int d = min(max(dst[e], 0), N_NODES - 1);
            int s = min(max(src[e], 0), N_NODES - 1);
            int b = d >> PBITS;
            mybin[k] = (short)b;
            myedge[k] = make_int2((s << PBITS) | (d & (PNODES - 1)),
                                  __float_as_int(w[e]));
            atomicAdd(&swhist[wv][b], 1);
        } else mybin[k] = -1;
    }
    __syncthreads();
    {
        int v = 0;
        if (t < NBINS) {
            v = swhist[0][t] + swhist[1][t] + swhist[2][t] + swhist[3][t];
            stot[t] = v;
        }
        stmp[t] = v;
    }
    __syncthreads();
    for (int off = 1; off < 512; off <<= 1) {
        int v0 = (t >= off) ? stmp[t - off] : 0;
        __syncthreads();
        stmp[t] += v0;
        __syncthreads();
    }
    if (t < NBINS) {
        lscan[t] = stmp[t] - stot[t];
        int c = stot[t];
        // count-only cursor: global slot base is b*BIN_CAP + prior count
        if (c > 0) sbase[t] = t * BIN_CAP + atomicAdd(&bin_cursor[t], c);
        int run = lscan[t];
        swcur[0][t] = run; run += swhist[0][t];
        swcur[1][t] = run; run += swhist[1][t];
        swcur[2][t] = run; run += swhist[2][t];
        swcur[3][t] = run;
    }
    __syncthreads();
#pragma unroll
    for (int k = 0; k < K3_PER_T; ++k) {
        int b = mybin[k];
        if (b >= 0) {
            int p = atomicAdd(&swcur[wv][b], 1);
            sdata[p] = myedge[k];
            sbinid[p] = (unsigned short)b;
        }
    }
    __syncthreads();
    int cnt = min(N_EDGES - base_e, K3_CHUNK);
#pragma unroll
    for (int k = 0; k < K3_PER_T; ++k) {
        int p = t + k * K3_THREADS;
        if (p < cnt) {
            int b = sbinid[p];
            int idx = sbase[b] + (p - lscan[b]);
            idx = min(idx, (b + 1) * BIN_CAP - 1);   // overflow-safe (no fault)
            csr_bin[idx] = sdata[p];
        }
    }
}

// ======================= dense GEMM 1 (R13-proven) =========================
// R11: launched FIRST; block 0 zeroes bin_cursor (replaces the memset
// dispatch). gemm1 is independent of the CSR build; the stream serializes
// this kernel before bin_scatter.

#define BK 16
__global__ __launch_bounds__(256) void gemm1_tiled(const float* __restrict__ x,
                                                   const float* __restrict__ W1,
                                                   unsigned short* __restrict__ s1b,
                                                   int* __restrict__ bin_cursor) {
    __shared__ float xT[BK][68];
    __shared__ float wt[BK][64];
    int t = threadIdx.x;
    if (blockIdx.x == 0)
        for (int i = t; i < NBINS; i += 256) bin_cursor[i] = 0;
    int n_base = blockIdx.x * 64;
    int cq = t & 15;
    int nq = t >> 4;
    int ld_node = t >> 2;
    int ld_k4   = (t & 3) * 4;
    int gnode = min(n_base + ld_node, N_NODES - 1);
    const float* xrow = x + (size_t)gnode * NFEAT;
    int wr = t >> 4;
    int wc = (t & 15) * 4;
    float acc[4][4] = {};
    for (int k0 = 0; k0 < NFEAT; k0 += BK) {
        float4 xv = *(const float4*)(xrow + k0 + ld_k4);
        xT[ld_k4 + 0][ld_node] = xv.x;
        xT[ld_k4 + 1][ld_node] = xv.y;
        xT[ld_k4 + 2][ld_node] = xv.z;
        xT[ld_k4 + 3][ld_node] = xv.w;
        *(float4*)&wt[wr][wc] = *(const float4*)(W1 + (size_t)(k0 + wr) * NHID + wc);
        __syncthreads();
#pragma unroll
        for (int k = 0; k < BK; ++k) {
            float4 a = *(const float4*)&xT[k][4 * nq];
            float4 bb = *(const float4*)&wt[k][4 * cq];
            acc[0][0] = fmaf(a.x, bb.x, acc[0][0]);
            acc[0][1] = fmaf(a.x, bb.y, acc[0][1]);
            acc[0][2] = fmaf(a.x, bb.z, acc[0][2]);
            acc[0][3] = fmaf(a.x, bb.w, acc[0][3]);
            acc[1][0] = fmaf(a.y, bb.x, acc[1][0]);
            acc[1][1] = fmaf(a.y, bb.y, acc[1][1]);
            acc[1][2] = fmaf(a.y, bb.z, acc[1][2]);
            acc[1][3] = fmaf(a.y, bb.w, acc[1][3]);
            acc[2][0] = fmaf(a.z, bb.x, acc[2][0]);
            acc[2][1] = fmaf(a.z, bb.y, acc[2][1]);
            acc[2][2] = fmaf(a.z, bb.z, acc[2][2]);
            acc[2][3] = fmaf(a.z, bb.w, acc[2][3]);
            acc[3][0] = fmaf(a.w, bb.x, acc[3][0]);
            acc[3][1] = fmaf(a.w, bb.y, acc[3][1]);
            acc[3][2] = fmaf(a.w, bb.z, acc[3][2]);
            acc[3][3] = fmaf(a.w, bb.w, acc[3][3]);
        }
        __syncthreads();
    }
#pragma unroll
    for (int i = 0; i < 4; ++i) {
        int n = n_base + 4 * nq + i;
        if (n < N_NODES) {
            ushort4 o;
            o.x = f2bf(acc[i][0]); o.y = f2bf(acc[i][1]);
            o.z = f2bf(acc[i][2]); o.w = f2bf(acc[i][3]);
            *(ushort4*)&s1b[(size_t)n * NHID + 4 * cq] = o;
        }
    }
}

// ============ fused per-bin sort + SpMM1 + bias/ReLU + GEMM2 ===============
// R12 version (reg-cached hist edges; bit-identical placement to R5).
__global__ __launch_bounds__(1024, 4) void sort_spmm1_fused(
        const int* __restrict__ bin_cursor, const int2* __restrict__ csr_bin,
        int2* __restrict__ csr_edge, int2* __restrict__ row_range,
        const uint2* __restrict__ s1p2, const float* __restrict__ b1,
        const float* __restrict__ W2, float* __restrict__ s2) {
    __shared__ int2 sdata[BIN_CAP];                  // 40 KB sorted edges
    __shared__ union {
        struct { int whist[16][PNODES]; int wcur[16][PNODES]; } c;  // 16 KB
        float hsh[64][64];                                          // 16 KB
    } u;
    __shared__ int ltot[PNODES];
    __shared__ int ltmp[PNODES];
    __shared__ float W2s[NHID * NCLASS];             // 4 KB
    __shared__ float b1s[NHID];
    int t = threadIdx.x;
    int wv = t >> 6;                                 // 16 waves
    int b = blockIdx.x;
    int base = b * BIN_CAP;
    int cnt = min(bin_cursor[b], BIN_CAP);

    for (int i = t; i < 16 * PNODES; i += 1024) ((int*)u.c.whist)[i] = 0;
    if (t < NHID * NCLASS) W2s[t] = W2[t];
    if (t < NHID) b1s[t] = b1[t];
    __syncthreads();

    // --- hist pass: load each thread's edges ONCE, keep in registers ---
    int2 myed[S_PER_T];
#pragma unroll
    for (int k = 0; k < S_PER_T; ++k) {
        int j = t + k * 1024;
        if (j < cnt) {
            int2 e0 = csr_bin[base + j];
            myed[k] = e0;
            atomicAdd(&u.c.whist[wv][e0.x & (PNODES - 1)], 1);
        }
    }
    __syncthreads();
    if (t < PNODES) {
        int v = 0;
#pragma unroll
        for (int k = 0; k < 16; ++k) v += u.c.whist[k][t];
        ltot[t] = v; ltmp[t] = v;
    }
    __syncthreads();
    for (int off = 1; off < PNODES; off <<= 1) {
        int a = 0;
        if (t < PNODES && t >= off) a = ltmp[t - off];
        __syncthreads();
        if (t < PNODES) ltmp[t] += a;
        __syncthreads();
    }
    if (t < PNODES) {
        int begl = ltmp[t] - ltot[t];                // local (0-based in bin)
        int node = b * PNODES + t;
        if (node < N_NODES)
            row_range[node] = make_int2(base + begl, base + ltmp[t]);
        int run = begl;
#pragma unroll
        for (int k = 0; k < 16; ++k) { u.c.wcur[k][t] = run; run += u.c.whist[k][t]; }
    }
    __syncthreads();
    // --- scatter pass: sorted (src, w) into LDS, from registers ---
#pragma unroll
    for (int k = 0; k < S_PER_T; ++k) {
        int j = t + k * 1024;
        if (j < cnt) {
            int2 e0 = myed[k];
            int p0 = atomicAdd(&u.c.wcur[wv][e0.x & (PNODES - 1)], 1);
            sdata[p0] = make_int2(e0.x >> PBITS, e0.y);
        }
    }
    __syncthreads();
    // --- coalesced writeback for spmm2 ---
    for (int i = t; i < cnt; i += 1024) csr_edge[base + i] = sdata[i];

    // --- spmm1 + bias/ReLU + gemm2, 64 node-groups x 16 lanes, 2 rounds ---
    int g = t >> 4, lane = t & 15;
#pragma unroll
    for (int round = 0; round < 2; ++round) {
        int nl = g + 64 * round;
        int node = b * PNODES + nl;
        if (node >= N_NODES) continue;
        int endl = ltmp[nl];
        int j = endl - ltot[nl];
        float4 accA = {0.f, 0.f, 0.f, 0.f}, accB = {0.f, 0.f, 0.f, 0.f};
        for (; j + 7 < endl; j += 8) {
            int2 e0 = sdata[j],     e1 = sdata[j + 1];
            int2 e2 = sdata[j + 2], e3 = sdata[j + 3];
            int2 e4 = sdata[j + 4], e5 = sdata[j + 5];
            int2 e6 = sdata[j + 6], e7 = sdata[j + 7];
            uint2 v0 = s1p2[(size_t)e0.x * 16 + lane];
            uint2 v1 = s1p2[(size_t)e1.x * 16 + lane];
            uint2 v2 = s1p2[(size_t)e2.x * 16 + lane];
            uint2 v3 = s1p2[(size_t)e3.x * 16 + lane];
            uint2 v4 = s1p2[(size_t)e4.x * 16 + lane];
            uint2 v5 = s1p2[(size_t)e5.x * 16 + lane];
            uint2 v6 = s1p2[(size_t)e6.x * 16 + lane];
            uint2 v7 = s1p2[(size_t)e7.x * 16 + lane];
            float w0 = __int_as_float(e0.y), w1 = __int_as_float(e1.y);
            float w2 = __int_as_float(e2.y), w3 = __int_as_float(e3.y);
            float w4 = __int_as_float(e4.y), w5 = __int_as_float(e5.y);
            float w6 = __int_as_float(e6.y), w7 = __int_as_float(e7.y);
            accA.x = fmaf(w0, __uint_as_float(v0.x << 16), accA.x);
            accA.y = fmaf(w0, __uint_as_float(v0.x & 0xFFFF0000u), accA.y);
            accA.z = fmaf(w0, __uint_as_float(v0.y << 16), accA.z);
            accA.w = fmaf(w0, __uint_as_float(v0.y & 0xFFFF0000u), accA.w);
            accB.x = fmaf(w1, __uint_as_float(v1.x << 16), accB.x);
            accB.y = fmaf(w1, __uint_as_float(v1.x & 0xFFFF0000u), accB.y);
            accB.z = fmaf(w1, __uint_as_float(v1.y << 16), accB.z);
            accB.w = fmaf(w1, __uint_as_float(v1.y & 0xFFFF0000u), accB.w);
            accA.x = fmaf(w2, __uint_as_float(v2.x << 16), accA.x);
            accA.y = fmaf(w2, __uint_as_float(v2.x & 0xFFFF0000u), accA.y);
            accA.z = fmaf(w2, __uint_as_float(v2.y << 16), accA.z);
            accA.w = fmaf(w2, __uint_as_float(v2.y & 0xFFFF0000u), accA.w);
            accB.x = fmaf(w3, __uint_as_float(v3.x << 16), accB.x);
            accB.y = fmaf(w3, __uint_as_float(v3.x & 0xFFFF0000u), accB.y);
            accB.z = fmaf(w3, __uint_as_float(v3.y << 16), accB.z);
            accB.w = fmaf(w3, __uint_as_float(v3.y & 0xFFFF0000u), accB.w);
            accA.x = fmaf(w4, __uint_as_float(v4.x << 16), accA.x);
            accA.y = fmaf(w4, __uint_as_float(v4.x & 0xFFFF0000u), accA.y);
            accA.z = fmaf(w4, __uint_as_float(v4.y << 16), accA.z);
            accA.w = fmaf(w4, __uint_as_float(v4.y & 0xFFFF0000u), accA.w);
            accB.x = fmaf(w5, __uint_as_float(v5.x << 16), accB.x);
            accB.y = fmaf(w5, __uint_as_float(v5.x & 0xFFFF0000u), accB.y);
            accB.z = fmaf(w5, __uint_as_float(v5.y << 16), accB.z);
            accB.w = fmaf(w5, __uint_as_float(v5.y & 0xFFFF0000u), accB.w);
            accA.x = fmaf(w6, __uint_as_float(v6.x << 16), accA.x);
            accA.y = fmaf(w6, __uint_as_float(v6.x & 0xFFFF0000u), accA.y);
            accA.z = fmaf(w6, __uint_as_float(v6.y << 16), accA.z);
            accA.w = fmaf(w6, __uint_as_float(v6.y & 0xFFFF0000u), accA.w);
            accB.x = fmaf(w7, __uint_as_float(v7.x << 16), accB.x);
            accB.y = fmaf(w7, __uint_as_float(v7.x & 0xFFFF0000u), accB.y);
            accB.z = fmaf(w7, __uint_as_float(v7.y << 16), accB.z);
            accB.w = fmaf(w7, __uint_as_float(v7.y & 0xFFFF0000u), accB.w);
        }
        for (; j < endl; ++j) {
            int2 e0 = sdata[j];
            uint2 v0 = s1p2[(size_t)e0.x * 16 + lane];
            float w0 = __int_as_float(e0.y);
            accA.x = fmaf(w0, __uint_as_float(v0.x << 16), accA.x);
            accA.y = fmaf(w0, __uint_as_float(v0.x & 0xFFFF0000u), accA.y);
            accA.z = fmaf(w0, __uint_as_float(v0.y << 16), accA.z);
            accA.w = fmaf(w0, __uint_as_float(v0.y & 0xFFFF0000u), accA.w);
        }
        float4 bb = *(const float4*)&b1s[4 * lane];
        float4 hv;
        hv.x = accA.x + accB.x + bb.x;
        hv.y = accA.y + accB.y + bb.y;
        hv.z = accA.z + accB.z + bb.z;
        hv.w = accA.w + accB.w + bb.w;
        hv.x = hv.x > 0.f ? hv.x : 0.f;
        hv.y = hv.y > 0.f ? hv.y : 0.f;
        hv.z = hv.z > 0.f ? hv.z : 0.f;
        hv.w = hv.w > 0.f ? hv.w : 0.f;
        // same-wave LDS park (lockstep within wave, no barrier needed)
        *(float4*)&u.hsh[g][4 * lane] = hv;
        float acc = 0.f;
#pragma unroll 16
        for (int k = 0; k < NHID; ++k)
            acc = fmaf(u.hsh[g][k], W2s[k * NCLASS + lane], acc);
        s2[(size_t)node * NCLASS + lane] = acc;
    }
}

// ======================= SpMM2 + bias + log_softmax ========================
// R13: 4 lanes/edge x 4 edges/iter with float4 s2 gathers. Per edge: 8 load
// instructions vs 32 (old 16-lane/edge scalar form). Partial sums combined
// via shfl_xor(4,8) within the 16-lane group; softmax reduces across q via
// shfl_xor(1,2). Sum order reassociated (tree) -- tolerance absorbs it.
__global__ void spmm2_csr_kernel(const int2* __restrict__ row_range,
                                 const int2* __restrict__ csr_edge,
                                 const float* __restrict__ s2,
                                 const float* __restrict__ b2,
                                 float* __restrict__ out) {
    int node = blockIdx.x * 16 + (threadIdx.x >> 4);
    if (node >= N_NODES) return;
    int l  = threadIdx.x & 15;
    int eo = l >> 2;                    // edge slot within quad (0..3)
    int q  = l & 3;                     // class quad: classes 4q..4q+3
    int2 rr = row_range[node];
    int beg = rr.x, end = rr.y;
    float4 accA = {0.f, 0.f, 0.f, 0.f}, accB = {0.f, 0.f, 0.f, 0.f};
    int j = beg;
    for (; j + 7 < end; j += 8) {       // 8 edges: two quads in flight
        int2 eA = csr_edge[j + eo];
        int2 eB = csr_edge[j + 4 + eo];
        float4 vA = *(const float4*)&s2[(size_t)eA.x * NCLASS + 4 * q];
        float4 vB = *(const float4*)&s2[(size_t)eB.x * NCLASS + 4 * q];
        float wA = __int_as_float(eA.y), wB = __int_as_float(eB.y);
        accA.x = fmaf(wA, vA.x, accA.x);
        accA.y = fmaf(wA, vA.y, accA.y);
        accA.z = fmaf(wA, vA.z, accA.z);
        accA.w = fmaf(wA, vA.w, accA.w);
        accB.x = fmaf(wB, vB.x, accB.x);
        accB.y = fmaf(wB, vB.y, accB.y);
        accB.z = fmaf(wB, vB.z, accB.z);
        accB.w = fmaf(wB, vB.w, accB.w);
    }
    for (; j + 3 < end; j += 4) {       // 4-edge quad
        int2 eA = csr_edge[j + eo];
        float4 vA = *(const float4*)&s2[(size_t)eA.x * NCLASS + 4 * q];
        float wA = __int_as_float(eA.y);
        accA.x = fmaf(wA, vA.x, accA.x);
        accA.y = fmaf(wA, vA.y, accA.y);
        accA.z = fmaf(wA, vA.z, accA.z);
        accA.w = fmaf(wA, vA.w, accA.w);
    }
    {                                   // tail: 0-3 edges, slot eo < rem
        int rem = end - j;
        if (eo < rem) {
            int2 eA = csr_edge[j + eo];
            float4 vA = *(const float4*)&s2[(size_t)eA.x * NCLASS + 4 * q];
            float wA = __int_as_float(eA.y);
            accB.x = fmaf(wA, vA.x, accB.x);
            accB.y = fmaf(wA, vA.y, accB.y);
            accB.z = fmaf(wA, vA.z, accB.z);
            accB.w = fmaf(wA, vA.w, accB.w);
        }
    }
    float4 v;
    v.x = accA.x + accB.x; v.y = accA.y + accB.y;
    v.z = accA.z + accB.z; v.w = accA.w + accB.w;
    // reduce across the 4 edge slots (lanes differing in bits 2-3 of l)
    for (int off = 4; off <= 8; off <<= 1) {
        v.x += __shfl_xor(v.x, off, 16);
        v.y += __shfl_xor(v.y, off, 16);
        v.z += __shfl_xor(v.z, off, 16);
        v.w += __shfl_xor(v.w, off, 16);
    }
    float4 bv = *(const float4*)&b2[4 * q];
    v.x += bv.x; v.y += bv.y; v.z += bv.z; v.w += bv.w;
    // log_softmax over 16 classes: in-lane max/sum of the quad, then across q
    float mx = fmaxf(fmaxf(v.x, v.y), fmaxf(v.z, v.w));
    for (int off = 1; off <= 2; off <<= 1) mx = fmaxf(mx, __shfl_xor(mx, off, 16));
    float ss = expf(v.x - mx) + expf(v.y - mx) + expf(v.z - mx) + expf(v.w - mx);
    for (int off = 1; off <= 2; off <<= 1) ss += __shfl_xor(ss, off, 16);
    float ls = mx + logf(ss);
    if (eo == 0) {                      // one slot writes the quad (float4)
        float4 o;
        o.x = v.x - ls; o.y = v.y - ls; o.z = v.z - ls; o.w = v.w - ls;
        *(float4*)&out[(size_t)node * NCLASS + 4 * q] = o;
    }
}

// ======================= fallback path (R3 atomic version) =================

__global__ void zero_kernel(float* __restrict__ h, float* __restrict__ out) {
    int i = blockIdx.x * 256 + threadIdx.x;
    if (i < N_NODES * NHID) h[i] = 0.f;
    if (i < N_NODES * NCLASS) out[i] = 0.f;
}

__global__ void gemm1_kernel(const float* __restrict__ x,
                             const float* __restrict__ W1,
                             float* __restrict__ s1) {
    int node = blockIdx.x * 4 + (threadIdx.x >> 6);
    int col  = threadIdx.x & 63;
    if (node >= N_NODES) return;
    const float* xr = x + (size_t)node * NFEAT;
    float sum = 0.f;
#pragma unroll 8
    for (int k = 0; k < NFEAT; ++k)
        sum = fmaf(xr[k], W1[k * NHID + col], sum);
    s1[(size_t)node * NHID + col] = sum;
}

__global__ void spmm1_kernel(const int* __restrict__ src, const int* __restrict__ dst,
                             const float* __restrict__ w, const float* __restrict__ s1,
                             float* __restrict__ h) {
    int e = blockIdx.x * 4 + (threadIdx.x >> 6);
    if (e >= N_EDGES) return;
    int lane = threadIdx.x & 63;
    int s = min(max(src[e], 0), N_NODES - 1);
    int d = min(max(dst[e], 0), N_NODES - 1);
    float v = w[e] * s1[(size_t)s * NHID + lane];
    atomicAdd(&h[(size_t)d * NHID + lane], v);
}

__global__ void bias_relu_kernel(float* __restrict__ h, const float* __restrict__ b1) {
    int i = blockIdx.x * 256 + threadIdx.x;
    if (i >= N_NODES * NHID) return;
    float v = h[i] + b1[i & (NHID - 1)];
    h[i] = v > 0.f ? v : 0.f;
}

__global__ void gemm2_kernel(const float* __restrict__ h,
                             const float* __restrict__ W2,
                             float* __restrict__ s2) {
    int node = blockIdx.x * 16 + (threadIdx.x >> 4);
    int col  = threadIdx.x & 15;
    if (node >= N_NODES) return;
    const float* hr = h + (size_t)node * NHID;
    float sum = 0.f;
#pragma unroll 8
    for (int k = 0; k < NHID; ++k)
        sum = fmaf(hr[k], W2[k * NCLASS + col], sum);
    s2[(size_t)node * NCLASS + col] = sum;
}

__global__ void spmm2_kernel(const int* __restrict__ src, const int* __restrict__ dst,
                             const float* __restrict__ w, const float* __restrict__ s2,
                             float* __restrict__ out) {
    int e = blockIdx.x * 16 + (threadIdx.x >> 4);
    if (e >= N_EDGES) return;
    int lane = threadIdx.x & 15;
    int s = min(max(src[e], 0), N_NODES - 1);
    int d = min(max(dst[e], 0), N_NODES - 1);
    float v = w[e] * s2[(size_t)s * NCLASS + lane];
    atomicAdd(&out[(size_t)d * NCLASS + lane], v);
}

__global__ void logsoftmax_kernel(float* __restrict__ out, const float* __restrict__ b2) {
    int n = blockIdx.x * 256 + threadIdx.x;
    if (n >= N_NODES) return;
    float v[NCLASS];
    float mx = -INFINITY;
#pragma unroll
    for (int c = 0; c < NCLASS; ++c) {
        v[c] = out[(size_t)n * NCLASS + c] + b2[c];
        mx = fmaxf(mx, v[c]);
    }
    float ssum = 0.f;
#pragma unroll
    for (int c = 0; c < NCLASS; ++c) ssum += expf(v[c] - mx);
    float ls = mx + logf(ssum);
#pragma unroll
    for (int c = 0; c < NCLASS; ++c) out[(size_t)n * NCLASS + c] = v[c] - ls;
}

// ======================= launch ============================================

extern "C" void kernel_launch(void* const* d_in, const int* in_sizes, int n_in,
                              void* d_out, int out_size, void* d_ws, size_t ws_size,
                              hipStream_t stream) {
    if (n_in != 8) return;
    const int expected[8] = { N_NODES * NFEAT, NFEAT * NHID, NHID,
                              NHID * NCLASS, NCLASS, N_EDGES, N_EDGES, N_EDGES };
    for (int i = 0; i < 8; ++i)
        if (in_sizes[i] != expected[i]) return;
    if (out_size != N_NODES * NCLASS) return;

    const float* x  = (const float*)d_in[0];
    const float* W1 = (const float*)d_in[1];
    const float* b1 = (const float*)d_in[2];
    const float* W2 = (const float*)d_in[3];
    const float* b2 = (const float*)d_in[4];
    const int* edge_src = (const int*)d_in[5];
    const int* edge_dst = (const int*)d_in[6];
    const float* edge_w = (const float*)d_in[7];
    float* out = (float*)d_out;

    const size_t S1_ELTS = (size_t)N_NODES * NHID;          // 3.2M (ushorts)
    const size_t CAP_WORDS = (size_t)NBINS * BIN_CAP * 2;   // int2 region, words
    // layout (32-bit words) — fully DISJOINT (s1b live alongside csr_bin
    // inside sort_spmm1_fused):
    //   [0, CAP)          csr_bin    (16 MB)
    //   [CAP, 2CAP)       csr_edge   (16 MB)
    //   [2CAP, +2N)       row_range  (0.4 MB)
    //   [.., +512)        bin_cursor (391 ints + pad, keeps s1b 8B-aligned)
    //   [.., +S1/2)       s1b        (6.4 MB bf16)
    //   [.., +N*NCLASS)   s2         (3.2 MB fp32)
    const size_t NEW_WORDS = 2 * CAP_WORDS + 2 * (size_t)N_NODES + 512
                           + S1_ELTS / 2 + (size_t)N_NODES * NCLASS;
    if (ws_size >= NEW_WORDS * 4) {
        int2*  csr_bin    = (int2*)d_ws;
        int2*  csr_edge   = (int2*)((int*)d_ws + CAP_WORDS);
        int2*  row_range  = (int2*)((int*)d_ws + 2 * CAP_WORDS);
        int*   bin_cursor = (int*)d_ws + 2 * CAP_WORDS + 2 * (size_t)N_NODES;
        unsigned short* s1b =
            (unsigned short*)((int*)d_ws + 2 * CAP_WORDS + 2 * (size_t)N_NODES + 512);
        float* s2 = (float*)d_ws + 2 * CAP_WORDS + 2 * (size_t)N_NODES + 512
                  + S1_ELTS / 2;

        // gemm1 first: its block 0 zeroes bin_cursor (replaces memset dispatch)
        gemm1_tiled<<<(N_NODES + 63) / 64, 256, 0, stream>>>(x, W1, s1b, bin_cursor);
        bin_scatter_kernel<<<K3_BLOCKS, K3_THREADS, 0, stream>>>(
            edge_src, edge_dst, edge_w, bin_cursor, csr_bin);
        sort_spmm1_fused<<<NBINS, 1024, 0, stream>>>(
            bin_cursor, csr_bin, csr_edge, row_range,
            (const uint2*)s1b, b1, W2, s2);
        spmm2_csr_kernel<<<(N_NODES + 15) / 16, 256, 0, stream>>>(
            row_range, csr_edge, s2, b2, out);
        return;
    }

    // --- fallback: proven atomic path (25.6 MB ws) ---
    if (ws_size < 2 * S1_ELTS * sizeof(float)) return;
    float* s1 = (float*)d_ws;
    float* h  = s1 + S1_ELTS;
    float* s2 = s1;
    zero_kernel<<<(N_NODES * NHID + 255) / 256, 256, 0, stream>>>(h, out);
    gemm1_kernel<<<(N_NODES + 3) / 4, 256, 0, stream>>>(x, W1, s1);
    spmm1_kernel<<<(N_EDGES + 3) / 4, 256, 0, stream>>>(edge_src, edge_dst, edge_w, s1, h);
    bias_relu_kernel<<<(N_NODES * NHID + 255) / 256, 256, 0, stream>>>(h, b1);
    gemm2_kernel<<<(N_NODES + 15) / 16, 256, 0, stream>>>(h, W2, s2);
    spmm2_kernel<<<(N_EDGES + 15) / 16, 256, 0, stream>>>(edge_src, edge_dst, edge_w, s2, out);
    logsoftmax_kernel<<<(N_NODES + 255) / 256, 256, 0, stream>>>(out, b2);
}

// Round 14
// 189.258 us; speedup vs baseline: 1.2931x; 1.0670x over previous
//
#include <hip/hip_runtime.h>
#include <math.h>

#define N_NODES 50000
#define N_EDGES 1600000
#define NFEAT 256
#define NHID 64
#define NCLASS 16

#define PBITS 7
#define PNODES 128                       // nodes per bin (R5-proven geometry)
#define NBINS ((N_NODES + PNODES - 1) / PNODES)   // 391
#define BIN_CAP 5120                     // mean 4092, sigma 64 -> +16 sigma
#define K3_CHUNK 4096
#define K3_THREADS 512
#define K3_PER_T 8                       // 4096 / 512
#define K3_BLOCKS ((N_EDGES + K3_CHUNK - 1) / K3_CHUNK)  // 391
#define S_PER_T 5                        // ceil(BIN_CAP / 1024)

typedef __attribute__((ext_vector_type(8))) short bf16x8;
typedef __attribute__((ext_vector_type(4))) float f32x4;

__device__ inline unsigned short f2bf(float f) {     // RNE f32 -> bf16
    unsigned u = __float_as_uint(f);
    return (unsigned short)((u + 0x7FFFu + ((u >> 16) & 1u)) >> 16);
}

// ======================= bin scatter (counting sort, pass 1) ===============
// R10-proven 512-thread version. bin_cursor is COUNT-ONLY (zeroed by
// gemm1 block 0, which runs in the PRECEDING dispatch); slot base is
// b*BIN_CAP.
__global__ __launch_bounds__(512) void bin_scatter_kernel(
        const int* __restrict__ src, const int* __restrict__ dst,
        const float* __restrict__ w, int* __restrict__ bin_cursor,
        int2* __restrict__ csr_bin) {
    __shared__ int2 sdata[K3_CHUNK];                 // 32 KB
    __shared__ unsigned short sbinid[K3_CHUNK];      // 8 KB
    __shared__ int swhist[4][NBINS];                 // 6.1 KB (wave-pair priv)
    __shared__ int swcur[4][NBINS];                  // 6.1 KB
    __shared__ int stot[NBINS];
    __shared__ int lscan[NBINS];
    __shared__ int sbase[NBINS];
    __shared__ int stmp[512];
    int t = threadIdx.x;
    int wv = t >> 7;                                 // 4 hist copies, 2 waves ea
    int base_e = blockIdx.x * K3_CHUNK;

    for (int b = t; b < NBINS; b += K3_THREADS) {
        swhist[0][b] = 0; swhist[1][b] = 0; swhist[2][b] = 0; swhist[3][b] = 0;
    }
    __syncthreads();

    int2 myedge[K3_PER_T];
    short mybin[K3_PER_T];
#pragma unroll
    for (int k = 0; k < K3_PER_T; ++k) {
        int e = base_e + t + k * K3_THREADS;
        if (e < N_EDGES) {
            int d = min(max(dst[e], 0), N_NODES - 1);
            int s = min(max(src[e], 0), N_NODES - 1);
            int b = d >> PBITS;
            mybin[k] = (short)b;
            myedge[k] = make_int2((s << PBITS) | (d & (PNODES - 1)),
                                  __float_as_int(w[e]));
            atomicAdd(&swhist[wv][b], 1);
        } else mybin[k] = -1;
    }
    __syncthreads();
    {
        int v = 0;
        if (t < NBINS) {
            v = swhist[0][t] + swhist[1][t] + swhist[2][t] + swhist[3][t];
            stot[t] = v;
        }
        stmp[t] = v;
    }
    __syncthreads();
    for (int off = 1; off < 512; off <<= 1) {
        int v0 = (t >= off) ? stmp[t - off] : 0;
        __syncthreads();
        stmp[t] += v0;
        __syncthreads();
    }
    if (t < NBINS) {
        lscan[t] = stmp[t] - stot[t];
        int c = stot[t];
        // count-only cursor: global slot base is b*BIN_CAP + prior count
        if (c > 0) sbase[t] = t * BIN_CAP + atomicAdd(&bin_cursor[t], c);
        int run = lscan[t];
        swcur[0][t] = run; run += swhist[0][t];
        swcur[1][t] = run; run += swhist[1][t];
        swcur[2][t] = run; run += swhist[2][t];
        swcur[3][t] = run;
    }
    __syncthreads();
#pragma unroll
    for (int k = 0; k < K3_PER_T; ++k) {
        int b = mybin[k];
        if (b >= 0) {
            int p = atomicAdd(&swcur[wv][b], 1);
            sdata[p] = myedge[k];
            sbinid[p] = (unsigned short)b;
        }
    }
    __syncthreads();
    int cnt = min(N_EDGES - base_e, K3_CHUNK);
#pragma unroll
    for (int k = 0; k < K3_PER_T; ++k) {
        int p = t + k * K3_THREADS;
        if (p < cnt) {
            int b = sbinid[p];
            int idx = sbase[b] + (p - lscan[b]);
            idx = min(idx, (b + 1) * BIN_CAP - 1);   // overflow-safe (no fault)
            csr_bin[idx] = sdata[p];
        }
    }
}

// ======================= dense GEMM 1 — MFMA (R14) =========================
// bf16 MFMA 16x16x32. W1^T staged once to padded LDS (b128 fragment reads,
// 2-way bank conflict = free). Per wave: 16 nodes x 64 cols, K-loop 8x32,
// 4 MFMAs/chunk. A/B use canonical CDNA lane maps (A row=lane&15,
// B col=lane&15, k-slot 8*(lane>>4)+i); any consistent k-permutation of both
// operands leaves the contraction invariant. C/D map is the HW-verified
// col=lane&15, row=(lane>>4)*4+r. Block 0 zeroes bin_cursor (R11 fold).
__global__ __launch_bounds__(256) void gemm1_mfma(
        const float* __restrict__ x, const float* __restrict__ W1,
        unsigned short* __restrict__ s1b, int* __restrict__ bin_cursor) {
    __shared__ unsigned short w1t[64][264];          // W1^T bf16, 33.8 KB
    int t = threadIdx.x;
    if (blockIdx.x == 0)
        for (int i = t; i < NBINS; i += 256) bin_cursor[i] = 0;
    for (int i = t; i < NFEAT * NHID; i += 256) {    // stage W1^T
        int k = i >> 6, c = i & 63;
        w1t[c][k] = f2bf(W1[(size_t)k * NHID + c]);
    }
    __syncthreads();

    int wave = t >> 6, lane = t & 63;
    int m  = lane & 15;                              // A row / B col / D col
    int kg = lane >> 4;                              // k-group 0..3
    int arow = blockIdx.x * 64 + wave * 16 + m;
    const float* xrow = x + (size_t)min(arow, N_NODES - 1) * NFEAT;

    f32x4 ac0 = {0.f,0.f,0.f,0.f}, ac1 = {0.f,0.f,0.f,0.f};
    f32x4 ac2 = {0.f,0.f,0.f,0.f}, ac3 = {0.f,0.f,0.f,0.f};
#pragma unroll
    for (int k0 = 0; k0 < NFEAT; k0 += 32) {
        float4 xa = *(const float4*)(xrow + k0 + 8 * kg);
        float4 xb = *(const float4*)(xrow + k0 + 8 * kg + 4);
        bf16x8 af;
        af[0] = (short)f2bf(xa.x); af[1] = (short)f2bf(xa.y);
        af[2] = (short)f2bf(xa.z); af[3] = (short)f2bf(xa.w);
        af[4] = (short)f2bf(xb.x); af[5] = (short)f2bf(xb.y);
        af[6] = (short)f2bf(xb.z); af[7] = (short)f2bf(xb.w);
        bf16x8 b0 = *(const bf16x8*)&w1t[m +  0][k0 + 8 * kg];
        bf16x8 b1 = *(const bf16x8*)&w1t[m + 16][k0 + 8 * kg];
        bf16x8 b2 = *(const bf16x8*)&w1t[m + 32][k0 + 8 * kg];
        bf16x8 b3 = *(const bf16x8*)&w1t[m + 48][k0 + 8 * kg];
        ac0 = __builtin_amdgcn_mfma_f32_16x16x32_bf16(af, b0, ac0, 0, 0, 0);
        ac1 = __builtin_amdgcn_mfma_f32_16x16x32_bf16(af, b1, ac1, 0, 0, 0);
        ac2 = __builtin_amdgcn_mfma_f32_16x16x32_bf16(af, b2, ac2, 0, 0, 0);
        ac3 = __builtin_amdgcn_mfma_f32_16x16x32_bf16(af, b3, ac3, 0, 0, 0);
    }
    // D(lane, r) = tile[row = 4*kg + r][col = m]
    int obase = blockIdx.x * 64 + wave * 16 + 4 * kg;
#pragma unroll
    for (int r = 0; r < 4; ++r) {
        int n = obase + r;
        if (n < N_NODES) {
            unsigned short* op = &s1b[(size_t)n * NHID];
            op[m]      = f2bf(ac0[r]);
            op[m + 16] = f2bf(ac1[r]);
            op[m + 32] = f2bf(ac2[r]);
            op[m + 48] = f2bf(ac3[r]);
        }
    }
}

// ============ fused per-bin sort + SpMM1 + bias/ReLU + GEMM2 ===============
// R12 version (reg-cached hist edges; bit-identical placement to R5).
__global__ __launch_bounds__(1024, 4) void sort_spmm1_fused(
        const int* __restrict__ bin_cursor, const int2* __restrict__ csr_bin,
        int2* __restrict__ csr_edge, int2* __restrict__ row_range,
        const uint2* __restrict__ s1p2, const float* __restrict__ b1,
        const float* __restrict__ W2, float* __restrict__ s2) {
    __shared__ int2 sdata[BIN_CAP];                  // 40 KB sorted edges
    __shared__ union {
        struct { int whist[16][PNODES]; int wcur[16][PNODES]; } c;  // 16 KB
        float hsh[64][64];                                          // 16 KB
    } u;
    __shared__ int ltot[PNODES];
    __shared__ int ltmp[PNODES];
    __shared__ float W2s[NHID * NCLASS];             // 4 KB
    __shared__ float b1s[NHID];
    int t = threadIdx.x;
    int wv = t >> 6;                                 // 16 waves
    int b = blockIdx.x;
    int base = b * BIN_CAP;
    int cnt = min(bin_cursor[b], BIN_CAP);

    for (int i = t; i < 16 * PNODES; i += 1024) ((int*)u.c.whist)[i] = 0;
    if (t < NHID * NCLASS) W2s[t] = W2[t];
    if (t < NHID) b1s[t] = b1[t];
    __syncthreads();

    // --- hist pass: load each thread's edges ONCE, keep in registers ---
    int2 myed[S_PER_T];
#pragma unroll
    for (int k = 0; k < S_PER_T; ++k) {
        int j = t + k * 1024;
        if (j < cnt) {
            int2 e0 = csr_bin[base + j];
            myed[k] = e0;
            atomicAdd(&u.c.whist[wv][e0.x & (PNODES - 1)], 1);
        }
    }
    __syncthreads();
    if (t < PNODES) {
        int v = 0;
#pragma unroll
        for (int k = 0; k < 16; ++k) v += u.c.whist[k][t];
        ltot[t] = v; ltmp[t] = v;
    }
    __syncthreads();
    for (int off = 1; off < PNODES; off <<= 1) {
        int a = 0;
        if (t < PNODES && t >= off) a = ltmp[t - off];
        __syncthreads();
        if (t < PNODES) ltmp[t] += a;
        __syncthreads();
    }
    if (t < PNODES) {
        int begl = ltmp[t] - ltot[t];                // local (0-based in bin)
        int node = b * PNODES + t;
        if (node < N_NODES)
            row_range[node] = make_int2(base + begl, base + ltmp[t]);
        int run = begl;
#pragma unroll
        for (int k = 0; k < 16; ++k) { u.c.wcur[k][t] = run; run += u.c.whist[k][t]; }
    }
    __syncthreads();
    // --- scatter pass: sorted (src, w) into LDS, from registers ---
#pragma unroll
    for (int k = 0; k < S_PER_T; ++k) {
        int j = t + k * 1024;
        if (j < cnt) {
            int2 e0 = myed[k];
            int p0 = atomicAdd(&u.c.wcur[wv][e0.x & (PNODES - 1)], 1);
            sdata[p0] = make_int2(e0.x >> PBITS, e0.y);
        }
    }
    __syncthreads();
    // --- coalesced writeback for spmm2 ---
    for (int i = t; i < cnt; i += 1024) csr_edge[base + i] = sdata[i];

    // --- spmm1 + bias/ReLU + gemm2, 64 node-groups x 16 lanes, 2 rounds ---
    int g = t >> 4, lane = t & 15;
#pragma unroll
    for (int round = 0; round < 2; ++round) {
        int nl = g + 64 * round;
        int node = b * PNODES + nl;
        if (node >= N_NODES) continue;
        int endl = ltmp[nl];
        int j = endl - ltot[nl];
        float4 accA = {0.f, 0.f, 0.f, 0.f}, accB = {0.f, 0.f, 0.f, 0.f};
        for (; j + 7 < endl; j += 8) {
            int2 e0 = sdata[j],     e1 = sdata[j + 1];
            int2 e2 = sdata[j + 2], e3 = sdata[j + 3];
            int2 e4 = sdata[j + 4], e5 = sdata[j + 5];
            int2 e6 = sdata[j + 6], e7 = sdata[j + 7];
            uint2 v0 = s1p2[(size_t)e0.x * 16 + lane];
            uint2 v1 = s1p2[(size_t)e1.x * 16 + lane];
            uint2 v2 = s1p2[(size_t)e2.x * 16 + lane];
            uint2 v3 = s1p2[(size_t)e3.x * 16 + lane];
            uint2 v4 = s1p2[(size_t)e4.x * 16 + lane];
            uint2 v5 = s1p2[(size_t)e5.x * 16 + lane];
            uint2 v6 = s1p2[(size_t)e6.x * 16 + lane];
            uint2 v7 = s1p2[(size_t)e7.x * 16 + lane];
            float w0 = __int_as_float(e0.y), w1 = __int_as_float(e1.y);
            float w2 = __int_as_float(e2.y), w3 = __int_as_float(e3.y);
            float w4 = __int_as_float(e4.y), w5 = __int_as_float(e5.y);
            float w6 = __int_as_float(e6.y), w7 = __int_as_float(e7.y);
            accA.x = fmaf(w0, __uint_as_float(v0.x << 16), accA.x);
            accA.y = fmaf(w0, __uint_as_float(v0.x & 0xFFFF0000u), accA.y);
            accA.z = fmaf(w0, __uint_as_float(v0.y << 16), accA.z);
            accA.w = fmaf(w0, __uint_as_float(v0.y & 0xFFFF0000u), accA.w);
            accB.x = fmaf(w1, __uint_as_float(v1.x << 16), accB.x);
            accB.y = fmaf(w1, __uint_as_float(v1.x & 0xFFFF0000u), accB.y);
            accB.z = fmaf(w1, __uint_as_float(v1.y << 16), accB.z);
            accB.w = fmaf(w1, __uint_as_float(v1.y & 0xFFFF0000u), accB.w);
            accA.x = fmaf(w2, __uint_as_float(v2.x << 16), accA.x);
            accA.y = fmaf(w2, __uint_as_float(v2.x & 0xFFFF0000u), accA.y);
            accA.z = fmaf(w2, __uint_as_float(v2.y << 16), accA.z);
            accA.w = fmaf(w2, __uint_as_float(v2.y & 0xFFFF0000u), accA.w);
            accB.x = fmaf(w3, __uint_as_float(v3.x << 16), accB.x);
            accB.y = fmaf(w3, __uint_as_float(v3.x & 0xFFFF0000u), accB.y);
            accB.z = fmaf(w3, __uint_as_float(v3.y << 16), accB.z);
            accB.w = fmaf(w3, __uint_as_float(v3.y & 0xFFFF0000u), accB.w);
            accA.x = fmaf(w4, __uint_as_float(v4.x << 16), accA.x);
            accA.y = fmaf(w4, __uint_as_float(v4.x & 0xFFFF0000u), accA.y);
            accA.z = fmaf(w4, __uint_as_float(v4.y << 16), accA.z);
            accA.w = fmaf(w4, __uint_as_float(v4.y & 0xFFFF0000u), accA.w);
            accB.x = fmaf(w5, __uint_as_float(v5.x << 16), accB.x);
            accB.y = fmaf(w5, __uint_as_float(v5.x & 0xFFFF0000u), accB.y);
            accB.z = fmaf(w5, __uint_as_float(v5.y << 16), accB.z);
            accB.w = fmaf(w5, __uint_as_float(v5.y & 0xFFFF0000u), accB.w);
            accA.x = fmaf(w6, __uint_as_float(v6.x << 16), accA.x);
            accA.y = fmaf(w6, __uint_as_float(v6.x & 0xFFFF0000u), accA.y);
            accA.z = fmaf(w6, __uint_as_float(v6.y << 16), accA.z);
            accA.w = fmaf(w6, __uint_as_float(v6.y & 0xFFFF0000u), accA.w);
            accB.x = fmaf(w7, __uint_as_float(v7.x << 16), accB.x);
            accB.y = fmaf(w7, __uint_as_float(v7.x & 0xFFFF0000u), accB.y);
            accB.z = fmaf(w7, __uint_as_float(v7.y << 16), accB.z);
            accB.w = fmaf(w7, __uint_as_float(v7.y & 0xFFFF0000u), accB.w);
        }
        for (; j < endl; ++j) {
            int2 e0 = sdata[j];
            uint2 v0 = s1p2[(size_t)e0.x * 16 + lane];
            float w0 = __int_as_float(e0.y);
            accA.x = fmaf(w0, __uint_as_float(v0.x << 16), accA.x);
            accA.y = fmaf(w0, __uint_as_float(v0.x & 0xFFFF0000u), accA.y);
            accA.z = fmaf(w0, __uint_as_float(v0.y << 16), accA.z);
            accA.w = fmaf(w0, __uint_as_float(v0.y & 0xFFFF0000u), accA.w);
        }
        float4 bb = *(const float4*)&b1s[4 * lane];
        float4 hv;
        hv.x = accA.x + accB.x + bb.x;
        hv.y = accA.y + accB.y + bb.y;
        hv.z = accA.z + accB.z + bb.z;
        hv.w = accA.w + accB.w + bb.w;
        hv.x = hv.x > 0.f ? hv.x : 0.f;
        hv.y = hv.y > 0.f ? hv.y : 0.f;
        hv.z = hv.z > 0.f ? hv.z : 0.f;
        hv.w = hv.w > 0.f ? hv.w : 0.f;
        // same-wave LDS park (lockstep within wave, no barrier needed)
        *(float4*)&u.hsh[g][4 * lane] = hv;
        float acc = 0.f;
#pragma unroll 16
        for (int k = 0; k < NHID; ++k)
            acc = fmaf(u.hsh[g][k], W2s[k * NCLASS + lane], acc);
        s2[(size_t)node * NCLASS + lane] = acc;
    }
}

// ======================= SpMM2 + bias + log_softmax ========================
// R13: 4 lanes/edge x 4 edges/iter with float4 s2 gathers; shfl_xor tree
// reductions; one float4 store per quad.
__global__ void spmm2_csr_kernel(const int2* __restrict__ row_range,
                                 const int2* __restrict__ csr_edge,
                                 const float* __restrict__ s2,
                                 const float* __restrict__ b2,
                                 float* __restrict__ out) {
    int node = blockIdx.x * 16 + (threadIdx.x >> 4);
    if (node >= N_NODES) return;
    int l  = threadIdx.x & 15;
    int eo = l >> 2;                    // edge slot within quad (0..3)
    int q  = l & 3;                     // class quad: classes 4q..4q+3
    int2 rr = row_range[node];
    int beg = rr.x, end = rr.y;
    float4 accA = {0.f, 0.f, 0.f, 0.f}, accB = {0.f, 0.f, 0.f, 0.f};
    int j = beg;
    for (; j + 7 < end; j += 8) {       // 8 edges: two quads in flight
        int2 eA = csr_edge[j + eo];
        int2 eB = csr_edge[j + 4 + eo];
        float4 vA = *(const float4*)&s2[(size_t)eA.x * NCLASS + 4 * q];
        float4 vB = *(const float4*)&s2[(size_t)eB.x * NCLASS + 4 * q];
        float wA = __int_as_float(eA.y), wB = __int_as_float(eB.y);
        accA.x = fmaf(wA, vA.x, accA.x);
        accA.y = fmaf(wA, vA.y, accA.y);
        accA.z = fmaf(wA, vA.z, accA.z);
        accA.w = fmaf(wA, vA.w, accA.w);
        accB.x = fmaf(wB, vB.x, accB.x);
        accB.y = fmaf(wB, vB.y, accB.y);
        accB.z = fmaf(wB, vB.z, accB.z);
        accB.w = fmaf(wB, vB.w, accB.w);
    }
    for (; j + 3 < end; j += 4) {       // 4-edge quad
        int2 eA = csr_edge[j + eo];
        float4 vA = *(const float4*)&s2[(size_t)eA.x * NCLASS + 4 * q];
        float wA = __int_as_float(eA.y);
        accA.x = fmaf(wA, vA.x, accA.x);
        accA.y = fmaf(wA, vA.y, accA.y);
        accA.z = fmaf(wA, vA.z, accA.z);
        accA.w = fmaf(wA, vA.w, accA.w);
    }
    {                                   // tail: 0-3 edges, slot eo < rem
        int rem = end - j;
        if (eo < rem) {
            int2 eA = csr_edge[j + eo];
            float4 vA = *(const float4*)&s2[(size_t)eA.x * NCLASS + 4 * q];
            float wA = __int_as_float(eA.y);
            accB.x = fmaf(wA, vA.x, accB.x);
            accB.y = fmaf(wA, vA.y, accB.y);
            accB.z = fmaf(wA, vA.z, accB.z);
            accB.w = fmaf(wA, vA.w, accB.w);
        }
    }
    float4 v;
    v.x = accA.x + accB.x; v.y = accA.y + accB.y;
    v.z = accA.z + accB.z; v.w = accA.w + accB.w;
    // reduce across the 4 edge slots (lanes differing in bits 2-3 of l)
    for (int off = 4; off <= 8; off <<= 1) {
        v.x += __shfl_xor(v.x, off, 16);
        v.y += __shfl_xor(v.y, off, 16);
        v.z += __shfl_xor(v.z, off, 16);
        v.w += __shfl_xor(v.w, off, 16);
    }
    float4 bv = *(const float4*)&b2[4 * q];
    v.x += bv.x; v.y += bv.y; v.z += bv.z; v.w += bv.w;
    // log_softmax over 16 classes: in-lane max/sum of the quad, then across q
    float mx = fmaxf(fmaxf(v.x, v.y), fmaxf(v.z, v.w));
    for (int off = 1; off <= 2; off <<= 1) mx = fmaxf(mx, __shfl_xor(mx, off, 16));
    float ss = expf(v.x - mx) + expf(v.y - mx) + expf(v.z - mx) + expf(v.w - mx);
    for (int off = 1; off <= 2; off <<= 1) ss += __shfl_xor(ss, off, 16);
    float ls = mx + logf(ss);
    if (eo == 0) {                      // one slot writes the quad (float4)
        float4 o;
        o.x = v.x - ls; o.y = v.y - ls; o.z = v.z - ls; o.w = v.w - ls;
        *(float4*)&out[(size_t)node * NCLASS + 4 * q] = o;
    }
}

// ======================= fallback path (R3 atomic version) =================

__global__ void zero_kernel(float* __restrict__ h, float* __restrict__ out) {
    int i = blockIdx.x * 256 + threadIdx.x;
    if (i < N_NODES * NHID) h[i] = 0.f;
    if (i < N_NODES * NCLASS) out[i] = 0.f;
}

__global__ void gemm1_kernel(const float* __restrict__ x,
                             const float* __restrict__ W1,
                             float* __restrict__ s1) {
    int node = blockIdx.x * 4 + (threadIdx.x >> 6);
    int col  = threadIdx.x & 63;
    if (node >= N_NODES) return;
    const float* xr = x + (size_t)node * NFEAT;
    float sum = 0.f;
#pragma unroll 8
    for (int k = 0; k < NFEAT; ++k)
        sum = fmaf(xr[k], W1[k * NHID + col], sum);
    s1[(size_t)node * NHID + col] = sum;
}

__global__ void spmm1_kernel(const int* __restrict__ src, const int* __restrict__ dst,
                             const float* __restrict__ w, const float* __restrict__ s1,
                             float* __restrict__ h) {
    int e = blockIdx.x * 4 + (threadIdx.x >> 6);
    if (e >= N_EDGES) return;
    int lane = threadIdx.x & 63;
    int s = min(max(src[e], 0), N_NODES - 1);
    int d = min(max(dst[e], 0), N_NODES - 1);
    float v = w[e] * s1[(size_t)s * NHID + lane];
    atomicAdd(&h[(size_t)d * NHID + lane], v);
}

__global__ void bias_relu_kernel(float* __restrict__ h, const float* __restrict__ b1) {
    int i = blockIdx.x * 256 + threadIdx.x;
    if (i >= N_NODES * NHID) return;
    float v = h[i] + b1[i & (NHID - 1)];
    h[i] = v > 0.f ? v : 0.f;
}

__global__ void gemm2_kernel(const float* __restrict__ h,
                             const float* __restrict__ W2,
                             float* __restrict__ s2) {
    int node = blockIdx.x * 16 + (threadIdx.x >> 4);
    int col  = threadIdx.x & 15;
    if (node >= N_NODES) return;
    const float* hr = h + (size_t)node * NHID;
    float sum = 0.f;
#pragma unroll 8
    for (int k = 0; k < NHID; ++k)
        sum = fmaf(hr[k], W2[k * NCLASS + col], sum);
    s2[(size_t)node * NCLASS + col] = sum;
}

__global__ void spmm2_kernel(const int* __restrict__ src, const int* __restrict__ dst,
                             const float* __restrict__ w, const float* __restrict__ s2,
                             float* __restrict__ out) {
    int e = blockIdx.x * 16 + (threadIdx.x >> 4);
    if (e >= N_EDGES) return;
    int lane = threadIdx.x & 15;
    int s = min(max(src[e], 0), N_NODES - 1);
    int d = min(max(dst[e], 0), N_NODES - 1);
    float v = w[e] * s2[(size_t)s * NCLASS + lane];
    atomicAdd(&out[(size_t)d * NCLASS + lane], v);
}

__global__ void logsoftmax_kernel(float* __restrict__ out, const float* __restrict__ b2) {
    int n = blockIdx.x * 256 + threadIdx.x;
    if (n >= N_NODES) return;
    float v[NCLASS];
    float mx = -INFINITY;
#pragma unroll
    for (int c = 0; c < NCLASS; ++c) {
        v[c] = out[(size_t)n * NCLASS + c] + b2[c];
        mx = fmaxf(mx, v[c]);
    }
    float ssum = 0.f;
#pragma unroll
    for (int c = 0; c < NCLASS; ++c) ssum += expf(v[c] - mx);
    float ls = mx + logf(ssum);
#pragma unroll
    for (int c = 0; c < NCLASS; ++c) out[(size_t)n * NCLASS + c] = v[c] - ls;
}

// ======================= launch ============================================

extern "C" void kernel_launch(void* const* d_in, const int* in_sizes, int n_in,
                              void* d_out, int out_size, void* d_ws, size_t ws_size,
                              hipStream_t stream) {
    if (n_in != 8) return;
    const int expected[8] = { N_NODES * NFEAT, NFEAT * NHID, NHID,
                              NHID * NCLASS, NCLASS, N_EDGES, N_EDGES, N_EDGES };
    for (int i = 0; i < 8; ++i)
        if (in_sizes[i] != expected[i]) return;
    if (out_size != N_NODES * NCLASS) return;

    const float* x  = (const float*)d_in[0];
    const float* W1 = (const float*)d_in[1];
    const float* b1 = (const float*)d_in[2];
    const float* W2 = (const float*)d_in[3];
    const float* b2 = (const float*)d_in[4];
    const int* edge_src = (const int*)d_in[5];
    const int* edge_dst = (const int*)d_in[6];
    const float* edge_w = (const float*)d_in[7];
    float* out = (float*)d_out;

    const size_t S1_ELTS = (size_t)N_NODES * NHID;          // 3.2M (ushorts)
    const size_t CAP_WORDS = (size_t)NBINS * BIN_CAP * 2;   // int2 region, words
    // layout (32-bit words) — fully DISJOINT (s1b live alongside csr_bin
    // inside sort_spmm1_fused):
    //   [0, CAP)          csr_bin    (16 MB)
    //   [CAP, 2CAP)       csr_edge   (16 MB)
    //   [2CAP, +2N)       row_range  (0.4 MB)
    //   [.., +512)        bin_cursor (391 ints + pad, keeps s1b 8B-aligned)
    //   [.., +S1/2)       s1b        (6.4 MB bf16)
    //   [.., +N*NCLASS)   s2         (3.2 MB fp32)
    const size_t NEW_WORDS = 2 * CAP_WORDS + 2 * (size_t)N_NODES + 512
                           + S1_ELTS / 2 + (size_t)N_NODES * NCLASS;
    if (ws_size >= NEW_WORDS * 4) {
        int2*  csr_bin    = (int2*)d_ws;
        int2*  csr_edge   = (int2*)((int*)d_ws + CAP_WORDS);
        int2*  row_range  = (int2*)((int*)d_ws + 2 * CAP_WORDS);
        int*   bin_cursor = (int*)d_ws + 2 * CAP_WORDS + 2 * (size_t)N_NODES;
        unsigned short* s1b =
            (unsigned short*)((int*)d_ws + 2 * CAP_WORDS + 2 * (size_t)N_NODES + 512);
        float* s2 = (float*)d_ws + 2 * CAP_WORDS + 2 * (size_t)N_NODES + 512
                  + S1_ELTS / 2;

        // gemm1 first: its block 0 zeroes bin_cursor (replaces memset dispatch)
        gemm1_mfma<<<(N_NODES + 63) / 64, 256, 0, stream>>>(x, W1, s1b, bin_cursor);
        bin_scatter_kernel<<<K3_BLOCKS, K3_THREADS, 0, stream>>>(
            edge_src, edge_dst, edge_w, bin_cursor, csr_bin);
        sort_spmm1_fused<<<NBINS, 1024, 0, stream>>>(
            bin_cursor, csr_bin, csr_edge, row_range,
            (const uint2*)s1b, b1, W2, s2);
        spmm2_csr_kernel<<<(N_NODES + 15) / 16, 256, 0, stream>>>(
            row_range, csr_edge, s2, b2, out);
        return;
    }

    // --- fallback: proven atomic path (25.6 MB ws) ---
    if (ws_size < 2 * S1_ELTS * sizeof(float)) return;
    float* s1 = (float*)d_ws;
    float* h  = s1 + S1_ELTS;
    float* s2 = s1;
    zero_kernel<<<(N_NODES * NHID + 255) / 256, 256, 0, stream>>>(h, out);
    gemm1_kernel<<<(N_NODES + 3) / 4, 256, 0, stream>>>(x, W1, s1);
    spmm1_kernel<<<(N_EDGES + 3) / 4, 256, 0, stream>>>(edge_src, edge_dst, edge_w, s1, h);
    bias_relu_kernel<<<(N_NODES * NHID + 255) / 256, 256, 0, stream>>>(h, b1);
    gemm2_kernel<<<(N_NODES + 15) / 16, 256, 0, stream>>>(h, W2, s2);
    spmm2_kernel<<<(N_EDGES + 15) / 16, 256, 0, stream>>>(edge_src, edge_dst, edge_w, s2, out);
    logsoftmax_kernel<<<(N_NODES + 255) / 256, 256, 0, stream>>>(out, b2);
}

// Round 15
// 179.007 us; speedup vs baseline: 1.3671x; 1.0573x over previous
//
#include <hip/hip_runtime.h>
#include <math.h>

#define N_NODES 50000
#define N_EDGES 1600000
#define NFEAT 256
#define NHID 64
#define NCLASS 16

#define PBITS 7
#define PNODES 128                       // nodes per bin (R5-proven geometry)
#define NBINS ((N_NODES + PNODES - 1) / PNODES)   // 391
#define BIN_CAP 5120                     // mean 4092, sigma 64 -> +16 sigma
#define K3_CHUNK 4096
#define K3_THREADS 512
#define K3_PER_T 8                       // 4096 / 512
#define K3_BLOCKS ((N_EDGES + K3_CHUNK - 1) / K3_CHUNK)  // 391
#define S_PER_T 5                        // ceil(BIN_CAP / 1024)

typedef __attribute__((ext_vector_type(8))) short bf16x8;
typedef __attribute__((ext_vector_type(4))) float f32x4;

__device__ inline unsigned short f2bf(float f) {     // RNE f32 -> bf16
    unsigned u = __float_as_uint(f);
    return (unsigned short)((u + 0x7FFFu + ((u >> 16) & 1u)) >> 16);
}

// ======================= bin scatter (counting sort, pass 1) ===============
// R10-proven 512-thread version. bin_cursor is COUNT-ONLY (zeroed by
// gemm1 block 0, which runs in the PRECEDING dispatch); slot base is
// b*BIN_CAP.
__global__ __launch_bounds__(512) void bin_scatter_kernel(
        const int* __restrict__ src, const int* __restrict__ dst,
        const float* __restrict__ w, int* __restrict__ bin_cursor,
        int2* __restrict__ csr_bin) {
    __shared__ int2 sdata[K3_CHUNK];                 // 32 KB
    __shared__ unsigned short sbinid[K3_CHUNK];      // 8 KB
    __shared__ int swhist[4][NBINS];                 // 6.1 KB (wave-pair priv)
    __shared__ int swcur[4][NBINS];                  // 6.1 KB
    __shared__ int stot[NBINS];
    __shared__ int lscan[NBINS];
    __shared__ int sbase[NBINS];
    __shared__ int stmp[512];
    int t = threadIdx.x;
    int wv = t >> 7;                                 // 4 hist copies, 2 waves ea
    int base_e = blockIdx.x * K3_CHUNK;

    for (int b = t; b < NBINS; b += K3_THREADS) {
        swhist[0][b] = 0; swhist[1][b] = 0; swhist[2][b] = 0; swhist[3][b] = 0;
    }
    __syncthreads();

    int2 myedge[K3_PER_T];
    short mybin[K3_PER_T];
#pragma unroll
    for (int k = 0; k < K3_PER_T; ++k) {
        int e = base_e + t + k * K3_THREADS;
        if (e < N_EDGES) {
            int d = min(max(dst[e], 0), N_NODES - 1);
            int s = min(max(src[e], 0), N_NODES - 1);
            int b = d >> PBITS;
            mybin[k] = (short)b;
            myedge[k] = make_int2((s << PBITS) | (d & (PNODES - 1)),
                                  __float_as_int(w[e]));
            atomicAdd(&swhist[wv][b], 1);
        } else mybin[k] = -1;
    }
    __syncthreads();
    {
        int v = 0;
        if (t < NBINS) {
            v = swhist[0][t] + swhist[1][t] + swhist[2][t] + swhist[3][t];
            stot[t] = v;
        }
        stmp[t] = v;
    }
    __syncthreads();
    for (int off = 1; off < 512; off <<= 1) {
        int v0 = (t >= off) ? stmp[t - off] : 0;
        __syncthreads();
        stmp[t] += v0;
        __syncthreads();
    }
    if (t < NBINS) {
        lscan[t] = stmp[t] - stot[t];
        int c = stot[t];
        // count-only cursor: global slot base is b*BIN_CAP + prior count
        if (c > 0) sbase[t] = t * BIN_CAP + atomicAdd(&bin_cursor[t], c);
        int run = lscan[t];
        swcur[0][t] = run; run += swhist[0][t];
        swcur[1][t] = run; run += swhist[1][t];
        swcur[2][t] = run; run += swhist[2][t];
        swcur[3][t] = run;
    }
    __syncthreads();
#pragma unroll
    for (int k = 0; k < K3_PER_T; ++k) {
        int b = mybin[k];
        if (b >= 0) {
            int p = atomicAdd(&swcur[wv][b], 1);
            sdata[p] = myedge[k];
            sbinid[p] = (unsigned short)b;
        }
    }
    __syncthreads();
    int cnt = min(N_EDGES - base_e, K3_CHUNK);
#pragma unroll
    for (int k = 0; k < K3_PER_T; ++k) {
        int p = t + k * K3_THREADS;
        if (p < cnt) {
            int b = sbinid[p];
            int idx = sbase[b] + (p - lscan[b]);
            idx = min(idx, (b + 1) * BIN_CAP - 1);   // overflow-safe (no fault)
            csr_bin[idx] = sdata[p];
        }
    }
}

// ======================= dense GEMM 1 — MFMA (R14-proven) ==================
__global__ __launch_bounds__(256) void gemm1_mfma(
        const float* __restrict__ x, const float* __restrict__ W1,
        unsigned short* __restrict__ s1b, int* __restrict__ bin_cursor) {
    __shared__ unsigned short w1t[64][264];          // W1^T bf16, 33.8 KB
    int t = threadIdx.x;
    if (blockIdx.x == 0)
        for (int i = t; i < NBINS; i += 256) bin_cursor[i] = 0;
    for (int i = t; i < NFEAT * NHID; i += 256) {    // stage W1^T
        int k = i >> 6, c = i & 63;
        w1t[c][k] = f2bf(W1[(size_t)k * NHID + c]);
    }
    __syncthreads();

    int wave = t >> 6, lane = t & 63;
    int m  = lane & 15;                              // A row / B col / D col
    int kg = lane >> 4;                              // k-group 0..3
    int arow = blockIdx.x * 64 + wave * 16 + m;
    const float* xrow = x + (size_t)min(arow, N_NODES - 1) * NFEAT;

    f32x4 ac0 = {0.f,0.f,0.f,0.f}, ac1 = {0.f,0.f,0.f,0.f};
    f32x4 ac2 = {0.f,0.f,0.f,0.f}, ac3 = {0.f,0.f,0.f,0.f};
#pragma unroll
    for (int k0 = 0; k0 < NFEAT; k0 += 32) {
        float4 xa = *(const float4*)(xrow + k0 + 8 * kg);
        float4 xb = *(const float4*)(xrow + k0 + 8 * kg + 4);
        bf16x8 af;
        af[0] = (short)f2bf(xa.x); af[1] = (short)f2bf(xa.y);
        af[2] = (short)f2bf(xa.z); af[3] = (short)f2bf(xa.w);
        af[4] = (short)f2bf(xb.x); af[5] = (short)f2bf(xb.y);
        af[6] = (short)f2bf(xb.z); af[7] = (short)f2bf(xb.w);
        bf16x8 b0 = *(const bf16x8*)&w1t[m +  0][k0 + 8 * kg];
        bf16x8 b1 = *(const bf16x8*)&w1t[m + 16][k0 + 8 * kg];
        bf16x8 b2 = *(const bf16x8*)&w1t[m + 32][k0 + 8 * kg];
        bf16x8 b3 = *(const bf16x8*)&w1t[m + 48][k0 + 8 * kg];
        ac0 = __builtin_amdgcn_mfma_f32_16x16x32_bf16(af, b0, ac0, 0, 0, 0);
        ac1 = __builtin_amdgcn_mfma_f32_16x16x32_bf16(af, b1, ac1, 0, 0, 0);
        ac2 = __builtin_amdgcn_mfma_f32_16x16x32_bf16(af, b2, ac2, 0, 0, 0);
        ac3 = __builtin_amdgcn_mfma_f32_16x16x32_bf16(af, b3, ac3, 0, 0, 0);
    }
    // D(lane, r) = tile[row = 4*kg + r][col = m]
    int obase = blockIdx.x * 64 + wave * 16 + 4 * kg;
#pragma unroll
    for (int r = 0; r < 4; ++r) {
        int n = obase + r;
        if (n < N_NODES) {
            unsigned short* op = &s1b[(size_t)n * NHID];
            op[m]      = f2bf(ac0[r]);
            op[m + 16] = f2bf(ac1[r]);
            op[m + 32] = f2bf(ac2[r]);
            op[m + 48] = f2bf(ac3[r]);
        }
    }
}

// ============ fused per-bin sort + SpMM1 + bias/ReLU + GEMM2 ===============
// R15: gather is 8 lanes/node x uint4 (8 bf16 cols/lane) -> per-edge VMEM
// and LDS-read instruction counts HALVED vs 16-lane/uint2; one round (128
// groups cover all 128 nodes; no round-2 tail). GEMM2 now in registers:
// 16 class-partials per lane, shfl_xor(1,2,4) butterfly within the 8-lane
// group, lane sub writes classes {2sub,2sub+1} via compile-time select.
// W2s padded to stride 17 -> 2-way bank conflict (free). hsh deleted.
__global__ __launch_bounds__(1024, 8) void sort_spmm1_fused(
        const int* __restrict__ bin_cursor, const int2* __restrict__ csr_bin,
        int2* __restrict__ csr_edge, int2* __restrict__ row_range,
        const uint4* __restrict__ s1p4, const float* __restrict__ b1,
        const float* __restrict__ W2, float* __restrict__ s2) {
    __shared__ int2 sdata[BIN_CAP];                  // 40 KB sorted edges
    __shared__ struct { int whist[16][PNODES]; int wcur[16][PNODES]; } c; // 16 KB
    __shared__ int ltot[PNODES];
    __shared__ int ltmp[PNODES];
    __shared__ float W2s[NHID * 17];                 // 4.25 KB, stride-17 pad
    __shared__ float b1s[NHID];
    int t = threadIdx.x;
    int wv = t >> 6;                                 // 16 waves
    int b = blockIdx.x;
    int base = b * BIN_CAP;
    int cnt = min(bin_cursor[b], BIN_CAP);

    for (int i = t; i < 16 * PNODES; i += 1024) ((int*)c.whist)[i] = 0;
    if (t < NHID * NCLASS) {
        int k = t >> 4, cc = t & 15;
        W2s[k * 17 + cc] = W2[t];
    }
    if (t < NHID) b1s[t] = b1[t];
    __syncthreads();

    // --- hist pass: load each thread's edges ONCE, keep in registers ---
    int2 myed[S_PER_T];
#pragma unroll
    for (int k = 0; k < S_PER_T; ++k) {
        int j = t + k * 1024;
        if (j < cnt) {
            int2 e0 = csr_bin[base + j];
            myed[k] = e0;
            atomicAdd(&c.whist[wv][e0.x & (PNODES - 1)], 1);
        }
    }
    __syncthreads();
    if (t < PNODES) {
        int v = 0;
#pragma unroll
        for (int k = 0; k < 16; ++k) v += c.whist[k][t];
        ltot[t] = v; ltmp[t] = v;
    }
    __syncthreads();
    for (int off = 1; off < PNODES; off <<= 1) {
        int a = 0;
        if (t < PNODES && t >= off) a = ltmp[t - off];
        __syncthreads();
        if (t < PNODES) ltmp[t] += a;
        __syncthreads();
    }
    if (t < PNODES) {
        int begl = ltmp[t] - ltot[t];                // local (0-based in bin)
        int node = b * PNODES + t;
        if (node < N_NODES)
            row_range[node] = make_int2(base + begl, base + ltmp[t]);
        int run = begl;
#pragma unroll
        for (int k = 0; k < 16; ++k) { c.wcur[k][t] = run; run += c.whist[k][t]; }
    }
    __syncthreads();
    // --- scatter pass: sorted (src, w) into LDS, from registers ---
#pragma unroll
    for (int k = 0; k < S_PER_T; ++k) {
        int j = t + k * 1024;
        if (j < cnt) {
            int2 e0 = myed[k];
            int p0 = atomicAdd(&c.wcur[wv][e0.x & (PNODES - 1)], 1);
            sdata[p0] = make_int2(e0.x >> PBITS, e0.y);
        }
    }
    __syncthreads();
    // --- coalesced writeback for spmm2 ---
    for (int i = t; i < cnt; i += 1024) csr_edge[base + i] = sdata[i];

    // --- spmm1: 128 groups x 8 lanes, uint4 gathers, one round ---
    int g = t >> 3, sub = t & 7;
    int node = b * PNODES + g;
    if (node >= N_NODES) return;
    int endl = ltmp[g];
    int j = endl - ltot[g];
    float accA[8] = {}, accB[8] = {};
    for (; j + 3 < endl; j += 4) {
        int2 e0 = sdata[j],     e1 = sdata[j + 1];
        int2 e2 = sdata[j + 2], e3 = sdata[j + 3];
        uint4 v0 = s1p4[(size_t)e0.x * 8 + sub];
        uint4 v1 = s1p4[(size_t)e1.x * 8 + sub];
        uint4 v2 = s1p4[(size_t)e2.x * 8 + sub];
        uint4 v3 = s1p4[(size_t)e3.x * 8 + sub];
        float w0 = __int_as_float(e0.y), w1 = __int_as_float(e1.y);
        float w2 = __int_as_float(e2.y), w3 = __int_as_float(e3.y);
        accA[0] = fmaf(w0, __uint_as_float(v0.x << 16), accA[0]);
        accA[1] = fmaf(w0, __uint_as_float(v0.x & 0xFFFF0000u), accA[1]);
        accA[2] = fmaf(w0, __uint_as_float(v0.y << 16), accA[2]);
        accA[3] = fmaf(w0, __uint_as_float(v0.y & 0xFFFF0000u), accA[3]);
        accA[4] = fmaf(w0, __uint_as_float(v0.z << 16), accA[4]);
        accA[5] = fmaf(w0, __uint_as_float(v0.z & 0xFFFF0000u), accA[5]);
        accA[6] = fmaf(w0, __uint_as_float(v0.w << 16), accA[6]);
        accA[7] = fmaf(w0, __uint_as_float(v0.w & 0xFFFF0000u), accA[7]);
        accB[0] = fmaf(w1, __uint_as_float(v1.x << 16), accB[0]);
        accB[1] = fmaf(w1, __uint_as_float(v1.x & 0xFFFF0000u), accB[1]);
        accB[2] = fmaf(w1, __uint_as_float(v1.y << 16), accB[2]);
        accB[3] = fmaf(w1, __uint_as_float(v1.y & 0xFFFF0000u), accB[3]);
        accB[4] = fmaf(w1, __uint_as_float(v1.z << 16), accB[4]);
        accB[5] = fmaf(w1, __uint_as_float(v1.z & 0xFFFF0000u), accB[5]);
        accB[6] = fmaf(w1, __uint_as_float(v1.w << 16), accB[6]);
        accB[7] = fmaf(w1, __uint_as_float(v1.w & 0xFFFF0000u), accB[7]);
        accA[0] = fmaf(w2, __uint_as_float(v2.x << 16), accA[0]);
        accA[1] = fmaf(w2, __uint_as_float(v2.x & 0xFFFF0000u), accA[1]);
        accA[2] = fmaf(w2, __uint_as_float(v2.y << 16), accA[2]);
        accA[3] = fmaf(w2, __uint_as_float(v2.y & 0xFFFF0000u), accA[3]);
        accA[4] = fmaf(w2, __uint_as_float(v2.z << 16), accA[4]);
        accA[5] = fmaf(w2, __uint_as_float(v2.z & 0xFFFF0000u), accA[5]);
        accA[6] = fmaf(w2, __uint_as_float(v2.w << 16), accA[6]);
        accA[7] = fmaf(w2, __uint_as_float(v2.w & 0xFFFF0000u), accA[7]);
        accB[0] = fmaf(w3, __uint_as_float(v3.x << 16), accB[0]);
        accB[1] = fmaf(w3, __uint_as_float(v3.x & 0xFFFF0000u), accB[1]);
        accB[2] = fmaf(w3, __uint_as_float(v3.y << 16), accB[2]);
        accB[3] = fmaf(w3, __uint_as_float(v3.y & 0xFFFF0000u), accB[3]);
        accB[4] = fmaf(w3, __uint_as_float(v3.z << 16), accB[4]);
        accB[5] = fmaf(w3, __uint_as_float(v3.z & 0xFFFF0000u), accB[5]);
        accB[6] = fmaf(w3, __uint_as_float(v3.w << 16), accB[6]);
        accB[7] = fmaf(w3, __uint_as_float(v3.w & 0xFFFF0000u), accB[7]);
    }
    for (; j < endl; ++j) {
        int2 e0 = sdata[j];
        uint4 v0 = s1p4[(size_t)e0.x * 8 + sub];
        float w0 = __int_as_float(e0.y);
        accA[0] = fmaf(w0, __uint_as_float(v0.x << 16), accA[0]);
        accA[1] = fmaf(w0, __uint_as_float(v0.x & 0xFFFF0000u), accA[1]);
        accA[2] = fmaf(w0, __uint_as_float(v0.y << 16), accA[2]);
        accA[3] = fmaf(w0, __uint_as_float(v0.y & 0xFFFF0000u), accA[3]);
        accA[4] = fmaf(w0, __uint_as_float(v0.z << 16), accA[4]);
        accA[5] = fmaf(w0, __uint_as_float(v0.z & 0xFFFF0000u), accA[5]);
        accA[6] = fmaf(w0, __uint_as_float(v0.w << 16), accA[6]);
        accA[7] = fmaf(w0, __uint_as_float(v0.w & 0xFFFF0000u), accA[7]);
    }
    // bias + ReLU in registers (lane sub owns cols 8*sub .. 8*sub+7)
    float h[8];
#pragma unroll
    for (int i = 0; i < 8; ++i) {
        float hv = accA[i] + accB[i] + b1s[8 * sub + i];
        h[i] = hv > 0.f ? hv : 0.f;
    }
    // gemm2 partials: 16 classes per lane over its 8 k's
    float cls[16] = {};
#pragma unroll
    for (int i = 0; i < 8; ++i)
#pragma unroll
        for (int cc = 0; cc < 16; ++cc)
            cls[cc] = fmaf(h[i], W2s[(8 * sub + i) * 17 + cc], cls[cc]);
    // butterfly reduce across the 8-lane group
#pragma unroll
    for (int off = 1; off <= 4; off <<= 1)
#pragma unroll
        for (int cc = 0; cc < 16; ++cc)
            cls[cc] += __shfl_xor(cls[cc], off, 8);
    // lane sub writes classes 2*sub, 2*sub+1 (compile-time select, no scratch)
    float o0 = 0.f, o1 = 0.f;
#pragma unroll
    for (int cc = 0; cc < 8; ++cc)
        if (sub == cc) { o0 = cls[2 * cc]; o1 = cls[2 * cc + 1]; }
    *(float2*)&s2[(size_t)node * NCLASS + 2 * sub] = make_float2(o0, o1);
}

// ======================= SpMM2 + bias + log_softmax ========================
// R13-proven: 4 lanes/edge x 4 edges/iter with float4 s2 gathers; shfl_xor
// tree reductions; one float4 store per quad.
__global__ void spmm2_csr_kernel(const int2* __restrict__ row_range,
                                 const int2* __restrict__ csr_edge,
                                 const float* __restrict__ s2,
                                 const float* __restrict__ b2,
                                 float* __restrict__ out) {
    int node = blockIdx.x * 16 + (threadIdx.x >> 4);
    if (node >= N_NODES) return;
    int l  = threadIdx.x & 15;
    int eo = l >> 2;                    // edge slot within quad (0..3)
    int q  = l & 3;                     // class quad: classes 4q..4q+3
    int2 rr = row_range[node];
    int beg = rr.x, end = rr.y;
    float4 accA = {0.f, 0.f, 0.f, 0.f}, accB = {0.f, 0.f, 0.f, 0.f};
    int j = beg;
    for (; j + 7 < end; j += 8) {       // 8 edges: two quads in flight
        int2 eA = csr_edge[j + eo];
        int2 eB = csr_edge[j + 4 + eo];
        float4 vA = *(const float4*)&s2[(size_t)eA.x * NCLASS + 4 * q];
        float4 vB = *(const float4*)&s2[(size_t)eB.x * NCLASS + 4 * q];
        float wA = __int_as_float(eA.y), wB = __int_as_float(eB.y);
        accA.x = fmaf(wA, vA.x, accA.x);
        accA.y = fmaf(wA, vA.y, accA.y);
        accA.z = fmaf(wA, vA.z, accA.z);
        accA.w = fmaf(wA, vA.w, accA.w);
        accB.x = fmaf(wB, vB.x, accB.x);
        accB.y = fmaf(wB, vB.y, accB.y);
        accB.z = fmaf(wB, vB.z, accB.z);
        accB.w = fmaf(wB, vB.w, accB.w);
    }
    for (; j + 3 < end; j += 4) {       // 4-edge quad
        int2 eA = csr_edge[j + eo];
        float4 vA = *(const float4*)&s2[(size_t)eA.x * NCLASS + 4 * q];
        float wA = __int_as_float(eA.y);
        accA.x = fmaf(wA, vA.x, accA.x);
        accA.y = fmaf(wA, vA.y, accA.y);
        accA.z = fmaf(wA, vA.z, accA.z);
        accA.w = fmaf(wA, vA.w, accA.w);
    }
    {                                   // tail: 0-3 edges, slot eo < rem
        int rem = end - j;
        if (eo < rem) {
            int2 eA = csr_edge[j + eo];
            float4 vA = *(const float4*)&s2[(size_t)eA.x * NCLASS + 4 * q];
            float wA = __int_as_float(eA.y);
            accB.x = fmaf(wA, vA.x, accB.x);
            accB.y = fmaf(wA, vA.y, accB.y);
            accB.z = fmaf(wA, vA.z, accB.z);
            accB.w = fmaf(wA, vA.w, accB.w);
        }
    }
    float4 v;
    v.x = accA.x + accB.x; v.y = accA.y + accB.y;
    v.z = accA.z + accB.z; v.w = accA.w + accB.w;
    // reduce across the 4 edge slots (lanes differing in bits 2-3 of l)
    for (int off = 4; off <= 8; off <<= 1) {
        v.x += __shfl_xor(v.x, off, 16);
        v.y += __shfl_xor(v.y, off, 16);
        v.z += __shfl_xor(v.z, off, 16);
        v.w += __shfl_xor(v.w, off, 16);
    }
    float4 bv = *(const float4*)&b2[4 * q];
    v.x += bv.x; v.y += bv.y; v.z += bv.z; v.w += bv.w;
    // log_softmax over 16 classes: in-lane max/sum of the quad, then across q
    float mx = fmaxf(fmaxf(v.x, v.y), fmaxf(v.z, v.w));
    for (int off = 1; off <= 2; off <<= 1) mx = fmaxf(mx, __shfl_xor(mx, off, 16));
    float ss = expf(v.x - mx) + expf(v.y - mx) + expf(v.z - mx) + expf(v.w - mx);
    for (int off = 1; off <= 2; off <<= 1) ss += __shfl_xor(ss, off, 16);
    float ls = mx + logf(ss);
    if (eo == 0) {                      // one slot writes the quad (float4)
        float4 o;
        o.x = v.x - ls; o.y = v.y - ls; o.z = v.z - ls; o.w = v.w - ls;
        *(float4*)&out[(size_t)node * NCLASS + 4 * q] = o;
    }
}

// ======================= fallback path (R3 atomic version) =================

__global__ void zero_kernel(float* __restrict__ h, float* __restrict__ out) {
    int i = blockIdx.x * 256 + threadIdx.x;
    if (i < N_NODES * NHID) h[i] = 0.f;
    if (i < N_NODES * NCLASS) out[i] = 0.f;
}

__global__ void gemm1_kernel(const float* __restrict__ x,
                             const float* __restrict__ W1,
                             float* __restrict__ s1) {
    int node = blockIdx.x * 4 + (threadIdx.x >> 6);
    int col  = threadIdx.x & 63;
    if (node >= N_NODES) return;
    const float* xr = x + (size_t)node * NFEAT;
    float sum = 0.f;
#pragma unroll 8
    for (int k = 0; k < NFEAT; ++k)
        sum = fmaf(xr[k], W1[k * NHID + col], sum);
    s1[(size_t)node * NHID + col] = sum;
}

__global__ void spmm1_kernel(const int* __restrict__ src, const int* __restrict__ dst,
                             const float* __restrict__ w, const float* __restrict__ s1,
                             float* __restrict__ h) {
    int e = blockIdx.x * 4 + (threadIdx.x >> 6);
    if (e >= N_EDGES) return;
    int lane = threadIdx.x & 63;
    int s = min(max(src[e], 0), N_NODES - 1);
    int d = min(max(dst[e], 0), N_NODES - 1);
    float v = w[e] * s1[(size_t)s * NHID + lane];
    atomicAdd(&h[(size_t)d * NHID + lane], v);
}

__global__ void bias_relu_kernel(float* __restrict__ h, const float* __restrict__ b1) {
    int i = blockIdx.x * 256 + threadIdx.x;
    if (i >= N_NODES * NHID) return;
    float v = h[i] + b1[i & (NHID - 1)];
    h[i] = v > 0.f ? v : 0.f;
}

__global__ void gemm2_kernel(const float* __restrict__ h,
                             const float* __restrict__ W2,
                             float* __restrict__ s2) {
    int node = blockIdx.x * 16 + (threadIdx.x >> 4);
    int col  = threadIdx.x & 15;
    if (node >= N_NODES) return;
    const float* hr = h + (size_t)node * NHID;
    float sum = 0.f;
#pragma unroll 8
    for (int k = 0; k < NHID; ++k)
        sum = fmaf(hr[k], W2[k * NCLASS + col], sum);
    s2[(size_t)node * NCLASS + col] = sum;
}

__global__ void spmm2_kernel(const int* __restrict__ src, const int* __restrict__ dst,
                             const float* __restrict__ w, const float* __restrict__ s2,
                             float* __restrict__ out) {
    int e = blockIdx.x * 16 + (threadIdx.x >> 4);
    if (e >= N_EDGES) return;
    int lane = threadIdx.x & 15;
    int s = min(max(src[e], 0), N_NODES - 1);
    int d = min(max(dst[e], 0), N_NODES - 1);
    float v = w[e] * s2[(size_t)s * NCLASS + lane];
    atomicAdd(&out[(size_t)d * NCLASS + lane], v);
}

__global__ void logsoftmax_kernel(float* __restrict__ out, const float* __restrict__ b2) {
    int n = blockIdx.x * 256 + threadIdx.x;
    if (n >= N_NODES) return;
    float v[NCLASS];
    float mx = -INFINITY;
#pragma unroll
    for (int c = 0; c < NCLASS; ++c) {
        v[c] = out[(size_t)n * NCLASS + c] + b2[c];
        mx = fmaxf(mx, v[c]);
    }
    float ssum = 0.f;
#pragma unroll
    for (int c = 0; c < NCLASS; ++c) ssum += expf(v[c] - mx);
    float ls = mx + logf(ssum);
#pragma unroll
    for (int c = 0; c < NCLASS; ++c) out[(size_t)n * NCLASS + c] = v[c] - ls;
}

// ======================= launch ============================================

extern "C" void kernel_launch(void* const* d_in, const int* in_sizes, int n_in,
                              void* d_out, int out_size, void* d_ws, size_t ws_size,
                              hipStream_t stream) {
    if (n_in != 8) return;
    const int expected[8] = { N_NODES * NFEAT, NFEAT * NHID, NHID,
                              NHID * NCLASS, NCLASS, N_EDGES, N_EDGES, N_EDGES };
    for (int i = 0; i < 8; ++i)
        if (in_sizes[i] != expected[i]) return;
    if (out_size != N_NODES * NCLASS) return;

    const float* x  = (const float*)d_in[0];
    const float* W1 = (const float*)d_in[1];
    const float* b1 = (const float*)d_in[2];
    const float* W2 = (const float*)d_in[3];
    const float* b2 = (const float*)d_in[4];
    const int* edge_src = (const int*)d_in[5];
    const int* edge_dst = (const int*)d_in[6];
    const float* edge_w = (const float*)d_in[7];
    float* out = (float*)d_out;

    const size_t S1_ELTS = (size_t)N_NODES * NHID;          // 3.2M (ushorts)
    const size_t CAP_WORDS = (size_t)NBINS * BIN_CAP * 2;   // int2 region, words
    // layout (32-bit words) — fully DISJOINT (s1b live alongside csr_bin
    // inside sort_spmm1_fused):
    //   [0, CAP)          csr_bin    (16 MB)
    //   [CAP, 2CAP)       csr_edge   (16 MB)
    //   [2CAP, +2N)       row_range  (0.4 MB)
    //   [.., +512)        bin_cursor (391 ints + pad, keeps s1b 16B-aligned)
    //   [.., +S1/2)       s1b        (6.4 MB bf16)
    //   [.., +N*NCLASS)   s2         (3.2 MB fp32)
    const size_t NEW_WORDS = 2 * CAP_WORDS + 2 * (size_t)N_NODES + 512
                           + S1_ELTS / 2 + (size_t)N_NODES * NCLASS;
    if (ws_size >= NEW_WORDS * 4) {
        int2*  csr_bin    = (int2*)d_ws;
        int2*  csr_edge   = (int2*)((int*)d_ws + CAP_WORDS);
        int2*  row_range  = (int2*)((int*)d_ws + 2 * CAP_WORDS);
        int*   bin_cursor = (int*)d_ws + 2 * CAP_WORDS + 2 * (size_t)N_NODES;
        unsigned short* s1b =
            (unsigned short*)((int*)d_ws + 2 * CAP_WORDS + 2 * (size_t)N_NODES + 512);
        float* s2 = (float*)d_ws + 2 * CAP_WORDS + 2 * (size_t)N_NODES + 512
                  + S1_ELTS / 2;

        // gemm1 first: its block 0 zeroes bin_cursor (replaces memset dispatch)
        gemm1_mfma<<<(N_NODES + 63) / 64, 256, 0, stream>>>(x, W1, s1b, bin_cursor);
        bin_scatter_kernel<<<K3_BLOCKS, K3_THREADS, 0, stream>>>(
            edge_src, edge_dst, edge_w, bin_cursor, csr_bin);
        sort_spmm1_fused<<<NBINS, 1024, 0, stream>>>(
            bin_cursor, csr_bin, csr_edge, row_range,
            (const uint4*)s1b, b1, W2, s2);
        spmm2_csr_kernel<<<(N_NODES + 15) / 16, 256, 0, stream>>>(
            row_range, csr_edge, s2, b2, out);
        return;
    }

    // --- fallback: proven atomic path (25.6 MB ws) ---
    if (ws_size < 2 * S1_ELTS * sizeof(float)) return;
    float* s1 = (float*)d_ws;
    float* h  = s1 + S1_ELTS;
    float* s2 = s1;
    zero_kernel<<<(N_NODES * NHID + 255) / 256, 256, 0, stream>>>(h, out);
    gemm1_kernel<<<(N_NODES + 3) / 4, 256, 0, stream>>>(x, W1, s1);
    spmm1_kernel<<<(N_EDGES + 3) / 4, 256, 0, stream>>>(edge_src, edge_dst, edge_w, s1, h);
    bias_relu_kernel<<<(N_NODES * NHID + 255) / 256, 256, 0, stream>>>(h, b1);
    gemm2_kernel<<<(N_NODES + 15) / 16, 256, 0, stream>>>(h, W2, s2);
    spmm2_kernel<<<(N_EDGES + 15) / 16, 256, 0, stream>>>(edge_src, edge_dst, edge_w, s2, out);
    logsoftmax_kernel<<<(N_NODES + 255) / 256, 256, 0, stream>>>(out, b2);
}